// Round 8
// baseline (297.402 us; speedup 1.0000x reference)
//
#include <hip/hip_runtime.h>
#include <math.h>

#define BT      4096
#define T_SEQ   2048
#define E_DIM   1024
#define V_DIM   2048
#define DK      128
#define DV      256

typedef unsigned short ushort_t;
typedef __attribute__((ext_vector_type(8)))  short bf16x8;
typedef __attribute__((ext_vector_type(4)))  unsigned short u16x4;
typedef __attribute__((ext_vector_type(16))) float f32x16;

__device__ __forceinline__ void decay_params(int h, float& ld, float& gamma) {
    const float s0 = -3.4657359027997265f;  // ln(1/32)
    const float e0 = -6.2383246250395092f;  // ln(1/512)
    float lin = s0 + (e0 - s0) * ((float)h * (1.0f / 7.0f));
    gamma = 1.0f - expf(lin);
    ld = logf(gamma);
}

__device__ __forceinline__ short f2bf(float f) {
    unsigned u = __float_as_uint(f);
    unsigned r = (u + 0x7fffu + ((u >> 16) & 1u)) >> 16;
    return (short)r;
}
__device__ __forceinline__ float bf2f(ushort_t u) {
    return __uint_as_float((unsigned)u << 16);
}

__device__ __forceinline__ void async_copy16(void* lds, const void* g) {
    __builtin_amdgcn_global_load_lds(
        (const __attribute__((address_space(1))) unsigned int*)g,
        (__attribute__((address_space(3))) unsigned int*)lds, 16, 0, 0);
}

// Simple XCD swizzle (contiguous strip per XCD) — used by tm64.
__device__ __forceinline__ void xcd_tile(int& bx, int& by) {
    const int nwgx = gridDim.x;
    const int nwg  = nwgx * gridDim.y;
    int bid = blockIdx.y * nwgx + blockIdx.x;
    bid = (bid & 7) * (nwg >> 3) + (bid >> 3);
    bx = bid % nwgx;
    by = bid / nwgx;
}

// Square XCD regions for qkv grid (16,16): each XCD owns 8 n-cols x 4 m-rows
// -> per-XCD L2 working set = A 2MB + B 4MB (vs 1+8 for the strip mapping).
// Bijective: xcd=(bx>>3)|((by>>2)<<1), idx=(bx&7)|((by&3)<<3).
__device__ __forceinline__ void xcd_map_qkv(int& bx, int& by) {
    int bid = blockIdx.y * 16 + blockIdx.x;
    const int xcd = bid & 7, idx = bid >> 3;            // idx in [0,32)
    bx = (xcd & 1) * 8 + (idx & 7);
    by = (xcd >> 1) * 4 + (idx >> 3);
}

// Square XCD regions for gate grid (8,32): each XCD owns 4 n-cols x 8 m-rows
// -> per-XCD working set = A 2MB + B 2MB.
// Bijective: xcd=(bx>>2)|((by>>3)<<1), idx=(bx&3)|((by&7)<<2).
__device__ __forceinline__ void xcd_map_gate(int& bx, int& by) {
    int bid = blockIdx.y * 8 + blockIdx.x;
    const int xcd = bid & 7, idx = bid >> 3;            // idx in [0,32)
    bx = (xcd & 1) * 4 + (idx & 3);
    by = (xcd >> 1) * 8 + (idx >> 2);
}

// ---------------------------------------------------------------------------
// fp32 -> bf16 elementwise
// ---------------------------------------------------------------------------
__global__ __launch_bounds__(256)
void f32_to_bf16_kernel(const float* __restrict__ in, ushort_t* __restrict__ out)
{
    int i = (blockIdx.x * 256 + threadIdx.x) * 8;
    float4 a = *(const float4*)&in[i];
    float4 b = *(const float4*)&in[i + 4];
    bf16x8 o;
    o[0] = f2bf(a.x); o[1] = f2bf(a.y); o[2] = f2bf(a.z); o[3] = f2bf(a.w);
    o[4] = f2bf(b.x); o[5] = f2bf(b.y); o[6] = f2bf(b.z); o[7] = f2bf(b.w);
    *(bf16x8*)&out[i] = o;
}

// ---------------------------------------------------------------------------
// W[K][N] fp32 -> Wt[N][K] bf16
// ---------------------------------------------------------------------------
__global__ __launch_bounds__(256)
void transpose_w_kernel(const float* __restrict__ W, ushort_t* __restrict__ Wt,
                        int K, int N)
{
    __shared__ float tile[32][33];
    const int k0 = blockIdx.y * 32, n0 = blockIdx.x * 32;
    const int t = threadIdx.x;
    const int r = t >> 3, c = (t & 7) * 4;
    float4 v = *(const float4*)&W[(size_t)(k0 + r) * N + n0 + c];
    tile[r][c] = v.x; tile[r][c + 1] = v.y; tile[r][c + 2] = v.z; tile[r][c + 3] = v.w;
    __syncthreads();
    u16x4 o;
    o[0] = (ushort_t)f2bf(tile[c][r]);
    o[1] = (ushort_t)f2bf(tile[c + 1][r]);
    o[2] = (ushort_t)f2bf(tile[c + 2][r]);
    o[3] = (ushort_t)f2bf(tile[c + 3][r]);
    *(u16x4*)&Wt[(size_t)(n0 + r) * K + k0 + c] = o;
}

// ---------------------------------------------------------------------------
// 8-PHASE 256x256 GEMM for qkv (round-4 proven schedule):
//   - bf16 output, ni-INNERMOST epilogue (both 64B halves of each 128B line
//     dirtied back-to-back -> no partial-line evict/rewrite)
//   - square XCD region mapping
// ---------------------------------------------------------------------------
__global__ __launch_bounds__(512, 2)
void gemm256p8(const ushort_t* __restrict__ A,
               const ushort_t* __restrict__ Bt,
               const float* __restrict__ bias,
               ushort_t* __restrict__ C, int ldc, int nkt)  // nkt >= 2
{
    __shared__ ushort_t As[2 * 16384];   // 64 KB
    __shared__ ushort_t Bs[2 * 16384];   // 64 KB

    const int tid = threadIdx.x;
    const int wid = tid >> 6, l = tid & 63;
    const int lc = l & 31, q = l >> 5;
    const int wr = wid >> 2, wc = wid & 3;
    int bx, by; xcd_map_qkv(bx, by);
    const int m0 = by * 256, n0 = bx * 256;

    const int sra = tid >> 3;
    const int spa = (tid & 7) ^ (sra & 7);
    const ushort_t* gA = A + (size_t)(m0 + sra) * 1024 + spa * 8;
    const int srb = tid >> 2;
    const int spb = (tid & 3) ^ ((srb >> 1) & 3);
    const ushort_t* gB = Bt + (size_t)(n0 + srb) * 1024 + spb * 8;
    const int da = tid * 8;

    int arow0 = (wr * 128 +  0 + lc) * 64;
    int arow1 = (wr * 128 + 32 + lc) * 64;
    int arow2 = (wr * 128 + 64 + lc) * 64;
    int arow3 = (wr * 128 + 96 + lc) * 64;
    int sk0 = ((0 * 2 + q) ^ (lc & 7)) * 8;
    int sk1 = ((1 * 2 + q) ^ (lc & 7)) * 8;
    int sk2 = ((2 * 2 + q) ^ (lc & 7)) * 8;
    int sk3 = ((3 * 2 + q) ^ (lc & 7)) * 8;
    int brow0 = (wc * 64 +  0 + lc) * 32;
    int brow1 = (wc * 64 + 32 + lc) * 32;
    int tk0 = ((0 + q) ^ ((lc >> 1) & 3)) * 8;
    int tk1 = ((2 + q) ^ ((lc >> 1) & 3)) * 8;
    int tk2 = 8192 + ((0 + q) ^ ((lc >> 1) & 3)) * 8;
    int tk3 = 8192 + ((2 + q) ^ ((lc >> 1) & 3)) * 8;

    f32x16 acc[4][2];
    #pragma unroll
    for (int mi = 0; mi < 4; ++mi)
        #pragma unroll
        for (int ni = 0; ni < 2; ++ni)
            #pragma unroll
            for (int e = 0; e < 16; ++e) acc[mi][ni][e] = 0.0f;

    async_copy16(&As[da],          gA);
    async_copy16(&As[8192 + da],   gA + 131072);
    async_copy16(&Bs[da],          gB);
    async_copy16(&Bs[4096 + da],   gB + 131072);
    async_copy16(&As[4096 + da],   gA + 65536);
    async_copy16(&As[12288 + da],  gA + 196608);
    async_copy16(&Bs[8192 + da],   gB + 32);
    async_copy16(&Bs[12288 + da],  gB + 131072 + 32);
    gA += 64; gB += 64;
    asm volatile("s_waitcnt vmcnt(0)" ::: "memory");
    __builtin_amdgcn_s_barrier();

    int cur = 0;
    for (int t = 0; t < nkt - 1; ++t) {
        const int cb = cur * 16384;
        const int nb = 16384 - cb;
        // ---- PH0 ----
        bf16x8 a00 = *(const bf16x8*)&As[cb + arow0 + sk0];
        bf16x8 a01 = *(const bf16x8*)&As[cb + arow0 + sk1];
        bf16x8 a10 = *(const bf16x8*)&As[cb + arow1 + sk0];
        bf16x8 a11 = *(const bf16x8*)&As[cb + arow1 + sk1];
        bf16x8 b00 = *(const bf16x8*)&Bs[cb + brow0 + tk0];
        bf16x8 b01 = *(const bf16x8*)&Bs[cb + brow0 + tk1];
        bf16x8 b10 = *(const bf16x8*)&Bs[cb + brow1 + tk0];
        bf16x8 b11 = *(const bf16x8*)&Bs[cb + brow1 + tk1];
        async_copy16(&As[nb + da],        gA);
        async_copy16(&As[nb + 8192 + da], gA + 131072);
        async_copy16(&Bs[nb + da],        gB);
        async_copy16(&Bs[nb + 4096 + da], gB + 131072);
        __builtin_amdgcn_s_barrier();
        asm volatile("s_waitcnt lgkmcnt(0)" ::: "memory");
        __builtin_amdgcn_s_setprio(1);
        acc[0][0] = __builtin_amdgcn_mfma_f32_32x32x16_bf16(a00, b00, acc[0][0], 0, 0, 0);
        acc[0][1] = __builtin_amdgcn_mfma_f32_32x32x16_bf16(a00, b10, acc[0][1], 0, 0, 0);
        acc[1][0] = __builtin_amdgcn_mfma_f32_32x32x16_bf16(a10, b00, acc[1][0], 0, 0, 0);
        acc[1][1] = __builtin_amdgcn_mfma_f32_32x32x16_bf16(a10, b10, acc[1][1], 0, 0, 0);
        acc[0][0] = __builtin_amdgcn_mfma_f32_32x32x16_bf16(a01, b01, acc[0][0], 0, 0, 0);
        acc[0][1] = __builtin_amdgcn_mfma_f32_32x32x16_bf16(a01, b11, acc[0][1], 0, 0, 0);
        acc[1][0] = __builtin_amdgcn_mfma_f32_32x32x16_bf16(a11, b01, acc[1][0], 0, 0, 0);
        acc[1][1] = __builtin_amdgcn_mfma_f32_32x32x16_bf16(a11, b11, acc[1][1], 0, 0, 0);
        __builtin_amdgcn_s_setprio(0);
        asm volatile("s_waitcnt vmcnt(6)" ::: "memory");
        __builtin_amdgcn_s_barrier();
        // ---- PH1 ----
        bf16x8 a20 = *(const bf16x8*)&As[cb + arow2 + sk0];
        bf16x8 a21 = *(const bf16x8*)&As[cb + arow2 + sk1];
        bf16x8 a30 = *(const bf16x8*)&As[cb + arow3 + sk0];
        bf16x8 a31 = *(const bf16x8*)&As[cb + arow3 + sk1];
        async_copy16(&As[nb + 4096 + da],  gA + 65536);
        async_copy16(&As[nb + 12288 + da], gA + 196608);
        __builtin_amdgcn_s_barrier();
        asm volatile("s_waitcnt lgkmcnt(0)" ::: "memory");
        __builtin_amdgcn_s_setprio(1);
        acc[2][0] = __builtin_amdgcn_mfma_f32_32x32x16_bf16(a20, b00, acc[2][0], 0, 0, 0);
        acc[2][1] = __builtin_amdgcn_mfma_f32_32x32x16_bf16(a20, b10, acc[2][1], 0, 0, 0);
        acc[3][0] = __builtin_amdgcn_mfma_f32_32x32x16_bf16(a30, b00, acc[3][0], 0, 0, 0);
        acc[3][1] = __builtin_amdgcn_mfma_f32_32x32x16_bf16(a30, b10, acc[3][1], 0, 0, 0);
        acc[2][0] = __builtin_amdgcn_mfma_f32_32x32x16_bf16(a21, b01, acc[2][0], 0, 0, 0);
        acc[2][1] = __builtin_amdgcn_mfma_f32_32x32x16_bf16(a21, b11, acc[2][1], 0, 0, 0);
        acc[3][0] = __builtin_amdgcn_mfma_f32_32x32x16_bf16(a31, b01, acc[3][0], 0, 0, 0);
        acc[3][1] = __builtin_amdgcn_mfma_f32_32x32x16_bf16(a31, b11, acc[3][1], 0, 0, 0);
        __builtin_amdgcn_s_setprio(0);
        asm volatile("s_waitcnt vmcnt(6)" ::: "memory");
        __builtin_amdgcn_s_barrier();
        // ---- PH2 ----
        bf16x8 a02 = *(const bf16x8*)&As[cb + arow0 + sk2];
        bf16x8 a03 = *(const bf16x8*)&As[cb + arow0 + sk3];
        bf16x8 a12 = *(const bf16x8*)&As[cb + arow1 + sk2];
        bf16x8 a13 = *(const bf16x8*)&As[cb + arow1 + sk3];
        bf16x8 b02 = *(const bf16x8*)&Bs[cb + brow0 + tk2];
        bf16x8 b03 = *(const bf16x8*)&Bs[cb + brow0 + tk3];
        bf16x8 b12 = *(const bf16x8*)&Bs[cb + brow1 + tk2];
        bf16x8 b13 = *(const bf16x8*)&Bs[cb + brow1 + tk3];
        async_copy16(&Bs[nb + 8192 + da],  gB + 32);
        async_copy16(&Bs[nb + 12288 + da], gB + 131072 + 32);
        gA += 64; gB += 64;
        __builtin_amdgcn_s_barrier();
        asm volatile("s_waitcnt lgkmcnt(0)" ::: "memory");
        __builtin_amdgcn_s_setprio(1);
        acc[0][0] = __builtin_amdgcn_mfma_f32_32x32x16_bf16(a02, b02, acc[0][0], 0, 0, 0);
        acc[0][1] = __builtin_amdgcn_mfma_f32_32x32x16_bf16(a02, b12, acc[0][1], 0, 0, 0);
        acc[1][0] = __builtin_amdgcn_mfma_f32_32x32x16_bf16(a12, b02, acc[1][0], 0, 0, 0);
        acc[1][1] = __builtin_amdgcn_mfma_f32_32x32x16_bf16(a12, b12, acc[1][1], 0, 0, 0);
        acc[0][0] = __builtin_amdgcn_mfma_f32_32x32x16_bf16(a03, b03, acc[0][0], 0, 0, 0);
        acc[0][1] = __builtin_amdgcn_mfma_f32_32x32x16_bf16(a03, b13, acc[0][1], 0, 0, 0);
        acc[1][0] = __builtin_amdgcn_mfma_f32_32x32x16_bf16(a13, b03, acc[1][0], 0, 0, 0);
        acc[1][1] = __builtin_amdgcn_mfma_f32_32x32x16_bf16(a13, b13, acc[1][1], 0, 0, 0);
        __builtin_amdgcn_s_setprio(0);
        __builtin_amdgcn_s_barrier();
        // ---- PH3 ----
        bf16x8 a22 = *(const bf16x8*)&As[cb + arow2 + sk2];
        bf16x8 a23 = *(const bf16x8*)&As[cb + arow2 + sk3];
        bf16x8 a32 = *(const bf16x8*)&As[cb + arow3 + sk2];
        bf16x8 a33 = *(const bf16x8*)&As[cb + arow3 + sk3];
        __builtin_amdgcn_s_barrier();
        asm volatile("s_waitcnt lgkmcnt(0)" ::: "memory");
        __builtin_amdgcn_s_setprio(1);
        acc[2][0] = __builtin_amdgcn_mfma_f32_32x32x16_bf16(a22, b02, acc[2][0], 0, 0, 0);
        acc[2][1] = __builtin_amdgcn_mfma_f32_32x32x16_bf16(a22, b12, acc[2][1], 0, 0, 0);
        acc[3][0] = __builtin_amdgcn_mfma_f32_32x32x16_bf16(a32, b02, acc[3][0], 0, 0, 0);
        acc[3][1] = __builtin_amdgcn_mfma_f32_32x32x16_bf16(a32, b12, acc[3][1], 0, 0, 0);
        acc[2][0] = __builtin_amdgcn_mfma_f32_32x32x16_bf16(a23, b03, acc[2][0], 0, 0, 0);
        acc[2][1] = __builtin_amdgcn_mfma_f32_32x32x16_bf16(a23, b13, acc[2][1], 0, 0, 0);
        acc[3][0] = __builtin_amdgcn_mfma_f32_32x32x16_bf16(a33, b03, acc[3][0], 0, 0, 0);
        acc[3][1] = __builtin_amdgcn_mfma_f32_32x32x16_bf16(a33, b13, acc[3][1], 0, 0, 0);
        __builtin_amdgcn_s_setprio(0);
        asm volatile("s_waitcnt vmcnt(4)" ::: "memory");
        __builtin_amdgcn_s_barrier();
        cur ^= 1;
    }

    {   // tail tile
        const int cb = cur * 16384;
        bf16x8 a00 = *(const bf16x8*)&As[cb + arow0 + sk0];
        bf16x8 a01 = *(const bf16x8*)&As[cb + arow0 + sk1];
        bf16x8 a10 = *(const bf16x8*)&As[cb + arow1 + sk0];
        bf16x8 a11 = *(const bf16x8*)&As[cb + arow1 + sk1];
        bf16x8 b00 = *(const bf16x8*)&Bs[cb + brow0 + tk0];
        bf16x8 b01 = *(const bf16x8*)&Bs[cb + brow0 + tk1];
        bf16x8 b10 = *(const bf16x8*)&Bs[cb + brow1 + tk0];
        bf16x8 b11 = *(const bf16x8*)&Bs[cb + brow1 + tk1];
        __builtin_amdgcn_s_barrier();
        asm volatile("s_waitcnt lgkmcnt(0)" ::: "memory");
        __builtin_amdgcn_s_setprio(1);
        acc[0][0] = __builtin_amdgcn_mfma_f32_32x32x16_bf16(a00, b00, acc[0][0], 0, 0, 0);
        acc[0][1] = __builtin_amdgcn_mfma_f32_32x32x16_bf16(a00, b10, acc[0][1], 0, 0, 0);
        acc[1][0] = __builtin_amdgcn_mfma_f32_32x32x16_bf16(a10, b00, acc[1][0], 0, 0, 0);
        acc[1][1] = __builtin_amdgcn_mfma_f32_32x32x16_bf16(a10, b10, acc[1][1], 0, 0, 0);
        acc[0][0] = __builtin_amdgcn_mfma_f32_32x32x16_bf16(a01, b01, acc[0][0], 0, 0, 0);
        acc[0][1] = __builtin_amdgcn_mfma_f32_32x32x16_bf16(a01, b11, acc[0][1], 0, 0, 0);
        acc[1][0] = __builtin_amdgcn_mfma_f32_32x32x16_bf16(a11, b01, acc[1][0], 0, 0, 0);
        acc[1][1] = __builtin_amdgcn_mfma_f32_32x32x16_bf16(a11, b11, acc[1][1], 0, 0, 0);
        __builtin_amdgcn_s_setprio(0);
        asm volatile("s_waitcnt vmcnt(2)" ::: "memory");
        __builtin_amdgcn_s_barrier();
        bf16x8 a20 = *(const bf16x8*)&As[cb + arow2 + sk0];
        bf16x8 a21 = *(const bf16x8*)&As[cb + arow2 + sk1];
        bf16x8 a30 = *(const bf16x8*)&As[cb + arow3 + sk0];
        bf16x8 a31 = *(const bf16x8*)&As[cb + arow3 + sk1];
        __builtin_amdgcn_s_barrier();
        asm volatile("s_waitcnt lgkmcnt(0)" ::: "memory");
        __builtin_amdgcn_s_setprio(1);
        acc[2][0] = __builtin_amdgcn_mfma_f32_32x32x16_bf16(a20, b00, acc[2][0], 0, 0, 0);
        acc[2][1] = __builtin_amdgcn_mfma_f32_32x32x16_bf16(a20, b10, acc[2][1], 0, 0, 0);
        acc[3][0] = __builtin_amdgcn_mfma_f32_32x32x16_bf16(a30, b00, acc[3][0], 0, 0, 0);
        acc[3][1] = __builtin_amdgcn_mfma_f32_32x32x16_bf16(a30, b10, acc[3][1], 0, 0, 0);
        acc[2][0] = __builtin_amdgcn_mfma_f32_32x32x16_bf16(a21, b01, acc[2][0], 0, 0, 0);
        acc[2][1] = __builtin_amdgcn_mfma_f32_32x32x16_bf16(a21, b11, acc[2][1], 0, 0, 0);
        acc[3][0] = __builtin_amdgcn_mfma_f32_32x32x16_bf16(a31, b01, acc[3][0], 0, 0, 0);
        acc[3][1] = __builtin_amdgcn_mfma_f32_32x32x16_bf16(a31, b11, acc[3][1], 0, 0, 0);
        __builtin_amdgcn_s_setprio(0);
        asm volatile("s_waitcnt vmcnt(0)" ::: "memory");
        __builtin_amdgcn_s_barrier();
        bf16x8 a02 = *(const bf16x8*)&As[cb + arow0 + sk2];
        bf16x8 a03 = *(const bf16x8*)&As[cb + arow0 + sk3];
        bf16x8 a12 = *(const bf16x8*)&As[cb + arow1 + sk2];
        bf16x8 a13 = *(const bf16x8*)&As[cb + arow1 + sk3];
        bf16x8 b02 = *(const bf16x8*)&Bs[cb + brow0 + tk2];
        bf16x8 b03 = *(const bf16x8*)&Bs[cb + brow0 + tk3];
        bf16x8 b12 = *(const bf16x8*)&Bs[cb + brow1 + tk2];
        bf16x8 b13 = *(const bf16x8*)&Bs[cb + brow1 + tk3];
        __builtin_amdgcn_s_barrier();
        asm volatile("s_waitcnt lgkmcnt(0)" ::: "memory");
        __builtin_amdgcn_s_setprio(1);
        acc[0][0] = __builtin_amdgcn_mfma_f32_32x32x16_bf16(a02, b02, acc[0][0], 0, 0, 0);
        acc[0][1] = __builtin_amdgcn_mfma_f32_32x32x16_bf16(a02, b12, acc[0][1], 0, 0, 0);
        acc[1][0] = __builtin_amdgcn_mfma_f32_32x32x16_bf16(a12, b02, acc[1][0], 0, 0, 0);
        acc[1][1] = __builtin_amdgcn_mfma_f32_32x32x16_bf16(a12, b12, acc[1][1], 0, 0, 0);
        acc[0][0] = __builtin_amdgcn_mfma_f32_32x32x16_bf16(a03, b03, acc[0][0], 0, 0, 0);
        acc[0][1] = __builtin_amdgcn_mfma_f32_32x32x16_bf16(a03, b13, acc[0][1], 0, 0, 0);
        acc[1][0] = __builtin_amdgcn_mfma_f32_32x32x16_bf16(a13, b03, acc[1][0], 0, 0, 0);
        acc[1][1] = __builtin_amdgcn_mfma_f32_32x32x16_bf16(a13, b13, acc[1][1], 0, 0, 0);
        __builtin_amdgcn_s_setprio(0);
        __builtin_amdgcn_s_barrier();
        bf16x8 a22 = *(const bf16x8*)&As[cb + arow2 + sk2];
        bf16x8 a23 = *(const bf16x8*)&As[cb + arow2 + sk3];
        bf16x8 a32 = *(const bf16x8*)&As[cb + arow3 + sk2];
        bf16x8 a33 = *(const bf16x8*)&As[cb + arow3 + sk3];
        asm volatile("s_waitcnt lgkmcnt(0)" ::: "memory");
        __builtin_amdgcn_s_setprio(1);
        acc[2][0] = __builtin_amdgcn_mfma_f32_32x32x16_bf16(a22, b02, acc[2][0], 0, 0, 0);
        acc[2][1] = __builtin_amdgcn_mfma_f32_32x32x16_bf16(a22, b12, acc[2][1], 0, 0, 0);
        acc[3][0] = __builtin_amdgcn_mfma_f32_32x32x16_bf16(a32, b02, acc[3][0], 0, 0, 0);
        acc[3][1] = __builtin_amdgcn_mfma_f32_32x32x16_bf16(a32, b12, acc[3][1], 0, 0, 0);
        acc[2][0] = __builtin_amdgcn_mfma_f32_32x32x16_bf16(a23, b03, acc[2][0], 0, 0, 0);
        acc[2][1] = __builtin_amdgcn_mfma_f32_32x32x16_bf16(a23, b13, acc[2][1], 0, 0, 0);
        acc[3][0] = __builtin_amdgcn_mfma_f32_32x32x16_bf16(a33, b03, acc[3][0], 0, 0, 0);
        acc[3][1] = __builtin_amdgcn_mfma_f32_32x32x16_bf16(a33, b13, acc[3][1], 0, 0, 0);
        __builtin_amdgcn_s_setprio(0);
    }

    // epilogue: bf16 C = acc + bias; ni INNERMOST so both 64B halves of each
    // 128B line are written back-to-back (no partial-line evictions).
    {
        const float bb0 = bias[n0 + wc * 64 + lc];
        const float bb1 = bias[n0 + wc * 64 + 32 + lc];
        #pragma unroll
        for (int mi = 0; mi < 4; ++mi) {
            #pragma unroll
            for (int r = 0; r < 16; ++r) {
                const int row = m0 + wr * 128 + mi * 32 + (r & 3) + 8 * (r >> 2) + 4 * q;
                ushort_t* cp = C + (size_t)row * ldc + n0 + wc * 64 + lc;
                cp[0]  = (ushort_t)f2bf(acc[mi][0][r] + bb0);
                cp[32] = (ushort_t)f2bf(acc[mi][1][r] + bb1);
            }
        }
    }
}

// ---------------------------------------------------------------------------
// 8-phase GATE GEMM (round-5 proven schedule): silu-only bf16 epilogue
// (ni innermost), square XCD regions. Runs EARLY.
// ---------------------------------------------------------------------------
__global__ __launch_bounds__(512)
void gemm_gate_p8(const ushort_t* __restrict__ A,
                  const ushort_t* __restrict__ Bt,
                  const float* __restrict__ bias,
                  ushort_t* __restrict__ C, int ldc,
                  int nkt)  // nkt >= 2
{
    __shared__ ushort_t As[2 * 8192];    // 32 KB
    __shared__ ushort_t Bs[2 * 16384];   // 64 KB

    const int tid = threadIdx.x;
    const int wid = tid >> 6, l = tid & 63;
    const int lc = l & 31, q = l >> 5;
    const int wr = wid >> 2, wc = wid & 3;
    int bx, by; xcd_map_gate(bx, by);
    const int m0 = by * 128, n0 = bx * 256;

    const int sra = tid >> 3;
    const int spa = (tid & 7) ^ (sra & 7);
    const ushort_t* gA = A + (size_t)(m0 + sra) * 1024 + spa * 8;
    const int srb = tid >> 2;
    const int spb = (tid & 3) ^ ((srb >> 1) & 3);
    const ushort_t* gB = Bt + (size_t)(n0 + srb) * 1024 + spb * 8;
    const int da = tid * 8;

    int arow0 = (wr * 64 +  0 + lc) * 64;
    int arow1 = (wr * 64 + 32 + lc) * 64;
    int sk0 = ((0 * 2 + q) ^ (lc & 7)) * 8;
    int sk1 = ((1 * 2 + q) ^ (lc & 7)) * 8;
    int sk2 = ((2 * 2 + q) ^ (lc & 7)) * 8;
    int sk3 = ((3 * 2 + q) ^ (lc & 7)) * 8;
    int brow0 = (wc * 64 +  0 + lc) * 32;
    int brow1 = (wc * 64 + 32 + lc) * 32;
    int tk0 = ((0 + q) ^ ((lc >> 1) & 3)) * 8;
    int tk1 = ((2 + q) ^ ((lc >> 1) & 3)) * 8;
    int tk2 = 8192 + ((0 + q) ^ ((lc >> 1) & 3)) * 8;
    int tk3 = 8192 + ((2 + q) ^ ((lc >> 1) & 3)) * 8;

    f32x16 acc[2][2];
    #pragma unroll
    for (int mi = 0; mi < 2; ++mi)
        #pragma unroll
        for (int ni = 0; ni < 2; ++ni)
            #pragma unroll
            for (int e = 0; e < 16; ++e) acc[mi][ni][e] = 0.0f;

    async_copy16(&As[da],          gA);
    async_copy16(&As[4096 + da],   gA + 65536);
    async_copy16(&Bs[da],          gB);
    async_copy16(&Bs[4096 + da],   gB + 131072);
    async_copy16(&Bs[8192 + da],   gB + 32);
    async_copy16(&Bs[12288 + da],  gB + 131072 + 32);
    gA += 64; gB += 64;
    asm volatile("s_waitcnt vmcnt(0)" ::: "memory");
    __builtin_amdgcn_s_barrier();

    int cur = 0;
    for (int t = 0; t < nkt - 1; ++t) {
        const int ca = cur * 8192,  na = 8192 - ca;
        const int cb = cur * 16384, nb = 16384 - cb;
        // ---- PH0: ks{0,1} ----
        bf16x8 a00 = *(const bf16x8*)&As[ca + arow0 + sk0];
        bf16x8 a01 = *(const bf16x8*)&As[ca + arow0 + sk1];
        bf16x8 a10 = *(const bf16x8*)&As[ca + arow1 + sk0];
        bf16x8 a11 = *(const bf16x8*)&As[ca + arow1 + sk1];
        bf16x8 b00 = *(const bf16x8*)&Bs[cb + brow0 + tk0];
        bf16x8 b01 = *(const bf16x8*)&Bs[cb + brow0 + tk1];
        bf16x8 b10 = *(const bf16x8*)&Bs[cb + brow1 + tk0];
        bf16x8 b11 = *(const bf16x8*)&Bs[cb + brow1 + tk1];
        async_copy16(&As[na + da],        gA);
        async_copy16(&As[na + 4096 + da], gA + 65536);
        async_copy16(&Bs[nb + da],        gB);
        async_copy16(&Bs[nb + 4096 + da], gB + 131072);
        __builtin_amdgcn_s_barrier();
        asm volatile("s_waitcnt lgkmcnt(0)" ::: "memory");
        __builtin_amdgcn_s_setprio(1);
        acc[0][0] = __builtin_amdgcn_mfma_f32_32x32x16_bf16(a00, b00, acc[0][0], 0, 0, 0);
        acc[0][1] = __builtin_amdgcn_mfma_f32_32x32x16_bf16(a00, b10, acc[0][1], 0, 0, 0);
        acc[1][0] = __builtin_amdgcn_mfma_f32_32x32x16_bf16(a10, b00, acc[1][0], 0, 0, 0);
        acc[1][1] = __builtin_amdgcn_mfma_f32_32x32x16_bf16(a10, b10, acc[1][1], 0, 0, 0);
        acc[0][0] = __builtin_amdgcn_mfma_f32_32x32x16_bf16(a01, b01, acc[0][0], 0, 0, 0);
        acc[0][1] = __builtin_amdgcn_mfma_f32_32x32x16_bf16(a01, b11, acc[0][1], 0, 0, 0);
        acc[1][0] = __builtin_amdgcn_mfma_f32_32x32x16_bf16(a11, b01, acc[1][0], 0, 0, 0);
        acc[1][1] = __builtin_amdgcn_mfma_f32_32x32x16_bf16(a11, b11, acc[1][1], 0, 0, 0);
        __builtin_amdgcn_s_setprio(0);
        asm volatile("s_waitcnt vmcnt(4)" ::: "memory");
        __builtin_amdgcn_s_barrier();
        // ---- PH1: ks{2,3} ----
        bf16x8 a02 = *(const bf16x8*)&As[ca + arow0 + sk2];
        bf16x8 a03 = *(const bf16x8*)&As[ca + arow0 + sk3];
        bf16x8 a12 = *(const bf16x8*)&As[ca + arow1 + sk2];
        bf16x8 a13 = *(const bf16x8*)&As[ca + arow1 + sk3];
        bf16x8 b02 = *(const bf16x8*)&Bs[cb + brow0 + tk2];
        bf16x8 b03 = *(const bf16x8*)&Bs[cb + brow0 + tk3];
        bf16x8 b12 = *(const bf16x8*)&Bs[cb + brow1 + tk2];
        bf16x8 b13 = *(const bf16x8*)&Bs[cb + brow1 + tk3];
        async_copy16(&Bs[nb + 8192 + da],  gB + 32);
        async_copy16(&Bs[nb + 12288 + da], gB + 131072 + 32);
        gA += 64; gB += 64;
        __builtin_amdgcn_s_barrier();
        asm volatile("s_waitcnt lgkmcnt(0)" ::: "memory");
        __builtin_amdgcn_s_setprio(1);
        acc[0][0] = __builtin_amdgcn_mfma_f32_32x32x16_bf16(a02, b02, acc[0][0], 0, 0, 0);
        acc[0][1] = __builtin_amdgcn_mfma_f32_32x32x16_bf16(a02, b12, acc[0][1], 0, 0, 0);
        acc[1][0] = __builtin_amdgcn_mfma_f32_32x32x16_bf16(a12, b02, acc[1][0], 0, 0, 0);
        acc[1][1] = __builtin_amdgcn_mfma_f32_32x32x16_bf16(a12, b12, acc[1][1], 0, 0, 0);
        acc[0][0] = __builtin_amdgcn_mfma_f32_32x32x16_bf16(a03, b03, acc[0][0], 0, 0, 0);
        acc[0][1] = __builtin_amdgcn_mfma_f32_32x32x16_bf16(a03, b13, acc[0][1], 0, 0, 0);
        acc[1][0] = __builtin_amdgcn_mfma_f32_32x32x16_bf16(a13, b03, acc[1][0], 0, 0, 0);
        acc[1][1] = __builtin_amdgcn_mfma_f32_32x32x16_bf16(a13, b13, acc[1][1], 0, 0, 0);
        __builtin_amdgcn_s_setprio(0);
        asm volatile("s_waitcnt vmcnt(2)" ::: "memory");
        __builtin_amdgcn_s_barrier();
        cur ^= 1;
    }

    {   // tail tile
        const int ca = cur * 8192;
        const int cb = cur * 16384;
        bf16x8 a00 = *(const bf16x8*)&As[ca + arow0 + sk0];
        bf16x8 a01 = *(const bf16x8*)&As[ca + arow0 + sk1];
        bf16x8 a10 = *(const bf16x8*)&As[ca + arow1 + sk0];
        bf16x8 a11 = *(const bf16x8*)&As[ca + arow1 + sk1];
        bf16x8 b00 = *(const bf16x8*)&Bs[cb + brow0 + tk0];
        bf16x8 b01 = *(const bf16x8*)&Bs[cb + brow0 + tk1];
        bf16x8 b10 = *(const bf16x8*)&Bs[cb + brow1 + tk0];
        bf16x8 b11 = *(const bf16x8*)&Bs[cb + brow1 + tk1];
        __builtin_amdgcn_s_barrier();
        asm volatile("s_waitcnt lgkmcnt(0)" ::: "memory");
        __builtin_amdgcn_s_setprio(1);
        acc[0][0] = __builtin_amdgcn_mfma_f32_32x32x16_bf16(a00, b00, acc[0][0], 0, 0, 0);
        acc[0][1] = __builtin_amdgcn_mfma_f32_32x32x16_bf16(a00, b10, acc[0][1], 0, 0, 0);
        acc[1][0] = __builtin_amdgcn_mfma_f32_32x32x16_bf16(a10, b00, acc[1][0], 0, 0, 0);
        acc[1][1] = __builtin_amdgcn_mfma_f32_32x32x16_bf16(a10, b10, acc[1][1], 0, 0, 0);
        acc[0][0] = __builtin_amdgcn_mfma_f32_32x32x16_bf16(a01, b01, acc[0][0], 0, 0, 0);
        acc[0][1] = __builtin_amdgcn_mfma_f32_32x32x16_bf16(a01, b11, acc[0][1], 0, 0, 0);
        acc[1][0] = __builtin_amdgcn_mfma_f32_32x32x16_bf16(a11, b01, acc[1][0], 0, 0, 0);
        acc[1][1] = __builtin_amdgcn_mfma_f32_32x32x16_bf16(a11, b11, acc[1][1], 0, 0, 0);
        __builtin_amdgcn_s_setprio(0);
        asm volatile("s_waitcnt vmcnt(0)" ::: "memory");
        __builtin_amdgcn_s_barrier();
        bf16x8 a02 = *(const bf16x8*)&As[ca + arow0 + sk2];
        bf16x8 a03 = *(const bf16x8*)&As[ca + arow0 + sk3];
        bf16x8 a12 = *(const bf16x8*)&As[ca + arow1 + sk2];
        bf16x8 a13 = *(const bf16x8*)&As[ca + arow1 + sk3];
        bf16x8 b02 = *(const bf16x8*)&Bs[cb + brow0 + tk2];
        bf16x8 b03 = *(const bf16x8*)&Bs[cb + brow0 + tk3];
        bf16x8 b12 = *(const bf16x8*)&Bs[cb + brow1 + tk2];
        bf16x8 b13 = *(const bf16x8*)&Bs[cb + brow1 + tk3];
        asm volatile("s_waitcnt lgkmcnt(0)" ::: "memory");
        __builtin_amdgcn_s_setprio(1);
        acc[0][0] = __builtin_amdgcn_mfma_f32_32x32x16_bf16(a02, b02, acc[0][0], 0, 0, 0);
        acc[0][1] = __builtin_amdgcn_mfma_f32_32x32x16_bf16(a02, b12, acc[0][1], 0, 0, 0);
        acc[1][0] = __builtin_amdgcn_mfma_f32_32x32x16_bf16(a12, b02, acc[1][0], 0, 0, 0);
        acc[1][1] = __builtin_amdgcn_mfma_f32_32x32x16_bf16(a12, b12, acc[1][1], 0, 0, 0);
        acc[0][0] = __builtin_amdgcn_mfma_f32_32x32x16_bf16(a03, b03, acc[0][0], 0, 0, 0);
        acc[0][1] = __builtin_amdgcn_mfma_f32_32x32x16_bf16(a03, b13, acc[0][1], 0, 0, 0);
        acc[1][0] = __builtin_amdgcn_mfma_f32_32x32x16_bf16(a13, b03, acc[1][0], 0, 0, 0);
        acc[1][1] = __builtin_amdgcn_mfma_f32_32x32x16_bf16(a13, b13, acc[1][1], 0, 0, 0);
        __builtin_amdgcn_s_setprio(0);
    }

    // epilogue: bf16 gate_raw = silu(acc + bias); ni innermost.
    {
        const float bb0 = bias[n0 + wc * 64 + lc];
        const float bb1 = bias[n0 + wc * 64 + 32 + lc];
        #pragma unroll
        for (int mi = 0; mi < 2; ++mi) {
            #pragma unroll
            for (int r = 0; r < 16; ++r) {
                const int row = m0 + wr * 64 + mi * 32 + (r & 3) + 8 * (r >> 2) + 4 * q;
                ushort_t* cp = C + (size_t)row * ldc + n0 + wc * 64 + lc;
                float v0 = acc[mi][0][r] + bb0;
                float v1 = acc[mi][1][r] + bb1;
                cp[0]  = (ushort_t)f2bf(v0 / (1.0f + expf(-v0)));
                cp[32] = (ushort_t)f2bf(v1 / (1.0f + expf(-v1)));
            }
        }
    }
}

// ---------------------------------------------------------------------------
// TM=64 GEMM (proj: 512 blocks, 2/CU). fp32 out + bias[col].
// Triple-buffered, depth-2 prefetch, counted vmcnt; simple XCD swizzle.
// ---------------------------------------------------------------------------
__global__ __launch_bounds__(256)
void gemm_tm64(const ushort_t* __restrict__ A, int lda,
               const ushort_t* __restrict__ Bt, int ldb,
               const float* __restrict__ bias,
               float* __restrict__ C, int ldc, int nkt)  // nkt >= 3
{
    __shared__ ushort_t As[3 * 64 * 32];
    __shared__ ushort_t Bs[3 * 128 * 32];

    const int tid = threadIdx.x;
    const int w  = tid >> 6, l = tid & 63;
    const int lc = l & 31, q = l >> 5;
    const int wr = w >> 1, wc = w & 1;
    int bx, by; xcd_tile(bx, by);
    const int m0 = by * 64, n0 = bx * 128;

    const int rA = tid >> 2,          kcA = (tid & 3) ^ ((rA >> 1) & 3);
    const int rB1 = (256 + tid) >> 2, kcB1 = (tid & 3) ^ ((rB1 >> 1) & 3);
    const ushort_t* gA  = A  + (size_t)(m0 + rA)  * lda + kcA  * 8;
    const ushort_t* gB0 = Bt + (size_t)(n0 + rA)  * ldb + kcA  * 8;
    const ushort_t* gB1 = Bt + (size_t)(n0 + rB1) * ldb + kcB1 * 8;
    const int sA  = w * 512;
    const int sB0 = w * 512;
    const int sB1 = 2048 + w * 512;

    const int sl = (lc >> 1) & 3;
    int aoff[2], boff[2][2];
    #pragma unroll
    for (int ks = 0; ks < 2; ++ks) {
        const int kk = ks * 2 + q;
        const int mrow = wr * 32 + lc;
        aoff[ks] = (mrow * 4 + (kk ^ sl)) * 8;
        #pragma unroll
        for (int ni = 0; ni < 2; ++ni) {
            const int nrow = wc * 64 + ni * 32 + lc;
            boff[ni][ks] = (nrow * 4 + (kk ^ sl)) * 8;
        }
    }

    f32x16 acc[2];
    #pragma unroll
    for (int ni = 0; ni < 2; ++ni)
        #pragma unroll
        for (int e = 0; e < 16; ++e) acc[ni][e] = 0.0f;

    auto stage = [&](int ab, int bb) {
        async_copy16(&As[ab + sA], gA);
        async_copy16(&Bs[bb + sB0], gB0); async_copy16(&Bs[bb + sB1], gB1);
        gA += 32; gB0 += 32; gB1 += 32;
    };
    auto compute = [&](int ab, int bb) {
        bf16x8 a[2], b[2][2];
        #pragma unroll
        for (int ks = 0; ks < 2; ++ks) {
            a[ks] = *(const bf16x8*)&As[ab + aoff[ks]];
            b[0][ks] = *(const bf16x8*)&Bs[bb + boff[0][ks]];
            b[1][ks] = *(const bf16x8*)&Bs[bb + boff[1][ks]];
        }
        #pragma unroll
        for (int ks = 0; ks < 2; ++ks)
            #pragma unroll
            for (int ni = 0; ni < 2; ++ni)
                acc[ni] = __builtin_amdgcn_mfma_f32_32x32x16_bf16(
                    a[ks], b[ni][ks], acc[ni], 0, 0, 0);
    };

    stage(0, 0); stage(2048, 4096);
    int as_ = 4096, bs_ = 8192;
    int ac_ = 0,    bc_ = 0;
    for (int kt = 0; kt < nkt - 2; ++kt) {
        asm volatile("s_waitcnt vmcnt(3)" ::: "memory");
        __builtin_amdgcn_s_barrier();
        stage(as_, bs_);
        compute(ac_, bc_);
        as_ = ac_; bs_ = bc_;
        ac_ = (ac_ == 4096) ? 0 : ac_ + 2048;
        bc_ = (bc_ == 8192) ? 0 : bc_ + 4096;
    }
    asm volatile("s_waitcnt vmcnt(3)" ::: "memory");
    __builtin_amdgcn_s_barrier();
    compute(ac_, bc_);
    ac_ = (ac_ == 4096) ? 0 : ac_ + 2048;
    bc_ = (bc_ == 8192) ? 0 : bc_ + 4096;
    asm volatile("s_waitcnt vmcnt(0)" ::: "memory");
    __builtin_amdgcn_s_barrier();
    compute(ac_, bc_);

    #pragma unroll
    for (int ni = 0; ni < 2; ++ni) {
        const int col = n0 + wc * 64 + ni * 32 + lc;
        const float bb = bias[col];
        #pragma unroll
        for (int r = 0; r < 16; ++r) {
            const int row = m0 + wr * 32 + (r & 3) + 8 * (r >> 2) + 4 * q;
            C[(size_t)row * ldc + col] = acc[ni][r] + bb;
        }
    }
}

// ---------------------------------------------------------------------------
// q/k prep: reads bf16 qkv [row][4096], xpos + gamma^{+-(t&63)} pre-scale,
// bf16 head-major [bh][T][128]
// ---------------------------------------------------------------------------
__global__ __launch_bounds__(256)
void qk_prep(const ushort_t* __restrict__ qkvb,
             ushort_t* __restrict__ qh, ushort_t* __restrict__ kh)
{
    const int row = blockIdx.x;
    const int t = threadIdx.x;
    const int b = row >> 11, trow = row & (T_SEQ - 1);
    const bool isK = t >= 128;
    const int col0 = (t & 127) * 8;
    const int h = col0 >> 7, d = col0 & 127;

    float ld, gamma;
    decay_params(h, ld, gamma);
    const float gsc = __expf(isK ? -ld * (float)(trow & 63) : ld * (float)(trow & 63));

    const ushort_t* src = qkvb + (size_t)row * 4096 + (isK ? E_DIM : 0) + col0;
    bf16x8 xv8 = *(const bf16x8*)src;
    float xv[8];
    #pragma unroll
    for (int p = 0; p < 8; ++p) xv[p] = bf2f((ushort_t)xv8[p]);

    const float tf = (float)trow * (1.0f / 512.0f);
    bf16x8 o;
    #pragma unroll
    for (int pi = 0; pi < 4; ++pi) {
        const int ip = col0 / 2 + pi;
        float sv = (2.0f * (float)ip + 409.6f) * (1.0f / 1433.6f);
        float e = __logf(sv) * tf;
        if (isK) e = -e;
        float sc = __expf(e);
        float invf = __expf((float)ip * -0.017988946038999563f);  // -ln(1e4)/512
        float sn, cs;
        sincosf((float)trow * invf, &sn, &cs);
        float c = cs * sc * gsc, s = sn * sc * gsc;
        float a = xv[2 * pi], bb = xv[2 * pi + 1];
        o[2 * pi]     = f2bf(a * c - bb * s);
        o[2 * pi + 1] = f2bf(bb * c + a * s);
    }
    ushort_t* dst = (isK ? kh : qh) + ((size_t)(b * 8 + h) * T_SEQ + trow) * 128 + d;
    *(bf16x8*)dst = o;
}

// ---------------------------------------------------------------------------
// V transpose: bf16 v-section of qkv -> vt [bh][256][T] bf16 (pure move)
// ---------------------------------------------------------------------------
__global__ __launch_bounds__(256)
void v_transpose(const ushort_t* __restrict__ qkvb, ushort_t* __restrict__ vt)
{
    __shared__ ushort_t tile[32][40];
    const int j0 = blockIdx.x * 32;
    const int zz = blockIdx.y;
    const int bh = zz >> 3, v0 = (zz & 7) * 32;
    const int b = bh >> 3, h = bh & 7;
    const int t = threadIdx.x;
    const int r = t >> 3, c = (t & 7) * 4;

    *(u16x4*)&tile[r][c] = *(const u16x4*)(qkvb + (size_t)(b * T_SEQ + j0 + r) * 4096
                                           + 2 * E_DIM + h * DV + v0 + c);
    __syncthreads();
    u16x4 o;
    o[0] = tile[c][r];
    o[1] = tile[c + 1][r];
    o[2] = tile[c + 2][r];
    o[3] = tile[c + 3][r];
    *(u16x4*)&vt[((size_t)bh * 256 + v0 + r) * T_SEQ + j0 + c] = o;
}

// ---------------------------------------------------------------------------
// kt2 = gamma^63 * kh^T per head: [bh][T][128] -> [bh][128][T]
// ---------------------------------------------------------------------------
__global__ __launch_bounds__(256)
void kt2_kernel(const ushort_t* __restrict__ kh, ushort_t* __restrict__ kt2)
{
    __shared__ ushort_t tile[32][40];
    const int j0 = blockIdx.x * 32;
    const int zz = blockIdx.y;
    const int bh = zz >> 2, k0 = (zz & 3) * 32;
    const int t = threadIdx.x;
    const int r = t >> 3, c = (t & 7) * 4;
    float ld, gamma; decay_params(bh & 7, ld, gamma);
    const float g63 = expf(ld * 63.0f);
    *(u16x4*)&tile[r][c] = *(const u16x4*)&kh[((size_t)bh * T_SEQ + j0 + r) * 128 + k0 + c];
    __syncthreads();
    u16x4 o;
    o[0] = (ushort_t)f2bf(bf2f(tile[c][r])     * g63);
    o[1] = (ushort_t)f2bf(bf2f(tile[c + 1][r]) * g63);
    o[2] = (ushort_t)f2bf(bf2f(tile[c + 2][r]) * g63);
    o[3] = (ushort_t)f2bf(bf2f(tile[c + 3][r]) * g63);
    *(u16x4*)&kt2[((size_t)bh * 128 + k0 + r) * T_SEQ + j0 + c] = o;
}

// ---------------------------------------------------------------------------
// Phase A: A_c[v][k] = sum_{j in chunk} vt[v][j] * kt2[k][j]  (bf16)
// ---------------------------------------------------------------------------
__global__ __launch_bounds__(256)
void chunk_kv(const ushort_t* __restrict__ vt, const ushort_t* __restrict__ kt2,
              ushort_t* __restrict__ Abuf)
{
    const int c = blockIdx.x;
    const int bh = blockIdx.y;
    const int tid = threadIdx.x;
    const int w = tid >> 6, l = tid & 63, lc = l & 31, q = l >> 5;
    const int j0 = c * 64;

    f32x16 acc[2][4];
    #pragma unroll
    for (int mi = 0; mi < 2; ++mi)
        #pragma unroll
        for (int ni = 0; ni < 4; ++ni)
            #pragma unroll
            for (int e = 0; e < 16; ++e) acc[mi][ni][e] = 0.0f;

    #pragma unroll
    for (int ks = 0; ks < 4; ++ks) {
        bf16x8 a[2], bfr[4];
        #pragma unroll
        for (int mi = 0; mi < 2; ++mi)
            a[mi] = *(const bf16x8*)(vt + ((size_t)bh * 256 + w * 64 + mi * 32 + lc) * T_SEQ
                                     + j0 + ks * 16 + q * 8);
        #pragma unroll
        for (int ni = 0; ni < 4; ++ni)
            bfr[ni] = *(const bf16x8*)(kt2 + ((size_t)bh * 128 + ni * 32 + lc) * T_SEQ
                                       + j0 + ks * 16 + q * 8);
        #pragma unroll
        for (int mi = 0; mi < 2; ++mi)
            #pragma unroll
            for (int ni = 0; ni < 4; ++ni)
                acc[mi][ni] = __builtin_amdgcn_mfma_f32_32x32x16_bf16(
                    a[mi], bfr[ni], acc[mi][ni], 0, 0, 0);
    }

    ushort_t* ab = Abuf + (size_t)(bh * 32 + c) * 256 * 128;
    #pragma unroll
    for (int mi = 0; mi < 2; ++mi)
        #pragma unroll
        for (int ni = 0; ni < 4; ++ni)
            #pragma unroll
            for (int r = 0; r < 16; ++r) {
                const int v = w * 64 + mi * 32 + (r & 3) + 8 * (r >> 2) + 4 * q;
                const int k = ni * 32 + lc;
                ab[(size_t)v * 128 + k] = (ushort_t)f2bf(acc[mi][ni][r]);
            }
}

// ---------------------------------------------------------------------------
// Phase B: IN-PLACE scan over chunks (St may alias Abuf: Abuf[off] is read
// BEFORE St[off] is written).  St[c] = gamma * S_c, S_{c+1} = g64*S_c + A_c.
// Final state -> curr_kv (fp32).
// ---------------------------------------------------------------------------
__global__ __launch_bounds__(256)
void scan_state(const ushort_t* __restrict__ Abuf, ushort_t* __restrict__ St,
                float* __restrict__ ckv)
{
    const int blk = blockIdx.x;
    const int bh = blk >> 7, sub = blk & 127;
    const int tid = threadIdx.x;
    const int v = sub * 2 + (tid >> 7), k = tid & 127;

    float ld, gamma;
    decay_params(bh & 7, ld, gamma);
    const float g64 = expf(ld * 64.0f);

    const size_t base = ((size_t)bh * 32 * 256 + v) * 128 + k;
    const size_t cstr = 256 * 128;
    float s = 0.0f;
    for (int c = 0; c < 32; ++c) {
        const size_t off = base + (size_t)c * cstr;
        const float a = bf2f(Abuf[off]);     // read BEFORE the aliased write
        St[off] = (ushort_t)f2bf(gamma * s);
        s = g64 * s + a;
    }
    const float inv_scale = rsqrtf((1.0f - expf(ld * (float)T_SEQ)) / (1.0f - gamma));
    ckv[((size_t)bh * 128 + k) * 256 + v] = s * inv_scale;
}

// ---------------------------------------------------------------------------
// Phase C: per-i-tile output, single-wave blocks, fused groupnorm AND gating
// multiply (gate_raw = silu(hs@w_g+b_g) precomputed) -> bf16 gated.
// ---------------------------------------------------------------------------
__global__ __launch_bounds__(64)
void retention_chunk(const ushort_t* __restrict__ qh,
                     const ushort_t* __restrict__ kh,
                     const ushort_t* __restrict__ vt,
                     const ushort_t* __restrict__ St,
                     const ushort_t* __restrict__ grw,
                     ushort_t* __restrict__ gated)
{
    const int it = blockIdx.x;
    const int bh = blockIdx.y;
    const int b = bh >> 3, h = bh & 7;
    const int c = it >> 1, w = it & 1;
    const int l = threadIdx.x, lc = l & 31, q = l >> 5;
    const int i0 = it * 32;
    const size_t bhT = (size_t)bh * T_SEQ;

    float ld, gamma;
    decay_params(h, ld, gamma);

    bf16x8 qf[8];
    {
        const ushort_t* qp = qh + (bhT + i0 + lc) * 128 + q * 8;
        #pragma unroll
        for (int c8 = 0; c8 < 8; ++c8)
            qf[c8] = *(const bf16x8*)(qp + c8 * 16);
    }

    f32x16 acc[8];
    #pragma unroll
    for (int vg = 0; vg < 8; ++vg)
        #pragma unroll
        for (int e = 0; e < 16; ++e) acc[vg][e] = 0.0f;

    if (c > 0) {
        const ushort_t* sp = St + ((size_t)(bh * 32 + c) * 256 + lc) * 128 + q * 8;
        #pragma unroll
        for (int vg = 0; vg < 8; ++vg) {
            const ushort_t* spv = sp + (size_t)vg * 32 * 128;
            #pragma unroll
            for (int ks = 0; ks < 8; ++ks) {
                bf16x8 sb = *(const bf16x8*)(spv + ks * 16);
                acc[vg] = __builtin_amdgcn_mfma_f32_32x32x16_bf16(
                    qf[ks], sb, acc[vg], 0, 0, 0);
            }
        }
    }

    for (int jt2 = 0; jt2 <= w; ++jt2) {
        const int j0 = c * 64 + jt2 * 32;

        f32x16 s;
        #pragma unroll
        for (int e = 0; e < 16; ++e) s[e] = 0.0f;
        const ushort_t* kp = kh + (bhT + j0 + lc) * 128 + q * 8;
        #pragma unroll
        for (int c8 = 0; c8 < 8; ++c8) {
            bf16x8 ka = *(const bf16x8*)(kp + c8 * 16);
            s = __builtin_amdgcn_mfma_f32_32x32x16_bf16(ka, qf[c8], s, 0, 0, 0);
        }

        float sv[16];
        #pragma unroll
        for (int r = 0; r < 16; ++r) {
            float val = s[r];
            if (jt2 == w) {
                int jr_ = (r & 3) + 8 * (r >> 2) + 4 * q;
                val = (jr_ <= lc) ? val : 0.0f;
            }
            sv[r] = val;
        }

        bf16x8 pa0, pa1;
        #pragma unroll
        for (int e = 0; e < 4; ++e) {
            float t1 = __shfl_xor(sv[e + 4], 32);
            float t0 = __shfl_xor(sv[e], 32);
            pa0[e]     = f2bf(q ? t1 : sv[e]);
            pa0[e + 4] = f2bf(q ? sv[e + 4] : t0);
            float t3 = __shfl_xor(sv[e + 12], 32);
            float t2 = __shfl_xor(sv[e + 8], 32);
            pa1[e]     = f2bf(q ? t3 : sv[e + 8]);
            pa1[e + 4] = f2bf(q ? sv[e + 12] : t2);
        }

        #pragma unroll
        for (int vg = 0; vg < 8; ++vg) {
            const ushort_t* vp = vt + ((size_t)bh * 256 + vg * 32 + lc) * T_SEQ + j0 + q * 8;
            bf16x8 vb0 = *(const bf16x8*)vp;
            bf16x8 vb1 = *(const bf16x8*)(vp + 16);
            acc[vg] = __builtin_amdgcn_mfma_f32_32x32x16_bf16(pa0, vb0, acc[vg], 0, 0, 0);
            acc[vg] = __builtin_amdgcn_mfma_f32_32x32x16_bf16(pa1, vb1, acc[vg], 0, 0, 0);
        }
    }

    #pragma unroll
    for (int r = 0; r < 16; ++r) {
        const int il = (r & 3) + 8 * (r >> 2) + 4 * q;
        const int i  = i0 + il;
        float denom = (1.0f - expf(ld * (float)(i + 1))) / (1.0f - gamma);
        float fs = 0.08838834764831845f * rsqrtf(denom);
        float vals[8];
        float a1 = 0.0f, a2 = 0.0f;
        #pragma unroll
        for (int vg = 0; vg < 8; ++vg) {
            float x = acc[vg][r] * fs;
            vals[vg] = x;
            a1 += x; a2 += x * x;
        }
        a1 += __shfl_xor(a1, 1);  a2 += __shfl_xor(a2, 1);
        a1 += __shfl_xor(a1, 2);  a2 += __shfl_xor(a2, 2);
        a1 += __shfl_xor(a1, 4);  a2 += __shfl_xor(a2, 4);
        a1 += __shfl_xor(a1, 8);  a2 += __shfl_xor(a2, 8);
        a1 += __shfl_xor(a1, 16); a2 += __shfl_xor(a2, 16);
        float mu = a1 * (1.0f / 256.0f);
        float var = a2 * (1.0f / 256.0f) - mu * mu;
        float rs = rsqrtf(var + 1e-5f);
        const size_t ob = ((size_t)(b * T_SEQ + i)) * V_DIM + h * DV + lc;
        ushort_t* op = gated + ob;
        const ushort_t* gp = grw + ob;
        #pragma unroll
        for (int vg = 0; vg < 8; ++vg) {
            float g = bf2f(gp[vg * 32]);
            op[vg * 32] = (ushort_t)f2bf((vals[vg] - mu) * rs * g);
        }
    }
}

// ---------------------------------------------------------------------------
extern "C" void kernel_launch(void* const* d_in, const int* in_sizes, int n_in,
                              void* d_out, int out_size, void* d_ws, size_t ws_size,
                              hipStream_t stream)
{
    const float* hs    = (const float*)d_in[0];
    const float* w_qkv = (const float*)d_in[1];
    const float* b_qkv = (const float*)d_in[2];
    const float* w_g   = (const float*)d_in[3];
    const float* b_g   = (const float*)d_in[4];
    const float* w_p   = (const float*)d_in[5];
    const float* b_p   = (const float*)d_in[6];
    float* out = (float*)d_out;

    const size_t MB = 1024 * 1024;
    // ws (96MB) timeline (qkv bf16, in-place scan):
    //   [0,32):  qkv_bf (qkv GEMM -> preps)  ->  Abuf (chunk_kv -> scan)
    //            -> St IN-PLACE (scan -> retention) -> wp_t@[0,4) (-> proj)
    //   [32,48): gate_raw (gate GEMM -> retention)
    //   [48,64): gated (retention -> proj)
    //   [64,72): wg_t@[64,68) (-> gate GEMM) -> qh (qk_prep -> retention)
    //   [72,88): vt (v_transpose -> retention)
    //   [88,96): wqkv_t (-> qkv GEMM) -> kh (qk_prep -> kt2/retention)
    // d_out (18MB): hs_bf@[0,8), kt2@[8,16) — dead before proj store;
    //               proj writes out@[0,16) at the END; ckv@[16,18).
    ushort_t* qkv_bf   = (ushort_t*)d_ws;
    ushort_t* Abuf     = (ushort_t*)d_ws;               // aliases qkv_bf (dead)
    ushort_t* Stbuf    = (ushort_t*)d_ws;               // IN-PLACE with Abuf
    ushort_t* wp_t     = (ushort_t*)d_ws;               // after retention
    ushort_t* gate_raw = (ushort_t*)((char*)d_ws + 32 * MB);
    ushort_t* gated_bf = (ushort_t*)((char*)d_ws + 48 * MB);
    ushort_t* wg_t     = (ushort_t*)((char*)d_ws + 64 * MB);
    ushort_t* qh       = (ushort_t*)((char*)d_ws + 64 * MB);  // after wg_t dead
    ushort_t* vt       = (ushort_t*)((char*)d_ws + 72 * MB);
    ushort_t* wqkv_t   = (ushort_t*)((char*)d_ws + 88 * MB);
    ushort_t* kh       = (ushort_t*)((char*)d_ws + 88 * MB);  // after wqkv_t dead
    ushort_t* hs_bf    = (ushort_t*)d_out;
    ushort_t* kt2      = (ushort_t*)((char*)d_out + 8 * MB);
    float*    ckv_out  = out + (size_t)BT * E_DIM;

    // 1. conversions
    f32_to_bf16_kernel<<<dim3(2048), 256, 0, stream>>>(hs, hs_bf);
    transpose_w_kernel<<<dim3(64, 32), 256, 0, stream>>>(w_g, wg_t, E_DIM, V_DIM);
    transpose_w_kernel<<<dim3(128, 32), 256, 0, stream>>>(w_qkv, wqkv_t, E_DIM, 4096);

    // 2. gate_raw = silu(hs @ w_g + b_g)  (early; no dependency on retention)
    gemm_gate_p8<<<dim3(8, 32), 512, 0, stream>>>(
        hs_bf, wg_t, b_g, gate_raw, V_DIM, E_DIM / 64);

    // 3. qkv = hs @ w_qkv + b_qkv  -> bf16
    gemm256p8<<<dim3(16, 16), 512, 0, stream>>>(
        hs_bf, wqkv_t, b_qkv, qkv_bf, 4096, E_DIM / 64);

    // 4. preps (consume bf16 qkv); qh over wg_t, kh over wqkv_t (both dead)
    qk_prep<<<dim3(BT), 256, 0, stream>>>(qkv_bf, qh, kh);
    v_transpose<<<dim3(64, 128), 256, 0, stream>>>(qkv_bf, vt);
    kt2_kernel<<<dim3(64, 64), 256, 0, stream>>>(kh, kt2);

    // 5. chunked retention: A (over dead qkv_bf) -> in-place scan -> outputs
    chunk_kv<<<dim3(32, 16), 256, 0, stream>>>(vt, kt2, Abuf);
    scan_state<<<dim3(2048), 256, 0, stream>>>(Abuf, Stbuf, ckv_out);
    retention_chunk<<<dim3(64, 16), 64, 0, stream>>>(qh, kh, vt, Stbuf, gate_raw, gated_bf);

    // 6. proj = gated @ w_p + b_p  (wp_t over dead St; out over dead hs_bf/kt2)
    transpose_w_kernel<<<dim3(32, 64), 256, 0, stream>>>(w_p, wp_t, V_DIM, E_DIM);
    gemm_tm64<<<dim3(8, 64), 256, 0, stream>>>(
        gated_bf, V_DIM, wp_t, V_DIM, b_p, out, E_DIM, V_DIM / 32);
}

// Round 9
// 297.052 us; speedup vs baseline: 1.0012x; 1.0012x over previous
//
#include <hip/hip_runtime.h>
#include <math.h>

#define BT      4096
#define T_SEQ   2048
#define E_DIM   1024
#define V_DIM   2048
#define DK      128
#define DV      256

typedef unsigned short ushort_t;
typedef __attribute__((ext_vector_type(8)))  short bf16x8;
typedef __attribute__((ext_vector_type(4)))  unsigned short u16x4;
typedef __attribute__((ext_vector_type(16))) float f32x16;

__device__ __forceinline__ void decay_params(int h, float& ld, float& gamma) {
    const float s0 = -3.4657359027997265f;  // ln(1/32)
    const float e0 = -6.2383246250395092f;  // ln(1/512)
    float lin = s0 + (e0 - s0) * ((float)h * (1.0f / 7.0f));
    gamma = 1.0f - expf(lin);
    ld = logf(gamma);
}

__device__ __forceinline__ short f2bf(float f) {
    unsigned u = __float_as_uint(f);
    unsigned r = (u + 0x7fffu + ((u >> 16) & 1u)) >> 16;
    return (short)r;
}
__device__ __forceinline__ float bf2f(ushort_t u) {
    return __uint_as_float((unsigned)u << 16);
}

__device__ __forceinline__ void async_copy16(void* lds, const void* g) {
    __builtin_amdgcn_global_load_lds(
        (const __attribute__((address_space(1))) unsigned int*)g,
        (__attribute__((address_space(3))) unsigned int*)lds, 16, 0, 0);
}

// Simple XCD swizzle (contiguous strip per XCD) — used by tm64.
__device__ __forceinline__ void xcd_tile(int& bx, int& by) {
    const int nwgx = gridDim.x;
    const int nwg  = nwgx * gridDim.y;
    int bid = blockIdx.y * nwgx + blockIdx.x;
    bid = (bid & 7) * (nwg >> 3) + (bid >> 3);
    bx = bid % nwgx;
    by = bid / nwgx;
}

// Square XCD regions for qkv grid (32,16): each XCD owns 8 n-cols x 8 m-rows
// (region = A 4MB + B 2MB). Bijective: xcd=(bx>>3)|((by>>3)<<2).
__device__ __forceinline__ void xcd_map_qkv2(int& bx, int& by) {
    int bid = blockIdx.y * 32 + blockIdx.x;
    const int xcd = bid & 7, idx = bid >> 3;            // idx in [0,64)
    bx = (xcd & 3) * 8 + (idx & 7);
    by = (xcd >> 2) * 8 + (idx >> 3);
}

// Square XCD regions for gate grid (8,32): each XCD owns 4 n-cols x 8 m-rows.
__device__ __forceinline__ void xcd_map_gate(int& bx, int& by) {
    int bid = blockIdx.y * 8 + blockIdx.x;
    const int xcd = bid & 7, idx = bid >> 3;            // idx in [0,32)
    bx = (xcd & 1) * 4 + (idx & 3);
    by = (xcd >> 1) * 8 + (idx >> 2);
}

// ---------------------------------------------------------------------------
// fp32 -> bf16 elementwise
// ---------------------------------------------------------------------------
__global__ __launch_bounds__(256)
void f32_to_bf16_kernel(const float* __restrict__ in, ushort_t* __restrict__ out)
{
    int i = (blockIdx.x * 256 + threadIdx.x) * 8;
    float4 a = *(const float4*)&in[i];
    float4 b = *(const float4*)&in[i + 4];
    bf16x8 o;
    o[0] = f2bf(a.x); o[1] = f2bf(a.y); o[2] = f2bf(a.z); o[3] = f2bf(a.w);
    o[4] = f2bf(b.x); o[5] = f2bf(b.y); o[6] = f2bf(b.z); o[7] = f2bf(b.w);
    *(bf16x8*)&out[i] = o;
}

// ---------------------------------------------------------------------------
// W[K][N] fp32 -> Wt[N][K] bf16
// ---------------------------------------------------------------------------
__global__ __launch_bounds__(256)
void transpose_w_kernel(const float* __restrict__ W, ushort_t* __restrict__ Wt,
                        int K, int N)
{
    __shared__ float tile[32][33];
    const int k0 = blockIdx.y * 32, n0 = blockIdx.x * 32;
    const int t = threadIdx.x;
    const int r = t >> 3, c = (t & 7) * 4;
    float4 v = *(const float4*)&W[(size_t)(k0 + r) * N + n0 + c];
    tile[r][c] = v.x; tile[r][c + 1] = v.y; tile[r][c + 2] = v.z; tile[r][c + 3] = v.w;
    __syncthreads();
    u16x4 o;
    o[0] = (ushort_t)f2bf(tile[c][r]);
    o[1] = (ushort_t)f2bf(tile[c + 1][r]);
    o[2] = (ushort_t)f2bf(tile[c + 2][r]);
    o[3] = (ushort_t)f2bf(tile[c + 3][r]);
    *(u16x4*)&Wt[(size_t)(n0 + r) * K + k0 + c] = o;
}

// ---------------------------------------------------------------------------
// qkv GEMM v2: BM=256, BN=128, BK=32, 256 threads (4 waves, 2Mx2N),
// per-wave 128x64 (round-3 PROVEN address math / staging swizzle / 3-buffer
// rotation / counted vmcnt(6)), with p8 phase innards (2 phases per K-tile:
// reads+stage -> barrier -> lgkmcnt(0) -> setprio -> 8 MFMA -> setprio ->
// [vmcnt(6)] -> barrier).  LDS 72KB -> 2 blocks/CU; grid 512 = 2/CU chip-wide
// so each CU hosts TWO INDEPENDENT barrier groups (m114 co-scheduling hides
// each block's convoy under the other's MFMA).  bf16 out, ni-innermost
// (one wave dirties a full 128B line back-to-back).  Square XCD map.
// Race ledger: prologue stages buf0,buf1 (12 loads) then vmcnt(6)+barrier
// proves buf0 landed; each tile's trailing vmcnt(6) (queue=12, retires
// oldest 6) proves the NEXT tile's buffer landed collectively; stage targets
// the buffer whose readers all passed the previous trailing barrier.
// ---------------------------------------------------------------------------
__global__ __launch_bounds__(256, 2)
void gemm_qkv_v2(const ushort_t* __restrict__ A,
                 const ushort_t* __restrict__ Bt,
                 const float* __restrict__ bias,
                 ushort_t* __restrict__ C, int ldc, int nkt)   // nkt >= 3
{
    __shared__ ushort_t As[3 * 8192];   // 48 KB: 3 bufs x 256r x 32k
    __shared__ ushort_t Bs[3 * 4096];   // 24 KB: 3 bufs x 128r x 32k

    const int tid = threadIdx.x;
    const int w  = tid >> 6, l = tid & 63;
    const int lc = l & 31, q = l >> 5;
    const int wr = w >> 1, wcn = w & 1;
    int bx, by; xcd_map_qkv2(bx, by);
    const int m0 = by * 256, n0 = bx * 128;

    // staging: thread covers row (j*64 + tid>>2), pre-swizzled K-slot
    const int rb = tid >> 2;
    const int kc = (tid & 3) ^ ((rb >> 1) & 3);
    const ushort_t* gA = A  + (size_t)(m0 + rb) * 1024 + kc * 8;
    const ushort_t* gB = Bt + (size_t)(n0 + rb) * 1024 + kc * 8;
    const int dst = tid * 8;               // ushort offset within a 64-row chunk

    const int sl = (lc >> 1) & 3;
    int aoff[4][2], boff[2][2];
    #pragma unroll
    for (int ks = 0; ks < 2; ++ks) {
        const int kk = ks * 2 + q;
        #pragma unroll
        for (int mi = 0; mi < 4; ++mi)
            aoff[mi][ks] = ((wr * 128 + mi * 32 + lc) * 4 + (kk ^ sl)) * 8;
        #pragma unroll
        for (int ni = 0; ni < 2; ++ni)
            boff[ni][ks] = ((wcn * 64 + ni * 32 + lc) * 4 + (kk ^ sl)) * 8;
    }

    f32x16 acc[4][2];
    #pragma unroll
    for (int mi = 0; mi < 4; ++mi)
        #pragma unroll
        for (int ni = 0; ni < 2; ++ni)
            #pragma unroll
            for (int e = 0; e < 16; ++e) acc[mi][ni][e] = 0.0f;

    auto stageA = [&](int ab) {            // 4 loads: A rows 0-255 of next tile
        async_copy16(&As[ab + 0 * 2048 + dst], gA + 0 * 65536);
        async_copy16(&As[ab + 1 * 2048 + dst], gA + 1 * 65536);
        async_copy16(&As[ab + 2 * 2048 + dst], gA + 2 * 65536);
        async_copy16(&As[ab + 3 * 2048 + dst], gA + 3 * 65536);
        gA += 32;
    };
    auto stageB = [&](int bb) {            // 2 loads: B rows 0-127
        async_copy16(&Bs[bb + 0 * 2048 + dst], gB + 0 * 65536);
        async_copy16(&Bs[bb + 1 * 2048 + dst], gB + 1 * 65536);
        gB += 32;
    };

    // prologue: stage tiles 0 and 1 (12 loads); prove buf0 before first reads
    stageA(0);     stageB(0);
    stageA(8192);  stageB(4096);
    asm volatile("s_waitcnt vmcnt(6)" ::: "memory");
    __builtin_amdgcn_s_barrier();

    int as_ = 16384, bs_ = 8192;           // next stage buffer
    int ac_ = 0,     bc_ = 0;              // compute buffer
    for (int t = 0; t < nkt - 2; ++t) {
        // ---- PH0: m-pair {0,1} + all B frags; stage next A ----
        bf16x8 b00 = *(const bf16x8*)&Bs[bc_ + boff[0][0]];
        bf16x8 b01 = *(const bf16x8*)&Bs[bc_ + boff[0][1]];
        bf16x8 b10 = *(const bf16x8*)&Bs[bc_ + boff[1][0]];
        bf16x8 b11 = *(const bf16x8*)&Bs[bc_ + boff[1][1]];
        bf16x8 a00 = *(const bf16x8*)&As[ac_ + aoff[0][0]];
        bf16x8 a01 = *(const bf16x8*)&As[ac_ + aoff[0][1]];
        bf16x8 a10 = *(const bf16x8*)&As[ac_ + aoff[1][0]];
        bf16x8 a11 = *(const bf16x8*)&As[ac_ + aoff[1][1]];
        stageA(as_);
        __builtin_amdgcn_s_barrier();
        asm volatile("s_waitcnt lgkmcnt(0)" ::: "memory");
        __builtin_amdgcn_s_setprio(1);
        acc[0][0] = __builtin_amdgcn_mfma_f32_32x32x16_bf16(a00, b00, acc[0][0], 0, 0, 0);
        acc[0][1] = __builtin_amdgcn_mfma_f32_32x32x16_bf16(a00, b10, acc[0][1], 0, 0, 0);
        acc[1][0] = __builtin_amdgcn_mfma_f32_32x32x16_bf16(a10, b00, acc[1][0], 0, 0, 0);
        acc[1][1] = __builtin_amdgcn_mfma_f32_32x32x16_bf16(a10, b10, acc[1][1], 0, 0, 0);
        acc[0][0] = __builtin_amdgcn_mfma_f32_32x32x16_bf16(a01, b01, acc[0][0], 0, 0, 0);
        acc[0][1] = __builtin_amdgcn_mfma_f32_32x32x16_bf16(a01, b11, acc[0][1], 0, 0, 0);
        acc[1][0] = __builtin_amdgcn_mfma_f32_32x32x16_bf16(a11, b01, acc[1][0], 0, 0, 0);
        acc[1][1] = __builtin_amdgcn_mfma_f32_32x32x16_bf16(a11, b11, acc[1][1], 0, 0, 0);
        __builtin_amdgcn_s_setprio(0);
        __builtin_amdgcn_s_barrier();
        // ---- PH1: m-pair {2,3} (reuse B); stage next B; counted vmcnt ----
        bf16x8 a20 = *(const bf16x8*)&As[ac_ + aoff[2][0]];
        bf16x8 a21 = *(const bf16x8*)&As[ac_ + aoff[2][1]];
        bf16x8 a30 = *(const bf16x8*)&As[ac_ + aoff[3][0]];
        bf16x8 a31 = *(const bf16x8*)&As[ac_ + aoff[3][1]];
        stageB(bs_);
        __builtin_amdgcn_s_barrier();
        asm volatile("s_waitcnt lgkmcnt(0)" ::: "memory");
        __builtin_amdgcn_s_setprio(1);
        acc[2][0] = __builtin_amdgcn_mfma_f32_32x32x16_bf16(a20, b00, acc[2][0], 0, 0, 0);
        acc[2][1] = __builtin_amdgcn_mfma_f32_32x32x16_bf16(a20, b10, acc[2][1], 0, 0, 0);
        acc[3][0] = __builtin_amdgcn_mfma_f32_32x32x16_bf16(a30, b00, acc[3][0], 0, 0, 0);
        acc[3][1] = __builtin_amdgcn_mfma_f32_32x32x16_bf16(a30, b10, acc[3][1], 0, 0, 0);
        acc[2][0] = __builtin_amdgcn_mfma_f32_32x32x16_bf16(a21, b01, acc[2][0], 0, 0, 0);
        acc[2][1] = __builtin_amdgcn_mfma_f32_32x32x16_bf16(a21, b11, acc[2][1], 0, 0, 0);
        acc[3][0] = __builtin_amdgcn_mfma_f32_32x32x16_bf16(a31, b01, acc[3][0], 0, 0, 0);
        acc[3][1] = __builtin_amdgcn_mfma_f32_32x32x16_bf16(a31, b11, acc[3][1], 0, 0, 0);
        __builtin_amdgcn_s_setprio(0);
        asm volatile("s_waitcnt vmcnt(6)" ::: "memory");
        __builtin_amdgcn_s_barrier();
        as_ = ac_; bs_ = bc_;
        ac_ = (ac_ == 16384) ? 0 : ac_ + 8192;
        bc_ = (bc_ == 8192)  ? 0 : bc_ + 4096;
    }

    // ---- tile nkt-2 (no staging; drain remaining 6 at the end) ----
    {
        bf16x8 b00 = *(const bf16x8*)&Bs[bc_ + boff[0][0]];
        bf16x8 b01 = *(const bf16x8*)&Bs[bc_ + boff[0][1]];
        bf16x8 b10 = *(const bf16x8*)&Bs[bc_ + boff[1][0]];
        bf16x8 b11 = *(const bf16x8*)&Bs[bc_ + boff[1][1]];
        #pragma unroll
        for (int mp = 0; mp < 2; ++mp) {
            bf16x8 x00 = *(const bf16x8*)&As[ac_ + aoff[mp * 2 + 0][0]];
            bf16x8 x01 = *(const bf16x8*)&As[ac_ + aoff[mp * 2 + 0][1]];
            bf16x8 x10 = *(const bf16x8*)&As[ac_ + aoff[mp * 2 + 1][0]];
            bf16x8 x11 = *(const bf16x8*)&As[ac_ + aoff[mp * 2 + 1][1]];
            asm volatile("s_waitcnt lgkmcnt(0)" ::: "memory");
            __builtin_amdgcn_s_setprio(1);
            acc[mp*2+0][0] = __builtin_amdgcn_mfma_f32_32x32x16_bf16(x00, b00, acc[mp*2+0][0], 0, 0, 0);
            acc[mp*2+0][1] = __builtin_amdgcn_mfma_f32_32x32x16_bf16(x00, b10, acc[mp*2+0][1], 0, 0, 0);
            acc[mp*2+1][0] = __builtin_amdgcn_mfma_f32_32x32x16_bf16(x10, b00, acc[mp*2+1][0], 0, 0, 0);
            acc[mp*2+1][1] = __builtin_amdgcn_mfma_f32_32x32x16_bf16(x10, b10, acc[mp*2+1][1], 0, 0, 0);
            acc[mp*2+0][0] = __builtin_amdgcn_mfma_f32_32x32x16_bf16(x01, b01, acc[mp*2+0][0], 0, 0, 0);
            acc[mp*2+0][1] = __builtin_amdgcn_mfma_f32_32x32x16_bf16(x01, b11, acc[mp*2+0][1], 0, 0, 0);
            acc[mp*2+1][0] = __builtin_amdgcn_mfma_f32_32x32x16_bf16(x11, b01, acc[mp*2+1][0], 0, 0, 0);
            acc[mp*2+1][1] = __builtin_amdgcn_mfma_f32_32x32x16_bf16(x11, b11, acc[mp*2+1][1], 0, 0, 0);
            __builtin_amdgcn_s_setprio(0);
        }
        asm volatile("s_waitcnt vmcnt(0)" ::: "memory");
        __builtin_amdgcn_s_barrier();
        ac_ = (ac_ == 16384) ? 0 : ac_ + 8192;
        bc_ = (bc_ == 8192)  ? 0 : bc_ + 4096;
    }
    // ---- final tile (all data resident; no barriers needed) ----
    {
        bf16x8 b00 = *(const bf16x8*)&Bs[bc_ + boff[0][0]];
        bf16x8 b01 = *(const bf16x8*)&Bs[bc_ + boff[0][1]];
        bf16x8 b10 = *(const bf16x8*)&Bs[bc_ + boff[1][0]];
        bf16x8 b11 = *(const bf16x8*)&Bs[bc_ + boff[1][1]];
        #pragma unroll
        for (int mi = 0; mi < 4; ++mi) {
            bf16x8 x0 = *(const bf16x8*)&As[ac_ + aoff[mi][0]];
            bf16x8 x1 = *(const bf16x8*)&As[ac_ + aoff[mi][1]];
            acc[mi][0] = __builtin_amdgcn_mfma_f32_32x32x16_bf16(x0, b00, acc[mi][0], 0, 0, 0);
            acc[mi][1] = __builtin_amdgcn_mfma_f32_32x32x16_bf16(x0, b10, acc[mi][1], 0, 0, 0);
            acc[mi][0] = __builtin_amdgcn_mfma_f32_32x32x16_bf16(x1, b01, acc[mi][0], 0, 0, 0);
            acc[mi][1] = __builtin_amdgcn_mfma_f32_32x32x16_bf16(x1, b11, acc[mi][1], 0, 0, 0);
        }
    }

    // epilogue: bf16 C = acc + bias; ni innermost (full 128B line per wave-row)
    {
        const float bb0 = bias[n0 + wcn * 64 + lc];
        const float bb1 = bias[n0 + wcn * 64 + 32 + lc];
        #pragma unroll
        for (int mi = 0; mi < 4; ++mi) {
            #pragma unroll
            for (int r = 0; r < 16; ++r) {
                const int row = m0 + wr * 128 + mi * 32 + (r & 3) + 8 * (r >> 2) + 4 * q;
                ushort_t* cp = C + (size_t)row * ldc + n0 + wcn * 64 + lc;
                cp[0]  = (ushort_t)f2bf(acc[mi][0][r] + bb0);
                cp[32] = (ushort_t)f2bf(acc[mi][1][r] + bb1);
            }
        }
    }
}

// ---------------------------------------------------------------------------
// 8-phase GATE GEMM (round-8, frozen): silu-only bf16 epilogue (ni innermost),
// square XCD regions. Runs EARLY.
// ---------------------------------------------------------------------------
__global__ __launch_bounds__(512)
void gemm_gate_p8(const ushort_t* __restrict__ A,
                  const ushort_t* __restrict__ Bt,
                  const float* __restrict__ bias,
                  ushort_t* __restrict__ C, int ldc,
                  int nkt)  // nkt >= 2
{
    __shared__ ushort_t As[2 * 8192];    // 32 KB
    __shared__ ushort_t Bs[2 * 16384];   // 64 KB

    const int tid = threadIdx.x;
    const int wid = tid >> 6, l = tid & 63;
    const int lc = l & 31, q = l >> 5;
    const int wr = wid >> 2, wc = wid & 3;
    int bx, by; xcd_map_gate(bx, by);
    const int m0 = by * 128, n0 = bx * 256;

    const int sra = tid >> 3;
    const int spa = (tid & 7) ^ (sra & 7);
    const ushort_t* gA = A + (size_t)(m0 + sra) * 1024 + spa * 8;
    const int srb = tid >> 2;
    const int spb = (tid & 3) ^ ((srb >> 1) & 3);
    const ushort_t* gB = Bt + (size_t)(n0 + srb) * 1024 + spb * 8;
    const int da = tid * 8;

    int arow0 = (wr * 64 +  0 + lc) * 64;
    int arow1 = (wr * 64 + 32 + lc) * 64;
    int sk0 = ((0 * 2 + q) ^ (lc & 7)) * 8;
    int sk1 = ((1 * 2 + q) ^ (lc & 7)) * 8;
    int sk2 = ((2 * 2 + q) ^ (lc & 7)) * 8;
    int sk3 = ((3 * 2 + q) ^ (lc & 7)) * 8;
    int brow0 = (wc * 64 +  0 + lc) * 32;
    int brow1 = (wc * 64 + 32 + lc) * 32;
    int tk0 = ((0 + q) ^ ((lc >> 1) & 3)) * 8;
    int tk1 = ((2 + q) ^ ((lc >> 1) & 3)) * 8;
    int tk2 = 8192 + ((0 + q) ^ ((lc >> 1) & 3)) * 8;
    int tk3 = 8192 + ((2 + q) ^ ((lc >> 1) & 3)) * 8;

    f32x16 acc[2][2];
    #pragma unroll
    for (int mi = 0; mi < 2; ++mi)
        #pragma unroll
        for (int ni = 0; ni < 2; ++ni)
            #pragma unroll
            for (int e = 0; e < 16; ++e) acc[mi][ni][e] = 0.0f;

    async_copy16(&As[da],          gA);
    async_copy16(&As[4096 + da],   gA + 65536);
    async_copy16(&Bs[da],          gB);
    async_copy16(&Bs[4096 + da],   gB + 131072);
    async_copy16(&Bs[8192 + da],   gB + 32);
    async_copy16(&Bs[12288 + da],  gB + 131072 + 32);
    gA += 64; gB += 64;
    asm volatile("s_waitcnt vmcnt(0)" ::: "memory");
    __builtin_amdgcn_s_barrier();

    int cur = 0;
    for (int t = 0; t < nkt - 1; ++t) {
        const int ca = cur * 8192,  na = 8192 - ca;
        const int cb = cur * 16384, nb = 16384 - cb;
        // ---- PH0: ks{0,1} ----
        bf16x8 a00 = *(const bf16x8*)&As[ca + arow0 + sk0];
        bf16x8 a01 = *(const bf16x8*)&As[ca + arow0 + sk1];
        bf16x8 a10 = *(const bf16x8*)&As[ca + arow1 + sk0];
        bf16x8 a11 = *(const bf16x8*)&As[ca + arow1 + sk1];
        bf16x8 b00 = *(const bf16x8*)&Bs[cb + brow0 + tk0];
        bf16x8 b01 = *(const bf16x8*)&Bs[cb + brow0 + tk1];
        bf16x8 b10 = *(const bf16x8*)&Bs[cb + brow1 + tk0];
        bf16x8 b11 = *(const bf16x8*)&Bs[cb + brow1 + tk1];
        async_copy16(&As[na + da],        gA);
        async_copy16(&As[na + 4096 + da], gA + 65536);
        async_copy16(&Bs[nb + da],        gB);
        async_copy16(&Bs[nb + 4096 + da], gB + 131072);
        __builtin_amdgcn_s_barrier();
        asm volatile("s_waitcnt lgkmcnt(0)" ::: "memory");
        __builtin_amdgcn_s_setprio(1);
        acc[0][0] = __builtin_amdgcn_mfma_f32_32x32x16_bf16(a00, b00, acc[0][0], 0, 0, 0);
        acc[0][1] = __builtin_amdgcn_mfma_f32_32x32x16_bf16(a00, b10, acc[0][1], 0, 0, 0);
        acc[1][0] = __builtin_amdgcn_mfma_f32_32x32x16_bf16(a10, b00, acc[1][0], 0, 0, 0);
        acc[1][1] = __builtin_amdgcn_mfma_f32_32x32x16_bf16(a10, b10, acc[1][1], 0, 0, 0);
        acc[0][0] = __builtin_amdgcn_mfma_f32_32x32x16_bf16(a01, b01, acc[0][0], 0, 0, 0);
        acc[0][1] = __builtin_amdgcn_mfma_f32_32x32x16_bf16(a01, b11, acc[0][1], 0, 0, 0);
        acc[1][0] = __builtin_amdgcn_mfma_f32_32x32x16_bf16(a11, b01, acc[1][0], 0, 0, 0);
        acc[1][1] = __builtin_amdgcn_mfma_f32_32x32x16_bf16(a11, b11, acc[1][1], 0, 0, 0);
        __builtin_amdgcn_s_setprio(0);
        asm volatile("s_waitcnt vmcnt(4)" ::: "memory");
        __builtin_amdgcn_s_barrier();
        // ---- PH1: ks{2,3} ----
        bf16x8 a02 = *(const bf16x8*)&As[ca + arow0 + sk2];
        bf16x8 a03 = *(const bf16x8*)&As[ca + arow0 + sk3];
        bf16x8 a12 = *(const bf16x8*)&As[ca + arow1 + sk2];
        bf16x8 a13 = *(const bf16x8*)&As[ca + arow1 + sk3];
        bf16x8 b02 = *(const bf16x8*)&Bs[cb + brow0 + tk2];
        bf16x8 b03 = *(const bf16x8*)&Bs[cb + brow0 + tk3];
        bf16x8 b12 = *(const bf16x8*)&Bs[cb + brow1 + tk2];
        bf16x8 b13 = *(const bf16x8*)&Bs[cb + brow1 + tk3];
        async_copy16(&Bs[nb + 8192 + da],  gB + 32);
        async_copy16(&Bs[nb + 12288 + da], gB + 131072 + 32);
        gA += 64; gB += 64;
        __builtin_amdgcn_s_barrier();
        asm volatile("s_waitcnt lgkmcnt(0)" ::: "memory");
        __builtin_amdgcn_s_setprio(1);
        acc[0][0] = __builtin_amdgcn_mfma_f32_32x32x16_bf16(a02, b02, acc[0][0], 0, 0, 0);
        acc[0][1] = __builtin_amdgcn_mfma_f32_32x32x16_bf16(a02, b12, acc[0][1], 0, 0, 0);
        acc[1][0] = __builtin_amdgcn_mfma_f32_32x32x16_bf16(a12, b02, acc[1][0], 0, 0, 0);
        acc[1][1] = __builtin_amdgcn_mfma_f32_32x32x16_bf16(a12, b12, acc[1][1], 0, 0, 0);
        acc[0][0] = __builtin_amdgcn_mfma_f32_32x32x16_bf16(a03, b03, acc[0][0], 0, 0, 0);
        acc[0][1] = __builtin_amdgcn_mfma_f32_32x32x16_bf16(a03, b13, acc[0][1], 0, 0, 0);
        acc[1][0] = __builtin_amdgcn_mfma_f32_32x32x16_bf16(a13, b03, acc[1][0], 0, 0, 0);
        acc[1][1] = __builtin_amdgcn_mfma_f32_32x32x16_bf16(a13, b13, acc[1][1], 0, 0, 0);
        __builtin_amdgcn_s_setprio(0);
        asm volatile("s_waitcnt vmcnt(2)" ::: "memory");
        __builtin_amdgcn_s_barrier();
        cur ^= 1;
    }

    {   // tail tile
        const int ca = cur * 8192;
        const int cb = cur * 16384;
        bf16x8 a00 = *(const bf16x8*)&As[ca + arow0 + sk0];
        bf16x8 a01 = *(const bf16x8*)&As[ca + arow0 + sk1];
        bf16x8 a10 = *(const bf16x8*)&As[ca + arow1 + sk0];
        bf16x8 a11 = *(const bf16x8*)&As[ca + arow1 + sk1];
        bf16x8 b00 = *(const bf16x8*)&Bs[cb + brow0 + tk0];
        bf16x8 b01 = *(const bf16x8*)&Bs[cb + brow0 + tk1];
        bf16x8 b10 = *(const bf16x8*)&Bs[cb + brow1 + tk0];
        bf16x8 b11 = *(const bf16x8*)&Bs[cb + brow1 + tk1];
        __builtin_amdgcn_s_barrier();
        asm volatile("s_waitcnt lgkmcnt(0)" ::: "memory");
        __builtin_amdgcn_s_setprio(1);
        acc[0][0] = __builtin_amdgcn_mfma_f32_32x32x16_bf16(a00, b00, acc[0][0], 0, 0, 0);
        acc[0][1] = __builtin_amdgcn_mfma_f32_32x32x16_bf16(a00, b10, acc[0][1], 0, 0, 0);
        acc[1][0] = __builtin_amdgcn_mfma_f32_32x32x16_bf16(a10, b00, acc[1][0], 0, 0, 0);
        acc[1][1] = __builtin_amdgcn_mfma_f32_32x32x16_bf16(a10, b10, acc[1][1], 0, 0, 0);
        acc[0][0] = __builtin_amdgcn_mfma_f32_32x32x16_bf16(a01, b01, acc[0][0], 0, 0, 0);
        acc[0][1] = __builtin_amdgcn_mfma_f32_32x32x16_bf16(a01, b11, acc[0][1], 0, 0, 0);
        acc[1][0] = __builtin_amdgcn_mfma_f32_32x32x16_bf16(a11, b01, acc[1][0], 0, 0, 0);
        acc[1][1] = __builtin_amdgcn_mfma_f32_32x32x16_bf16(a11, b11, acc[1][1], 0, 0, 0);
        __builtin_amdgcn_s_setprio(0);
        asm volatile("s_waitcnt vmcnt(0)" ::: "memory");
        __builtin_amdgcn_s_barrier();
        bf16x8 a02 = *(const bf16x8*)&As[ca + arow0 + sk2];
        bf16x8 a03 = *(const bf16x8*)&As[ca + arow0 + sk3];
        bf16x8 a12 = *(const bf16x8*)&As[ca + arow1 + sk2];
        bf16x8 a13 = *(const bf16x8*)&As[ca + arow1 + sk3];
        bf16x8 b02 = *(const bf16x8*)&Bs[cb + brow0 + tk2];
        bf16x8 b03 = *(const bf16x8*)&Bs[cb + brow0 + tk3];
        bf16x8 b12 = *(const bf16x8*)&Bs[cb + brow1 + tk2];
        bf16x8 b13 = *(const bf16x8*)&Bs[cb + brow1 + tk3];
        asm volatile("s_waitcnt lgkmcnt(0)" ::: "memory");
        __builtin_amdgcn_s_setprio(1);
        acc[0][0] = __builtin_amdgcn_mfma_f32_32x32x16_bf16(a02, b02, acc[0][0], 0, 0, 0);
        acc[0][1] = __builtin_amdgcn_mfma_f32_32x32x16_bf16(a02, b12, acc[0][1], 0, 0, 0);
        acc[1][0] = __builtin_amdgcn_mfma_f32_32x32x16_bf16(a12, b02, acc[1][0], 0, 0, 0);
        acc[1][1] = __builtin_amdgcn_mfma_f32_32x32x16_bf16(a12, b12, acc[1][1], 0, 0, 0);
        acc[0][0] = __builtin_amdgcn_mfma_f32_32x32x16_bf16(a03, b03, acc[0][0], 0, 0, 0);
        acc[0][1] = __builtin_amdgcn_mfma_f32_32x32x16_bf16(a03, b13, acc[0][1], 0, 0, 0);
        acc[1][0] = __builtin_amdgcn_mfma_f32_32x32x16_bf16(a13, b03, acc[1][0], 0, 0, 0);
        acc[1][1] = __builtin_amdgcn_mfma_f32_32x32x16_bf16(a13, b13, acc[1][1], 0, 0, 0);
        __builtin_amdgcn_s_setprio(0);
    }

    // epilogue: bf16 gate_raw = silu(acc + bias); ni innermost.
    {
        const float bb0 = bias[n0 + wc * 64 + lc];
        const float bb1 = bias[n0 + wc * 64 + 32 + lc];
        #pragma unroll
        for (int mi = 0; mi < 2; ++mi) {
            #pragma unroll
            for (int r = 0; r < 16; ++r) {
                const int row = m0 + wr * 64 + mi * 32 + (r & 3) + 8 * (r >> 2) + 4 * q;
                ushort_t* cp = C + (size_t)row * ldc + n0 + wc * 64 + lc;
                float v0 = acc[mi][0][r] + bb0;
                float v1 = acc[mi][1][r] + bb1;
                cp[0]  = (ushort_t)f2bf(v0 / (1.0f + expf(-v0)));
                cp[32] = (ushort_t)f2bf(v1 / (1.0f + expf(-v1)));
            }
        }
    }
}

// ---------------------------------------------------------------------------
// TM=64 GEMM (proj: 512 blocks, 2/CU). fp32 out + bias[col].
// Triple-buffered, depth-2 prefetch, counted vmcnt; simple XCD swizzle.
// ---------------------------------------------------------------------------
__global__ __launch_bounds__(256)
void gemm_tm64(const ushort_t* __restrict__ A, int lda,
               const ushort_t* __restrict__ Bt, int ldb,
               const float* __restrict__ bias,
               float* __restrict__ C, int ldc, int nkt)  // nkt >= 3
{
    __shared__ ushort_t As[3 * 64 * 32];
    __shared__ ushort_t Bs[3 * 128 * 32];

    const int tid = threadIdx.x;
    const int w  = tid >> 6, l = tid & 63;
    const int lc = l & 31, q = l >> 5;
    const int wr = w >> 1, wc = w & 1;
    int bx, by; xcd_tile(bx, by);
    const int m0 = by * 64, n0 = bx * 128;

    const int rA = tid >> 2,          kcA = (tid & 3) ^ ((rA >> 1) & 3);
    const int rB1 = (256 + tid) >> 2, kcB1 = (tid & 3) ^ ((rB1 >> 1) & 3);
    const ushort_t* gA  = A  + (size_t)(m0 + rA)  * lda + kcA  * 8;
    const ushort_t* gB0 = Bt + (size_t)(n0 + rA)  * ldb + kcA  * 8;
    const ushort_t* gB1 = Bt + (size_t)(n0 + rB1) * ldb + kcB1 * 8;
    const int sA  = w * 512;
    const int sB0 = w * 512;
    const int sB1 = 2048 + w * 512;

    const int sl = (lc >> 1) & 3;
    int aoff[2], boff[2][2];
    #pragma unroll
    for (int ks = 0; ks < 2; ++ks) {
        const int kk = ks * 2 + q;
        const int mrow = wr * 32 + lc;
        aoff[ks] = (mrow * 4 + (kk ^ sl)) * 8;
        #pragma unroll
        for (int ni = 0; ni < 2; ++ni) {
            const int nrow = wc * 64 + ni * 32 + lc;
            boff[ni][ks] = (nrow * 4 + (kk ^ sl)) * 8;
        }
    }

    f32x16 acc[2];
    #pragma unroll
    for (int ni = 0; ni < 2; ++ni)
        #pragma unroll
        for (int e = 0; e < 16; ++e) acc[ni][e] = 0.0f;

    auto stage = [&](int ab, int bb) {
        async_copy16(&As[ab + sA], gA);
        async_copy16(&Bs[bb + sB0], gB0); async_copy16(&Bs[bb + sB1], gB1);
        gA += 32; gB0 += 32; gB1 += 32;
    };
    auto compute = [&](int ab, int bb) {
        bf16x8 a[2], b[2][2];
        #pragma unroll
        for (int ks = 0; ks < 2; ++ks) {
            a[ks] = *(const bf16x8*)&As[ab + aoff[ks]];
            b[0][ks] = *(const bf16x8*)&Bs[bb + boff[0][ks]];
            b[1][ks] = *(const bf16x8*)&Bs[bb + boff[1][ks]];
        }
        #pragma unroll
        for (int ks = 0; ks < 2; ++ks)
            #pragma unroll
            for (int ni = 0; ni < 2; ++ni)
                acc[ni] = __builtin_amdgcn_mfma_f32_32x32x16_bf16(
                    a[ks], b[ni][ks], acc[ni], 0, 0, 0);
    };

    stage(0, 0); stage(2048, 4096);
    int as_ = 4096, bs_ = 8192;
    int ac_ = 0,    bc_ = 0;
    for (int kt = 0; kt < nkt - 2; ++kt) {
        asm volatile("s_waitcnt vmcnt(3)" ::: "memory");
        __builtin_amdgcn_s_barrier();
        stage(as_, bs_);
        compute(ac_, bc_);
        as_ = ac_; bs_ = bc_;
        ac_ = (ac_ == 4096) ? 0 : ac_ + 2048;
        bc_ = (bc_ == 8192) ? 0 : bc_ + 4096;
    }
    asm volatile("s_waitcnt vmcnt(3)" ::: "memory");
    __builtin_amdgcn_s_barrier();
    compute(ac_, bc_);
    ac_ = (ac_ == 4096) ? 0 : ac_ + 2048;
    bc_ = (bc_ == 8192) ? 0 : bc_ + 4096;
    asm volatile("s_waitcnt vmcnt(0)" ::: "memory");
    __builtin_amdgcn_s_barrier();
    compute(ac_, bc_);

    #pragma unroll
    for (int ni = 0; ni < 2; ++ni) {
        const int col = n0 + wc * 64 + ni * 32 + lc;
        const float bb = bias[col];
        #pragma unroll
        for (int r = 0; r < 16; ++r) {
            const int row = m0 + wr * 32 + (r & 3) + 8 * (r >> 2) + 4 * q;
            C[(size_t)row * ldc + col] = acc[ni][r] + bb;
        }
    }
}

// ---------------------------------------------------------------------------
// q/k prep: reads bf16 qkv [row][4096], xpos + gamma^{+-(t&63)} pre-scale,
// bf16 head-major [bh][T][128]
// ---------------------------------------------------------------------------
__global__ __launch_bounds__(256)
void qk_prep(const ushort_t* __restrict__ qkvb,
             ushort_t* __restrict__ qh, ushort_t* __restrict__ kh)
{
    const int row = blockIdx.x;
    const int t = threadIdx.x;
    const int b = row >> 11, trow = row & (T_SEQ - 1);
    const bool isK = t >= 128;
    const int col0 = (t & 127) * 8;
    const int h = col0 >> 7, d = col0 & 127;

    float ld, gamma;
    decay_params(h, ld, gamma);
    const float gsc = __expf(isK ? -ld * (float)(trow & 63) : ld * (float)(trow & 63));

    const ushort_t* src = qkvb + (size_t)row * 4096 + (isK ? E_DIM : 0) + col0;
    bf16x8 xv8 = *(const bf16x8*)src;
    float xv[8];
    #pragma unroll
    for (int p = 0; p < 8; ++p) xv[p] = bf2f((ushort_t)xv8[p]);

    const float tf = (float)trow * (1.0f / 512.0f);
    bf16x8 o;
    #pragma unroll
    for (int pi = 0; pi < 4; ++pi) {
        const int ip = col0 / 2 + pi;
        float sv = (2.0f * (float)ip + 409.6f) * (1.0f / 1433.6f);
        float e = __logf(sv) * tf;
        if (isK) e = -e;
        float sc = __expf(e);
        float invf = __expf((float)ip * -0.017988946038999563f);  // -ln(1e4)/512
        float sn, cs;
        sincosf((float)trow * invf, &sn, &cs);
        float c = cs * sc * gsc, s = sn * sc * gsc;
        float a = xv[2 * pi], bb = xv[2 * pi + 1];
        o[2 * pi]     = f2bf(a * c - bb * s);
        o[2 * pi + 1] = f2bf(bb * c + a * s);
    }
    ushort_t* dst = (isK ? kh : qh) + ((size_t)(b * 8 + h) * T_SEQ + trow) * 128 + d;
    *(bf16x8*)dst = o;
}

// ---------------------------------------------------------------------------
// V transpose: bf16 v-section of qkv -> vt [bh][256][T] bf16 (pure move)
// ---------------------------------------------------------------------------
__global__ __launch_bounds__(256)
void v_transpose(const ushort_t* __restrict__ qkvb, ushort_t* __restrict__ vt)
{
    __shared__ ushort_t tile[32][40];
    const int j0 = blockIdx.x * 32;
    const int zz = blockIdx.y;
    const int bh = zz >> 3, v0 = (zz & 7) * 32;
    const int b = bh >> 3, h = bh & 7;
    const int t = threadIdx.x;
    const int r = t >> 3, c = (t & 7) * 4;

    *(u16x4*)&tile[r][c] = *(const u16x4*)(qkvb + (size_t)(b * T_SEQ + j0 + r) * 4096
                                           + 2 * E_DIM + h * DV + v0 + c);
    __syncthreads();
    u16x4 o;
    o[0] = tile[c][r];
    o[1] = tile[c + 1][r];
    o[2] = tile[c + 2][r];
    o[3] = tile[c + 3][r];
    *(u16x4*)&vt[((size_t)bh * 256 + v0 + r) * T_SEQ + j0 + c] = o;
}

// ---------------------------------------------------------------------------
// kt2 = gamma^63 * kh^T per head: [bh][T][128] -> [bh][128][T]
// ---------------------------------------------------------------------------
__global__ __launch_bounds__(256)
void kt2_kernel(const ushort_t* __restrict__ kh, ushort_t* __restrict__ kt2)
{
    __shared__ ushort_t tile[32][40];
    const int j0 = blockIdx.x * 32;
    const int zz = blockIdx.y;
    const int bh = zz >> 2, k0 = (zz & 3) * 32;
    const int t = threadIdx.x;
    const int r = t >> 3, c = (t & 7) * 4;
    float ld, gamma; decay_params(bh & 7, ld, gamma);
    const float g63 = expf(ld * 63.0f);
    *(u16x4*)&tile[r][c] = *(const u16x4*)&kh[((size_t)bh * T_SEQ + j0 + r) * 128 + k0 + c];
    __syncthreads();
    u16x4 o;
    o[0] = (ushort_t)f2bf(bf2f(tile[c][r])     * g63);
    o[1] = (ushort_t)f2bf(bf2f(tile[c + 1][r]) * g63);
    o[2] = (ushort_t)f2bf(bf2f(tile[c + 2][r]) * g63);
    o[3] = (ushort_t)f2bf(bf2f(tile[c + 3][r]) * g63);
    *(u16x4*)&kt2[((size_t)bh * 128 + k0 + r) * T_SEQ + j0 + c] = o;
}

// ---------------------------------------------------------------------------
// Phase A: A_c[v][k] = sum_{j in chunk} vt[v][j] * kt2[k][j]  (bf16)
// ---------------------------------------------------------------------------
__global__ __launch_bounds__(256)
void chunk_kv(const ushort_t* __restrict__ vt, const ushort_t* __restrict__ kt2,
              ushort_t* __restrict__ Abuf)
{
    const int c = blockIdx.x;
    const int bh = blockIdx.y;
    const int tid = threadIdx.x;
    const int w = tid >> 6, l = tid & 63, lc = l & 31, q = l >> 5;
    const int j0 = c * 64;

    f32x16 acc[2][4];
    #pragma unroll
    for (int mi = 0; mi < 2; ++mi)
        #pragma unroll
        for (int ni = 0; ni < 4; ++ni)
            #pragma unroll
            for (int e = 0; e < 16; ++e) acc[mi][ni][e] = 0.0f;

    #pragma unroll
    for (int ks = 0; ks < 4; ++ks) {
        bf16x8 a[2], bfr[4];
        #pragma unroll
        for (int mi = 0; mi < 2; ++mi)
            a[mi] = *(const bf16x8*)(vt + ((size_t)bh * 256 + w * 64 + mi * 32 + lc) * T_SEQ
                                     + j0 + ks * 16 + q * 8);
        #pragma unroll
        for (int ni = 0; ni < 4; ++ni)
            bfr[ni] = *(const bf16x8*)(kt2 + ((size_t)bh * 128 + ni * 32 + lc) * T_SEQ
                                       + j0 + ks * 16 + q * 8);
        #pragma unroll
        for (int mi = 0; mi < 2; ++mi)
            #pragma unroll
            for (int ni = 0; ni < 4; ++ni)
                acc[mi][ni] = __builtin_amdgcn_mfma_f32_32x32x16_bf16(
                    a[mi], bfr[ni], acc[mi][ni], 0, 0, 0);
    }

    ushort_t* ab = Abuf + (size_t)(bh * 32 + c) * 256 * 128;
    #pragma unroll
    for (int mi = 0; mi < 2; ++mi)
        #pragma unroll
        for (int ni = 0; ni < 4; ++ni)
            #pragma unroll
            for (int r = 0; r < 16; ++r) {
                const int v = w * 64 + mi * 32 + (r & 3) + 8 * (r >> 2) + 4 * q;
                const int k = ni * 32 + lc;
                ab[(size_t)v * 128 + k] = (ushort_t)f2bf(acc[mi][ni][r]);
            }
}

// ---------------------------------------------------------------------------
// Phase B: IN-PLACE scan over chunks (St may alias Abuf: Abuf[off] is read
// BEFORE St[off] is written).  St[c] = gamma * S_c, S_{c+1} = g64*S_c + A_c.
// Final state -> curr_kv (fp32).
// ---------------------------------------------------------------------------
__global__ __launch_bounds__(256)
void scan_state(const ushort_t* __restrict__ Abuf, ushort_t* __restrict__ St,
                float* __restrict__ ckv)
{
    const int blk = blockIdx.x;
    const int bh = blk >> 7, sub = blk & 127;
    const int tid = threadIdx.x;
    const int v = sub * 2 + (tid >> 7), k = tid & 127;

    float ld, gamma;
    decay_params(bh & 7, ld, gamma);
    const float g64 = expf(ld * 64.0f);

    const size_t base = ((size_t)bh * 32 * 256 + v) * 128 + k;
    const size_t cstr = 256 * 128;
    float s = 0.0f;
    for (int c = 0; c < 32; ++c) {
        const size_t off = base + (size_t)c * cstr;
        const float a = bf2f(Abuf[off]);     // read BEFORE the aliased write
        St[off] = (ushort_t)f2bf(gamma * s);
        s = g64 * s + a;
    }
    const float inv_scale = rsqrtf((1.0f - expf(ld * (float)T_SEQ)) / (1.0f - gamma));
    ckv[((size_t)bh * 128 + k) * 256 + v] = s * inv_scale;
}

// ---------------------------------------------------------------------------
// Phase C: per-i-tile output, single-wave blocks, fused groupnorm AND gating
// multiply (gate_raw = silu(hs@w_g+b_g) precomputed) -> bf16 gated.
// ---------------------------------------------------------------------------
__global__ __launch_bounds__(64)
void retention_chunk(const ushort_t* __restrict__ qh,
                     const ushort_t* __restrict__ kh,
                     const ushort_t* __restrict__ vt,
                     const ushort_t* __restrict__ St,
                     const ushort_t* __restrict__ grw,
                     ushort_t* __restrict__ gated)
{
    const int it = blockIdx.x;
    const int bh = blockIdx.y;
    const int b = bh >> 3, h = bh & 7;
    const int c = it >> 1, w = it & 1;
    const int l = threadIdx.x, lc = l & 31, q = l >> 5;
    const int i0 = it * 32;
    const size_t bhT = (size_t)bh * T_SEQ;

    float ld, gamma;
    decay_params(h, ld, gamma);

    bf16x8 qf[8];
    {
        const ushort_t* qp = qh + (bhT + i0 + lc) * 128 + q * 8;
        #pragma unroll
        for (int c8 = 0; c8 < 8; ++c8)
            qf[c8] = *(const bf16x8*)(qp + c8 * 16);
    }

    f32x16 acc[8];
    #pragma unroll
    for (int vg = 0; vg < 8; ++vg)
        #pragma unroll
        for (int e = 0; e < 16; ++e) acc[vg][e] = 0.0f;

    if (c > 0) {
        const ushort_t* sp = St + ((size_t)(bh * 32 + c) * 256 + lc) * 128 + q * 8;
        #pragma unroll
        for (int vg = 0; vg < 8; ++vg) {
            const ushort_t* spv = sp + (size_t)vg * 32 * 128;
            #pragma unroll
            for (int ks = 0; ks < 8; ++ks) {
                bf16x8 sb = *(const bf16x8*)(spv + ks * 16);
                acc[vg] = __builtin_amdgcn_mfma_f32_32x32x16_bf16(
                    qf[ks], sb, acc[vg], 0, 0, 0);
            }
        }
    }

    for (int jt2 = 0; jt2 <= w; ++jt2) {
        const int j0 = c * 64 + jt2 * 32;

        f32x16 s;
        #pragma unroll
        for (int e = 0; e < 16; ++e) s[e] = 0.0f;
        const ushort_t* kp = kh + (bhT + j0 + lc) * 128 + q * 8;
        #pragma unroll
        for (int c8 = 0; c8 < 8; ++c8) {
            bf16x8 ka = *(const bf16x8*)(kp + c8 * 16);
            s = __builtin_amdgcn_mfma_f32_32x32x16_bf16(ka, qf[c8], s, 0, 0, 0);
        }

        float sv[16];
        #pragma unroll
        for (int r = 0; r < 16; ++r) {
            float val = s[r];
            if (jt2 == w) {
                int jr_ = (r & 3) + 8 * (r >> 2) + 4 * q;
                val = (jr_ <= lc) ? val : 0.0f;
            }
            sv[r] = val;
        }

        bf16x8 pa0, pa1;
        #pragma unroll
        for (int e = 0; e < 4; ++e) {
            float t1 = __shfl_xor(sv[e + 4], 32);
            float t0 = __shfl_xor(sv[e], 32);
            pa0[e]     = f2bf(q ? t1 : sv[e]);
            pa0[e + 4] = f2bf(q ? sv[e + 4] : t0);
            float t3 = __shfl_xor(sv[e + 12], 32);
            float t2 = __shfl_xor(sv[e + 8], 32);
            pa1[e]     = f2bf(q ? t3 : sv[e + 8]);
            pa1[e + 4] = f2bf(q ? sv[e + 12] : t2);
        }

        #pragma unroll
        for (int vg = 0; vg < 8; ++vg) {
            const ushort_t* vp = vt + ((size_t)bh * 256 + vg * 32 + lc) * T_SEQ + j0 + q * 8;
            bf16x8 vb0 = *(const bf16x8*)vp;
            bf16x8 vb1 = *(const bf16x8*)(vp + 16);
            acc[vg] = __builtin_amdgcn_mfma_f32_32x32x16_bf16(pa0, vb0, acc[vg], 0, 0, 0);
            acc[vg] = __builtin_amdgcn_mfma_f32_32x32x16_bf16(pa1, vb1, acc[vg], 0, 0, 0);
        }
    }

    #pragma unroll
    for (int r = 0; r < 16; ++r) {
        const int il = (r & 3) + 8 * (r >> 2) + 4 * q;
        const int i  = i0 + il;
        float denom = (1.0f - expf(ld * (float)(i + 1))) / (1.0f - gamma);
        float fs = 0.08838834764831845f * rsqrtf(denom);
        float vals[8];
        float a1 = 0.0f, a2 = 0.0f;
        #pragma unroll
        for (int vg = 0; vg < 8; ++vg) {
            float x = acc[vg][r] * fs;
            vals[vg] = x;
            a1 += x; a2 += x * x;
        }
        a1 += __shfl_xor(a1, 1);  a2 += __shfl_xor(a2, 1);
        a1 += __shfl_xor(a1, 2);  a2 += __shfl_xor(a2, 2);
        a1 += __shfl_xor(a1, 4);  a2 += __shfl_xor(a2, 4);
        a1 += __shfl_xor(a1, 8);  a2 += __shfl_xor(a2, 8);
        a1 += __shfl_xor(a1, 16); a2 += __shfl_xor(a2, 16);
        float mu = a1 * (1.0f / 256.0f);
        float var = a2 * (1.0f / 256.0f) - mu * mu;
        float rs = rsqrtf(var + 1e-5f);
        const size_t ob = ((size_t)(b * T_SEQ + i)) * V_DIM + h * DV + lc;
        ushort_t* op = gated + ob;
        const ushort_t* gp = grw + ob;
        #pragma unroll
        for (int vg = 0; vg < 8; ++vg) {
            float g = bf2f(gp[vg * 32]);
            op[vg * 32] = (ushort_t)f2bf((vals[vg] - mu) * rs * g);
        }
    }
}

// ---------------------------------------------------------------------------
extern "C" void kernel_launch(void* const* d_in, const int* in_sizes, int n_in,
                              void* d_out, int out_size, void* d_ws, size_t ws_size,
                              hipStream_t stream)
{
    const float* hs    = (const float*)d_in[0];
    const float* w_qkv = (const float*)d_in[1];
    const float* b_qkv = (const float*)d_in[2];
    const float* w_g   = (const float*)d_in[3];
    const float* b_g   = (const float*)d_in[4];
    const float* w_p   = (const float*)d_in[5];
    const float* b_p   = (const float*)d_in[6];
    float* out = (float*)d_out;

    const size_t MB = 1024 * 1024;
    // ws (96MB) timeline (qkv bf16, in-place scan):
    //   [0,32):  qkv_bf (qkv GEMM -> preps)  ->  Abuf (chunk_kv -> scan)
    //            -> St IN-PLACE (scan -> retention) -> wp_t@[0,4) (-> proj)
    //   [32,48): gate_raw (gate GEMM -> retention)
    //   [48,64): gated (retention -> proj)
    //   [64,72): wg_t@[64,68) (-> gate GEMM) -> qh (qk_prep -> retention)
    //   [72,88): vt (v_transpose -> retention)
    //   [88,96): wqkv_t (-> qkv GEMM) -> kh (qk_prep -> kt2/retention)
    // d_out (18MB): hs_bf@[0,8), kt2@[8,16) — dead before proj store;
    //               proj writes out@[0,16) at the END; ckv@[16,18).
    ushort_t* qkv_bf   = (ushort_t*)d_ws;
    ushort_t* Abuf     = (ushort_t*)d_ws;               // aliases qkv_bf (dead)
    ushort_t* Stbuf    = (ushort_t*)d_ws;               // IN-PLACE with Abuf
    ushort_t* wp_t     = (ushort_t*)d_ws;               // after retention
    ushort_t* gate_raw = (ushort_t*)((char*)d_ws + 32 * MB);
    ushort_t* gated_bf = (ushort_t*)((char*)d_ws + 48 * MB);
    ushort_t* wg_t     = (ushort_t*)((char*)d_ws + 64 * MB);
    ushort_t* qh       = (ushort_t*)((char*)d_ws + 64 * MB);  // after wg_t dead
    ushort_t* vt       = (ushort_t*)((char*)d_ws + 72 * MB);
    ushort_t* wqkv_t   = (ushort_t*)((char*)d_ws + 88 * MB);
    ushort_t* kh       = (ushort_t*)((char*)d_ws + 88 * MB);  // after wqkv_t dead
    ushort_t* hs_bf    = (ushort_t*)d_out;
    ushort_t* kt2      = (ushort_t*)((char*)d_out + 8 * MB);
    float*    ckv_out  = out + (size_t)BT * E_DIM;

    // 1. conversions
    f32_to_bf16_kernel<<<dim3(2048), 256, 0, stream>>>(hs, hs_bf);
    transpose_w_kernel<<<dim3(64, 32), 256, 0, stream>>>(w_g, wg_t, E_DIM, V_DIM);
    transpose_w_kernel<<<dim3(128, 32), 256, 0, stream>>>(w_qkv, wqkv_t, E_DIM, 4096);

    // 2. gate_raw = silu(hs @ w_g + b_g)  (early; no dependency on retention)
    gemm_gate_p8<<<dim3(8, 32), 512, 0, stream>>>(
        hs_bf, wg_t, b_g, gate_raw, V_DIM, E_DIM / 64);

    // 3. qkv = hs @ w_qkv + b_qkv -> bf16 (v2: 256x128 tiles, 2 blocks/CU)
    gemm_qkv_v2<<<dim3(32, 16), 256, 0, stream>>>(
        hs_bf, wqkv_t, b_qkv, qkv_bf, 4096, E_DIM / 32);

    // 4. preps (consume bf16 qkv); qh over wg_t, kh over wqkv_t (both dead)
    qk_prep<<<dim3(BT), 256, 0, stream>>>(qkv_bf, qh, kh);
    v_transpose<<<dim3(64, 128), 256, 0, stream>>>(qkv_bf, vt);
    kt2_kernel<<<dim3(64, 64), 256, 0, stream>>>(kh, kt2);

    // 5. chunked retention: A (over dead qkv_bf) -> in-place scan -> outputs
    chunk_kv<<<dim3(32, 16), 256, 0, stream>>>(vt, kt2, Abuf);
    scan_state<<<dim3(2048), 256, 0, stream>>>(Abuf, Stbuf, ckv_out);
    retention_chunk<<<dim3(64, 16), 64, 0, stream>>>(qh, kh, vt, Stbuf, gate_raw, gated_bf);

    // 6. proj = gated @ w_p + b_p  (wp_t over dead St; out over dead hs_bf/kt2)
    transpose_w_kernel<<<dim3(32, 64), 256, 0, stream>>>(w_p, wp_t, V_DIM, E_DIM);
    gemm_tm64<<<dim3(8, 64), 256, 0, stream>>>(
        gated_bf, V_DIM, wp_t, V_DIM, b_p, out, E_DIM, V_DIM / 32);
}

// Round 10
// 295.569 us; speedup vs baseline: 1.0062x; 1.0050x over previous
//
#include <hip/hip_runtime.h>
#include <math.h>

#define BT      4096
#define T_SEQ   2048
#define E_DIM   1024
#define V_DIM   2048
#define DK      128
#define DV      256

typedef unsigned short ushort_t;
typedef __attribute__((ext_vector_type(8)))  short bf16x8;
typedef __attribute__((ext_vector_type(4)))  unsigned short u16x4;
typedef __attribute__((ext_vector_type(16))) float f32x16;

__device__ __forceinline__ void decay_params(int h, float& ld, float& gamma) {
    const float s0 = -3.4657359027997265f;  // ln(1/32)
    const float e0 = -6.2383246250395092f;  // ln(1/512)
    float lin = s0 + (e0 - s0) * ((float)h * (1.0f / 7.0f));
    gamma = 1.0f - expf(lin);
    ld = logf(gamma);
}

__device__ __forceinline__ short f2bf(float f) {
    unsigned u = __float_as_uint(f);
    unsigned r = (u + 0x7fffu + ((u >> 16) & 1u)) >> 16;
    return (short)r;
}
__device__ __forceinline__ float bf2f(ushort_t u) {
    return __uint_as_float((unsigned)u << 16);
}

__device__ __forceinline__ void async_copy16(void* lds, const void* g) {
    __builtin_amdgcn_global_load_lds(
        (const __attribute__((address_space(1))) unsigned int*)g,
        (__attribute__((address_space(3))) unsigned int*)lds, 16, 0, 0);
}

// Simple XCD swizzle (contiguous strip per XCD) — used by tm64.
__device__ __forceinline__ void xcd_tile(int& bx, int& by) {
    const int nwgx = gridDim.x;
    const int nwg  = nwgx * gridDim.y;
    int bid = blockIdx.y * nwgx + blockIdx.x;
    bid = (bid & 7) * (nwg >> 3) + (bid >> 3);
    bx = bid % nwgx;
    by = bid / nwgx;
}

// Square XCD regions for qkv grid (16,16): each XCD owns 8 n-cols x 4 m-rows.
// Bijective: xcd=(bx>>3)|((by>>2)<<1), idx=(bx&7)|((by&3)<<3).
__device__ __forceinline__ void xcd_map_qkv(int& bx, int& by) {
    int bid = blockIdx.y * 16 + blockIdx.x;
    const int xcd = bid & 7, idx = bid >> 3;            // idx in [0,32)
    bx = (xcd & 1) * 8 + (idx & 7);
    by = (xcd >> 1) * 4 + (idx >> 3);
}

// Square XCD regions for gate grid (8,32): each XCD owns 4 n-cols x 8 m-rows.
__device__ __forceinline__ void xcd_map_gate(int& bx, int& by) {
    int bid = blockIdx.y * 8 + blockIdx.x;
    const int xcd = bid & 7, idx = bid >> 3;            // idx in [0,32)
    bx = (xcd & 1) * 4 + (idx & 3);
    by = (xcd >> 1) * 8 + (idx >> 2);
}

// ---------------------------------------------------------------------------
// Batched prep: one launch does {w_qkv transpose, w_g transpose, hs f32->bf16}.
// Block-uniform branch on blockIdx.x ranges; each sub-job keeps its proven body.
//   [0,4096):    w_qkv [1024][4096] -> wqkv_t   (tile bx=t%128, by=t/128)
//   [4096,6144): w_g   [1024][2048] -> wg_t     (tile bx=u%64,  by=u/64)
//   [6144,8192): hs f32 -> bf16 (2048 chunks of 2048 elems)
// ---------------------------------------------------------------------------
__device__ __forceinline__ void transpose_tile_body(
    const float* __restrict__ W, ushort_t* __restrict__ Wt,
    int K, int N, int bx, int by, float (*tile)[33], int t)
{
    const int k0 = by * 32, n0 = bx * 32;
    const int r = t >> 3, c = (t & 7) * 4;
    float4 v = *(const float4*)&W[(size_t)(k0 + r) * N + n0 + c];
    tile[r][c] = v.x; tile[r][c + 1] = v.y; tile[r][c + 2] = v.z; tile[r][c + 3] = v.w;
    __syncthreads();
    u16x4 o;
    o[0] = (ushort_t)f2bf(tile[c][r]);
    o[1] = (ushort_t)f2bf(tile[c + 1][r]);
    o[2] = (ushort_t)f2bf(tile[c + 2][r]);
    o[3] = (ushort_t)f2bf(tile[c + 3][r]);
    *(u16x4*)&Wt[(size_t)(n0 + r) * K + k0 + c] = o;
}

__global__ __launch_bounds__(256)
void prep_batch(const float* __restrict__ hs, ushort_t* __restrict__ hs_bf,
                const float* __restrict__ w_qkv, ushort_t* __restrict__ wqkv_t,
                const float* __restrict__ w_g, ushort_t* __restrict__ wg_t)
{
    __shared__ float tile[32][33];
    const int t = threadIdx.x;
    const int blk = blockIdx.x;
    if (blk < 4096) {
        transpose_tile_body(w_qkv, wqkv_t, 1024, 4096, blk % 128, blk / 128, tile, t);
    } else if (blk < 6144) {
        const int u = blk - 4096;
        transpose_tile_body(w_g, wg_t, 1024, 2048, u % 64, u / 64, tile, t);
    } else {
        const int u = blk - 6144;
        int i = (u * 256 + t) * 8;
        float4 a = *(const float4*)&hs[i];
        float4 b = *(const float4*)&hs[i + 4];
        bf16x8 o;
        o[0] = f2bf(a.x); o[1] = f2bf(a.y); o[2] = f2bf(a.z); o[3] = f2bf(a.w);
        o[4] = f2bf(b.x); o[5] = f2bf(b.y); o[6] = f2bf(b.z); o[7] = f2bf(b.w);
        *(bf16x8*)&hs_bf[i] = o;
    }
}

// ---------------------------------------------------------------------------
// W[K][N] fp32 -> Wt[N][K] bf16 (standalone; used late for w_p only)
// ---------------------------------------------------------------------------
__global__ __launch_bounds__(256)
void transpose_w_kernel(const float* __restrict__ W, ushort_t* __restrict__ Wt,
                        int K, int N)
{
    __shared__ float tile[32][33];
    transpose_tile_body(W, Wt, K, N, blockIdx.x, blockIdx.y, tile, threadIdx.x);
}

// ---------------------------------------------------------------------------
// 8-PHASE 256x256 GEMM for qkv (round-8 proven BEST: 48.3us, Mfma 29%):
// bf16 output, ni-innermost epilogue, square XCD regions.
// ---------------------------------------------------------------------------
__global__ __launch_bounds__(512, 2)
void gemm256p8(const ushort_t* __restrict__ A,
               const ushort_t* __restrict__ Bt,
               const float* __restrict__ bias,
               ushort_t* __restrict__ C, int ldc, int nkt)  // nkt >= 2
{
    __shared__ ushort_t As[2 * 16384];   // 64 KB
    __shared__ ushort_t Bs[2 * 16384];   // 64 KB

    const int tid = threadIdx.x;
    const int wid = tid >> 6, l = tid & 63;
    const int lc = l & 31, q = l >> 5;
    const int wr = wid >> 2, wc = wid & 3;
    int bx, by; xcd_map_qkv(bx, by);
    const int m0 = by * 256, n0 = bx * 256;

    const int sra = tid >> 3;
    const int spa = (tid & 7) ^ (sra & 7);
    const ushort_t* gA = A + (size_t)(m0 + sra) * 1024 + spa * 8;
    const int srb = tid >> 2;
    const int spb = (tid & 3) ^ ((srb >> 1) & 3);
    const ushort_t* gB = Bt + (size_t)(n0 + srb) * 1024 + spb * 8;
    const int da = tid * 8;

    int arow0 = (wr * 128 +  0 + lc) * 64;
    int arow1 = (wr * 128 + 32 + lc) * 64;
    int arow2 = (wr * 128 + 64 + lc) * 64;
    int arow3 = (wr * 128 + 96 + lc) * 64;
    int sk0 = ((0 * 2 + q) ^ (lc & 7)) * 8;
    int sk1 = ((1 * 2 + q) ^ (lc & 7)) * 8;
    int sk2 = ((2 * 2 + q) ^ (lc & 7)) * 8;
    int sk3 = ((3 * 2 + q) ^ (lc & 7)) * 8;
    int brow0 = (wc * 64 +  0 + lc) * 32;
    int brow1 = (wc * 64 + 32 + lc) * 32;
    int tk0 = ((0 + q) ^ ((lc >> 1) & 3)) * 8;
    int tk1 = ((2 + q) ^ ((lc >> 1) & 3)) * 8;
    int tk2 = 8192 + ((0 + q) ^ ((lc >> 1) & 3)) * 8;
    int tk3 = 8192 + ((2 + q) ^ ((lc >> 1) & 3)) * 8;

    f32x16 acc[4][2];
    #pragma unroll
    for (int mi = 0; mi < 4; ++mi)
        #pragma unroll
        for (int ni = 0; ni < 2; ++ni)
            #pragma unroll
            for (int e = 0; e < 16; ++e) acc[mi][ni][e] = 0.0f;

    async_copy16(&As[da],          gA);
    async_copy16(&As[8192 + da],   gA + 131072);
    async_copy16(&Bs[da],          gB);
    async_copy16(&Bs[4096 + da],   gB + 131072);
    async_copy16(&As[4096 + da],   gA + 65536);
    async_copy16(&As[12288 + da],  gA + 196608);
    async_copy16(&Bs[8192 + da],   gB + 32);
    async_copy16(&Bs[12288 + da],  gB + 131072 + 32);
    gA += 64; gB += 64;
    asm volatile("s_waitcnt vmcnt(0)" ::: "memory");
    __builtin_amdgcn_s_barrier();

    int cur = 0;
    for (int t = 0; t < nkt - 1; ++t) {
        const int cb = cur * 16384;
        const int nb = 16384 - cb;
        // ---- PH0 ----
        bf16x8 a00 = *(const bf16x8*)&As[cb + arow0 + sk0];
        bf16x8 a01 = *(const bf16x8*)&As[cb + arow0 + sk1];
        bf16x8 a10 = *(const bf16x8*)&As[cb + arow1 + sk0];
        bf16x8 a11 = *(const bf16x8*)&As[cb + arow1 + sk1];
        bf16x8 b00 = *(const bf16x8*)&Bs[cb + brow0 + tk0];
        bf16x8 b01 = *(const bf16x8*)&Bs[cb + brow0 + tk1];
        bf16x8 b10 = *(const bf16x8*)&Bs[cb + brow1 + tk0];
        bf16x8 b11 = *(const bf16x8*)&Bs[cb + brow1 + tk1];
        async_copy16(&As[nb + da],        gA);
        async_copy16(&As[nb + 8192 + da], gA + 131072);
        async_copy16(&Bs[nb + da],        gB);
        async_copy16(&Bs[nb + 4096 + da], gB + 131072);
        __builtin_amdgcn_s_barrier();
        asm volatile("s_waitcnt lgkmcnt(0)" ::: "memory");
        __builtin_amdgcn_s_setprio(1);
        acc[0][0] = __builtin_amdgcn_mfma_f32_32x32x16_bf16(a00, b00, acc[0][0], 0, 0, 0);
        acc[0][1] = __builtin_amdgcn_mfma_f32_32x32x16_bf16(a00, b10, acc[0][1], 0, 0, 0);
        acc[1][0] = __builtin_amdgcn_mfma_f32_32x32x16_bf16(a10, b00, acc[1][0], 0, 0, 0);
        acc[1][1] = __builtin_amdgcn_mfma_f32_32x32x16_bf16(a10, b10, acc[1][1], 0, 0, 0);
        acc[0][0] = __builtin_amdgcn_mfma_f32_32x32x16_bf16(a01, b01, acc[0][0], 0, 0, 0);
        acc[0][1] = __builtin_amdgcn_mfma_f32_32x32x16_bf16(a01, b11, acc[0][1], 0, 0, 0);
        acc[1][0] = __builtin_amdgcn_mfma_f32_32x32x16_bf16(a11, b01, acc[1][0], 0, 0, 0);
        acc[1][1] = __builtin_amdgcn_mfma_f32_32x32x16_bf16(a11, b11, acc[1][1], 0, 0, 0);
        __builtin_amdgcn_s_setprio(0);
        asm volatile("s_waitcnt vmcnt(6)" ::: "memory");
        __builtin_amdgcn_s_barrier();
        // ---- PH1 ----
        bf16x8 a20 = *(const bf16x8*)&As[cb + arow2 + sk0];
        bf16x8 a21 = *(const bf16x8*)&As[cb + arow2 + sk1];
        bf16x8 a30 = *(const bf16x8*)&As[cb + arow3 + sk0];
        bf16x8 a31 = *(const bf16x8*)&As[cb + arow3 + sk1];
        async_copy16(&As[nb + 4096 + da],  gA + 65536);
        async_copy16(&As[nb + 12288 + da], gA + 196608);
        __builtin_amdgcn_s_barrier();
        asm volatile("s_waitcnt lgkmcnt(0)" ::: "memory");
        __builtin_amdgcn_s_setprio(1);
        acc[2][0] = __builtin_amdgcn_mfma_f32_32x32x16_bf16(a20, b00, acc[2][0], 0, 0, 0);
        acc[2][1] = __builtin_amdgcn_mfma_f32_32x32x16_bf16(a20, b10, acc[2][1], 0, 0, 0);
        acc[3][0] = __builtin_amdgcn_mfma_f32_32x32x16_bf16(a30, b00, acc[3][0], 0, 0, 0);
        acc[3][1] = __builtin_amdgcn_mfma_f32_32x32x16_bf16(a30, b10, acc[3][1], 0, 0, 0);
        acc[2][0] = __builtin_amdgcn_mfma_f32_32x32x16_bf16(a21, b01, acc[2][0], 0, 0, 0);
        acc[2][1] = __builtin_amdgcn_mfma_f32_32x32x16_bf16(a21, b11, acc[2][1], 0, 0, 0);
        acc[3][0] = __builtin_amdgcn_mfma_f32_32x32x16_bf16(a31, b01, acc[3][0], 0, 0, 0);
        acc[3][1] = __builtin_amdgcn_mfma_f32_32x32x16_bf16(a31, b11, acc[3][1], 0, 0, 0);
        __builtin_amdgcn_s_setprio(0);
        asm volatile("s_waitcnt vmcnt(6)" ::: "memory");
        __builtin_amdgcn_s_barrier();
        // ---- PH2 ----
        bf16x8 a02 = *(const bf16x8*)&As[cb + arow0 + sk2];
        bf16x8 a03 = *(const bf16x8*)&As[cb + arow0 + sk3];
        bf16x8 a12 = *(const bf16x8*)&As[cb + arow1 + sk2];
        bf16x8 a13 = *(const bf16x8*)&As[cb + arow1 + sk3];
        bf16x8 b02 = *(const bf16x8*)&Bs[cb + brow0 + tk2];
        bf16x8 b03 = *(const bf16x8*)&Bs[cb + brow0 + tk3];
        bf16x8 b12 = *(const bf16x8*)&Bs[cb + brow1 + tk2];
        bf16x8 b13 = *(const bf16x8*)&Bs[cb + brow1 + tk3];
        async_copy16(&Bs[nb + 8192 + da],  gB + 32);
        async_copy16(&Bs[nb + 12288 + da], gB + 131072 + 32);
        gA += 64; gB += 64;
        __builtin_amdgcn_s_barrier();
        asm volatile("s_waitcnt lgkmcnt(0)" ::: "memory");
        __builtin_amdgcn_s_setprio(1);
        acc[0][0] = __builtin_amdgcn_mfma_f32_32x32x16_bf16(a02, b02, acc[0][0], 0, 0, 0);
        acc[0][1] = __builtin_amdgcn_mfma_f32_32x32x16_bf16(a02, b12, acc[0][1], 0, 0, 0);
        acc[1][0] = __builtin_amdgcn_mfma_f32_32x32x16_bf16(a12, b02, acc[1][0], 0, 0, 0);
        acc[1][1] = __builtin_amdgcn_mfma_f32_32x32x16_bf16(a12, b12, acc[1][1], 0, 0, 0);
        acc[0][0] = __builtin_amdgcn_mfma_f32_32x32x16_bf16(a03, b03, acc[0][0], 0, 0, 0);
        acc[0][1] = __builtin_amdgcn_mfma_f32_32x32x16_bf16(a03, b13, acc[0][1], 0, 0, 0);
        acc[1][0] = __builtin_amdgcn_mfma_f32_32x32x16_bf16(a13, b03, acc[1][0], 0, 0, 0);
        acc[1][1] = __builtin_amdgcn_mfma_f32_32x32x16_bf16(a13, b13, acc[1][1], 0, 0, 0);
        __builtin_amdgcn_s_setprio(0);
        __builtin_amdgcn_s_barrier();
        // ---- PH3 ----
        bf16x8 a22 = *(const bf16x8*)&As[cb + arow2 + sk2];
        bf16x8 a23 = *(const bf16x8*)&As[cb + arow2 + sk3];
        bf16x8 a32 = *(const bf16x8*)&As[cb + arow3 + sk2];
        bf16x8 a33 = *(const bf16x8*)&As[cb + arow3 + sk3];
        __builtin_amdgcn_s_barrier();
        asm volatile("s_waitcnt lgkmcnt(0)" ::: "memory");
        __builtin_amdgcn_s_setprio(1);
        acc[2][0] = __builtin_amdgcn_mfma_f32_32x32x16_bf16(a22, b02, acc[2][0], 0, 0, 0);
        acc[2][1] = __builtin_amdgcn_mfma_f32_32x32x16_bf16(a22, b12, acc[2][1], 0, 0, 0);
        acc[3][0] = __builtin_amdgcn_mfma_f32_32x32x16_bf16(a32, b02, acc[3][0], 0, 0, 0);
        acc[3][1] = __builtin_amdgcn_mfma_f32_32x32x16_bf16(a32, b12, acc[3][1], 0, 0, 0);
        acc[2][0] = __builtin_amdgcn_mfma_f32_32x32x16_bf16(a23, b03, acc[2][0], 0, 0, 0);
        acc[2][1] = __builtin_amdgcn_mfma_f32_32x32x16_bf16(a23, b13, acc[2][1], 0, 0, 0);
        acc[3][0] = __builtin_amdgcn_mfma_f32_32x32x16_bf16(a33, b03, acc[3][0], 0, 0, 0);
        acc[3][1] = __builtin_amdgcn_mfma_f32_32x32x16_bf16(a33, b13, acc[3][1], 0, 0, 0);
        __builtin_amdgcn_s_setprio(0);
        asm volatile("s_waitcnt vmcnt(4)" ::: "memory");
        __builtin_amdgcn_s_barrier();
        cur ^= 1;
    }

    {   // tail tile
        const int cb = cur * 16384;
        bf16x8 a00 = *(const bf16x8*)&As[cb + arow0 + sk0];
        bf16x8 a01 = *(const bf16x8*)&As[cb + arow0 + sk1];
        bf16x8 a10 = *(const bf16x8*)&As[cb + arow1 + sk0];
        bf16x8 a11 = *(const bf16x8*)&As[cb + arow1 + sk1];
        bf16x8 b00 = *(const bf16x8*)&Bs[cb + brow0 + tk0];
        bf16x8 b01 = *(const bf16x8*)&Bs[cb + brow0 + tk1];
        bf16x8 b10 = *(const bf16x8*)&Bs[cb + brow1 + tk0];
        bf16x8 b11 = *(const bf16x8*)&Bs[cb + brow1 + tk1];
        __builtin_amdgcn_s_barrier();
        asm volatile("s_waitcnt lgkmcnt(0)" ::: "memory");
        __builtin_amdgcn_s_setprio(1);
        acc[0][0] = __builtin_amdgcn_mfma_f32_32x32x16_bf16(a00, b00, acc[0][0], 0, 0, 0);
        acc[0][1] = __builtin_amdgcn_mfma_f32_32x32x16_bf16(a00, b10, acc[0][1], 0, 0, 0);
        acc[1][0] = __builtin_amdgcn_mfma_f32_32x32x16_bf16(a10, b00, acc[1][0], 0, 0, 0);
        acc[1][1] = __builtin_amdgcn_mfma_f32_32x32x16_bf16(a10, b10, acc[1][1], 0, 0, 0);
        acc[0][0] = __builtin_amdgcn_mfma_f32_32x32x16_bf16(a01, b01, acc[0][0], 0, 0, 0);
        acc[0][1] = __builtin_amdgcn_mfma_f32_32x32x16_bf16(a01, b11, acc[0][1], 0, 0, 0);
        acc[1][0] = __builtin_amdgcn_mfma_f32_32x32x16_bf16(a11, b01, acc[1][0], 0, 0, 0);
        acc[1][1] = __builtin_amdgcn_mfma_f32_32x32x16_bf16(a11, b11, acc[1][1], 0, 0, 0);
        __builtin_amdgcn_s_setprio(0);
        asm volatile("s_waitcnt vmcnt(2)" ::: "memory");
        __builtin_amdgcn_s_barrier();
        bf16x8 a20 = *(const bf16x8*)&As[cb + arow2 + sk0];
        bf16x8 a21 = *(const bf16x8*)&As[cb + arow2 + sk1];
        bf16x8 a30 = *(const bf16x8*)&As[cb + arow3 + sk0];
        bf16x8 a31 = *(const bf16x8*)&As[cb + arow3 + sk1];
        __builtin_amdgcn_s_barrier();
        asm volatile("s_waitcnt lgkmcnt(0)" ::: "memory");
        __builtin_amdgcn_s_setprio(1);
        acc[2][0] = __builtin_amdgcn_mfma_f32_32x32x16_bf16(a20, b00, acc[2][0], 0, 0, 0);
        acc[2][1] = __builtin_amdgcn_mfma_f32_32x32x16_bf16(a20, b10, acc[2][1], 0, 0, 0);
        acc[3][0] = __builtin_amdgcn_mfma_f32_32x32x16_bf16(a30, b00, acc[3][0], 0, 0, 0);
        acc[3][1] = __builtin_amdgcn_mfma_f32_32x32x16_bf16(a30, b10, acc[3][1], 0, 0, 0);
        acc[2][0] = __builtin_amdgcn_mfma_f32_32x32x16_bf16(a21, b01, acc[2][0], 0, 0, 0);
        acc[2][1] = __builtin_amdgcn_mfma_f32_32x32x16_bf16(a21, b11, acc[2][1], 0, 0, 0);
        acc[3][0] = __builtin_amdgcn_mfma_f32_32x32x16_bf16(a31, b01, acc[3][0], 0, 0, 0);
        acc[3][1] = __builtin_amdgcn_mfma_f32_32x32x16_bf16(a31, b11, acc[3][1], 0, 0, 0);
        __builtin_amdgcn_s_setprio(0);
        asm volatile("s_waitcnt vmcnt(0)" ::: "memory");
        __builtin_amdgcn_s_barrier();
        bf16x8 a02 = *(const bf16x8*)&As[cb + arow0 + sk2];
        bf16x8 a03 = *(const bf16x8*)&As[cb + arow0 + sk3];
        bf16x8 a12 = *(const bf16x8*)&As[cb + arow1 + sk2];
        bf16x8 a13 = *(const bf16x8*)&As[cb + arow1 + sk3];
        bf16x8 b02 = *(const bf16x8*)&Bs[cb + brow0 + tk2];
        bf16x8 b03 = *(const bf16x8*)&Bs[cb + brow0 + tk3];
        bf16x8 b12 = *(const bf16x8*)&Bs[cb + brow1 + tk2];
        bf16x8 b13 = *(const bf16x8*)&Bs[cb + brow1 + tk3];
        __builtin_amdgcn_s_barrier();
        asm volatile("s_waitcnt lgkmcnt(0)" ::: "memory");
        __builtin_amdgcn_s_setprio(1);
        acc[0][0] = __builtin_amdgcn_mfma_f32_32x32x16_bf16(a02, b02, acc[0][0], 0, 0, 0);
        acc[0][1] = __builtin_amdgcn_mfma_f32_32x32x16_bf16(a02, b12, acc[0][1], 0, 0, 0);
        acc[1][0] = __builtin_amdgcn_mfma_f32_32x32x16_bf16(a12, b02, acc[1][0], 0, 0, 0);
        acc[1][1] = __builtin_amdgcn_mfma_f32_32x32x16_bf16(a12, b12, acc[1][1], 0, 0, 0);
        acc[0][0] = __builtin_amdgcn_mfma_f32_32x32x16_bf16(a03, b03, acc[0][0], 0, 0, 0);
        acc[0][1] = __builtin_amdgcn_mfma_f32_32x32x16_bf16(a03, b13, acc[0][1], 0, 0, 0);
        acc[1][0] = __builtin_amdgcn_mfma_f32_32x32x16_bf16(a13, b03, acc[1][0], 0, 0, 0);
        acc[1][1] = __builtin_amdgcn_mfma_f32_32x32x16_bf16(a13, b13, acc[1][1], 0, 0, 0);
        __builtin_amdgcn_s_setprio(0);
        __builtin_amdgcn_s_barrier();
        bf16x8 a22 = *(const bf16x8*)&As[cb + arow2 + sk2];
        bf16x8 a23 = *(const bf16x8*)&As[cb + arow2 + sk3];
        bf16x8 a32 = *(const bf16x8*)&As[cb + arow3 + sk2];
        bf16x8 a33 = *(const bf16x8*)&As[cb + arow3 + sk3];
        asm volatile("s_waitcnt lgkmcnt(0)" ::: "memory");
        __builtin_amdgcn_s_setprio(1);
        acc[2][0] = __builtin_amdgcn_mfma_f32_32x32x16_bf16(a22, b02, acc[2][0], 0, 0, 0);
        acc[2][1] = __builtin_amdgcn_mfma_f32_32x32x16_bf16(a22, b12, acc[2][1], 0, 0, 0);
        acc[3][0] = __builtin_amdgcn_mfma_f32_32x32x16_bf16(a32, b02, acc[3][0], 0, 0, 0);
        acc[3][1] = __builtin_amdgcn_mfma_f32_32x32x16_bf16(a32, b12, acc[3][1], 0, 0, 0);
        acc[2][0] = __builtin_amdgcn_mfma_f32_32x32x16_bf16(a23, b03, acc[2][0], 0, 0, 0);
        acc[2][1] = __builtin_amdgcn_mfma_f32_32x32x16_bf16(a23, b13, acc[2][1], 0, 0, 0);
        acc[3][0] = __builtin_amdgcn_mfma_f32_32x32x16_bf16(a33, b03, acc[3][0], 0, 0, 0);
        acc[3][1] = __builtin_amdgcn_mfma_f32_32x32x16_bf16(a33, b13, acc[3][1], 0, 0, 0);
        __builtin_amdgcn_s_setprio(0);
    }

    // epilogue: bf16 C = acc + bias; ni innermost.
    {
        const float bb0 = bias[n0 + wc * 64 + lc];
        const float bb1 = bias[n0 + wc * 64 + 32 + lc];
        #pragma unroll
        for (int mi = 0; mi < 4; ++mi) {
            #pragma unroll
            for (int r = 0; r < 16; ++r) {
                const int row = m0 + wr * 128 + mi * 32 + (r & 3) + 8 * (r >> 2) + 4 * q;
                ushort_t* cp = C + (size_t)row * ldc + n0 + wc * 64 + lc;
                cp[0]  = (ushort_t)f2bf(acc[mi][0][r] + bb0);
                cp[32] = (ushort_t)f2bf(acc[mi][1][r] + bb1);
            }
        }
    }
}

// ---------------------------------------------------------------------------
// 8-phase GATE GEMM (round-8, frozen): silu-only bf16 epilogue (ni innermost),
// square XCD regions. Runs EARLY.
// ---------------------------------------------------------------------------
__global__ __launch_bounds__(512)
void gemm_gate_p8(const ushort_t* __restrict__ A,
                  const ushort_t* __restrict__ Bt,
                  const float* __restrict__ bias,
                  ushort_t* __restrict__ C, int ldc,
                  int nkt)  // nkt >= 2
{
    __shared__ ushort_t As[2 * 8192];    // 32 KB
    __shared__ ushort_t Bs[2 * 16384];   // 64 KB

    const int tid = threadIdx.x;
    const int wid = tid >> 6, l = tid & 63;
    const int lc = l & 31, q = l >> 5;
    const int wr = wid >> 2, wc = wid & 3;
    int bx, by; xcd_map_gate(bx, by);
    const int m0 = by * 128, n0 = bx * 256;

    const int sra = tid >> 3;
    const int spa = (tid & 7) ^ (sra & 7);
    const ushort_t* gA = A + (size_t)(m0 + sra) * 1024 + spa * 8;
    const int srb = tid >> 2;
    const int spb = (tid & 3) ^ ((srb >> 1) & 3);
    const ushort_t* gB = Bt + (size_t)(n0 + srb) * 1024 + spb * 8;
    const int da = tid * 8;

    int arow0 = (wr * 64 +  0 + lc) * 64;
    int arow1 = (wr * 64 + 32 + lc) * 64;
    int sk0 = ((0 * 2 + q) ^ (lc & 7)) * 8;
    int sk1 = ((1 * 2 + q) ^ (lc & 7)) * 8;
    int sk2 = ((2 * 2 + q) ^ (lc & 7)) * 8;
    int sk3 = ((3 * 2 + q) ^ (lc & 7)) * 8;
    int brow0 = (wc * 64 +  0 + lc) * 32;
    int brow1 = (wc * 64 + 32 + lc) * 32;
    int tk0 = ((0 + q) ^ ((lc >> 1) & 3)) * 8;
    int tk1 = ((2 + q) ^ ((lc >> 1) & 3)) * 8;
    int tk2 = 8192 + ((0 + q) ^ ((lc >> 1) & 3)) * 8;
    int tk3 = 8192 + ((2 + q) ^ ((lc >> 1) & 3)) * 8;

    f32x16 acc[2][2];
    #pragma unroll
    for (int mi = 0; mi < 2; ++mi)
        #pragma unroll
        for (int ni = 0; ni < 2; ++ni)
            #pragma unroll
            for (int e = 0; e < 16; ++e) acc[mi][ni][e] = 0.0f;

    async_copy16(&As[da],          gA);
    async_copy16(&As[4096 + da],   gA + 65536);
    async_copy16(&Bs[da],          gB);
    async_copy16(&Bs[4096 + da],   gB + 131072);
    async_copy16(&Bs[8192 + da],   gB + 32);
    async_copy16(&Bs[12288 + da],  gB + 131072 + 32);
    gA += 64; gB += 64;
    asm volatile("s_waitcnt vmcnt(0)" ::: "memory");
    __builtin_amdgcn_s_barrier();

    int cur = 0;
    for (int t = 0; t < nkt - 1; ++t) {
        const int ca = cur * 8192,  na = 8192 - ca;
        const int cb = cur * 16384, nb = 16384 - cb;
        // ---- PH0: ks{0,1} ----
        bf16x8 a00 = *(const bf16x8*)&As[ca + arow0 + sk0];
        bf16x8 a01 = *(const bf16x8*)&As[ca + arow0 + sk1];
        bf16x8 a10 = *(const bf16x8*)&As[ca + arow1 + sk0];
        bf16x8 a11 = *(const bf16x8*)&As[ca + arow1 + sk1];
        bf16x8 b00 = *(const bf16x8*)&Bs[cb + brow0 + tk0];
        bf16x8 b01 = *(const bf16x8*)&Bs[cb + brow0 + tk1];
        bf16x8 b10 = *(const bf16x8*)&Bs[cb + brow1 + tk0];
        bf16x8 b11 = *(const bf16x8*)&Bs[cb + brow1 + tk1];
        async_copy16(&As[na + da],        gA);
        async_copy16(&As[na + 4096 + da], gA + 65536);
        async_copy16(&Bs[nb + da],        gB);
        async_copy16(&Bs[nb + 4096 + da], gB + 131072);
        __builtin_amdgcn_s_barrier();
        asm volatile("s_waitcnt lgkmcnt(0)" ::: "memory");
        __builtin_amdgcn_s_setprio(1);
        acc[0][0] = __builtin_amdgcn_mfma_f32_32x32x16_bf16(a00, b00, acc[0][0], 0, 0, 0);
        acc[0][1] = __builtin_amdgcn_mfma_f32_32x32x16_bf16(a00, b10, acc[0][1], 0, 0, 0);
        acc[1][0] = __builtin_amdgcn_mfma_f32_32x32x16_bf16(a10, b00, acc[1][0], 0, 0, 0);
        acc[1][1] = __builtin_amdgcn_mfma_f32_32x32x16_bf16(a10, b10, acc[1][1], 0, 0, 0);
        acc[0][0] = __builtin_amdgcn_mfma_f32_32x32x16_bf16(a01, b01, acc[0][0], 0, 0, 0);
        acc[0][1] = __builtin_amdgcn_mfma_f32_32x32x16_bf16(a01, b11, acc[0][1], 0, 0, 0);
        acc[1][0] = __builtin_amdgcn_mfma_f32_32x32x16_bf16(a11, b01, acc[1][0], 0, 0, 0);
        acc[1][1] = __builtin_amdgcn_mfma_f32_32x32x16_bf16(a11, b11, acc[1][1], 0, 0, 0);
        __builtin_amdgcn_s_setprio(0);
        asm volatile("s_waitcnt vmcnt(4)" ::: "memory");
        __builtin_amdgcn_s_barrier();
        // ---- PH1: ks{2,3} ----
        bf16x8 a02 = *(const bf16x8*)&As[ca + arow0 + sk2];
        bf16x8 a03 = *(const bf16x8*)&As[ca + arow0 + sk3];
        bf16x8 a12 = *(const bf16x8*)&As[ca + arow1 + sk2];
        bf16x8 a13 = *(const bf16x8*)&As[ca + arow1 + sk3];
        bf16x8 b02 = *(const bf16x8*)&Bs[cb + brow0 + tk2];
        bf16x8 b03 = *(const bf16x8*)&Bs[cb + brow0 + tk3];
        bf16x8 b12 = *(const bf16x8*)&Bs[cb + brow1 + tk2];
        bf16x8 b13 = *(const bf16x8*)&Bs[cb + brow1 + tk3];
        async_copy16(&Bs[nb + 8192 + da],  gB + 32);
        async_copy16(&Bs[nb + 12288 + da], gB + 131072 + 32);
        gA += 64; gB += 64;
        __builtin_amdgcn_s_barrier();
        asm volatile("s_waitcnt lgkmcnt(0)" ::: "memory");
        __builtin_amdgcn_s_setprio(1);
        acc[0][0] = __builtin_amdgcn_mfma_f32_32x32x16_bf16(a02, b02, acc[0][0], 0, 0, 0);
        acc[0][1] = __builtin_amdgcn_mfma_f32_32x32x16_bf16(a02, b12, acc[0][1], 0, 0, 0);
        acc[1][0] = __builtin_amdgcn_mfma_f32_32x32x16_bf16(a12, b02, acc[1][0], 0, 0, 0);
        acc[1][1] = __builtin_amdgcn_mfma_f32_32x32x16_bf16(a12, b12, acc[1][1], 0, 0, 0);
        acc[0][0] = __builtin_amdgcn_mfma_f32_32x32x16_bf16(a03, b03, acc[0][0], 0, 0, 0);
        acc[0][1] = __builtin_amdgcn_mfma_f32_32x32x16_bf16(a03, b13, acc[0][1], 0, 0, 0);
        acc[1][0] = __builtin_amdgcn_mfma_f32_32x32x16_bf16(a13, b03, acc[1][0], 0, 0, 0);
        acc[1][1] = __builtin_amdgcn_mfma_f32_32x32x16_bf16(a13, b13, acc[1][1], 0, 0, 0);
        __builtin_amdgcn_s_setprio(0);
        asm volatile("s_waitcnt vmcnt(2)" ::: "memory");
        __builtin_amdgcn_s_barrier();
        cur ^= 1;
    }

    {   // tail tile
        const int ca = cur * 8192;
        const int cb = cur * 16384;
        bf16x8 a00 = *(const bf16x8*)&As[ca + arow0 + sk0];
        bf16x8 a01 = *(const bf16x8*)&As[ca + arow0 + sk1];
        bf16x8 a10 = *(const bf16x8*)&As[ca + arow1 + sk0];
        bf16x8 a11 = *(const bf16x8*)&As[ca + arow1 + sk1];
        bf16x8 b00 = *(const bf16x8*)&Bs[cb + brow0 + tk0];
        bf16x8 b01 = *(const bf16x8*)&Bs[cb + brow0 + tk1];
        bf16x8 b10 = *(const bf16x8*)&Bs[cb + brow1 + tk0];
        bf16x8 b11 = *(const bf16x8*)&Bs[cb + brow1 + tk1];
        __builtin_amdgcn_s_barrier();
        asm volatile("s_waitcnt lgkmcnt(0)" ::: "memory");
        __builtin_amdgcn_s_setprio(1);
        acc[0][0] = __builtin_amdgcn_mfma_f32_32x32x16_bf16(a00, b00, acc[0][0], 0, 0, 0);
        acc[0][1] = __builtin_amdgcn_mfma_f32_32x32x16_bf16(a00, b10, acc[0][1], 0, 0, 0);
        acc[1][0] = __builtin_amdgcn_mfma_f32_32x32x16_bf16(a10, b00, acc[1][0], 0, 0, 0);
        acc[1][1] = __builtin_amdgcn_mfma_f32_32x32x16_bf16(a10, b10, acc[1][1], 0, 0, 0);
        acc[0][0] = __builtin_amdgcn_mfma_f32_32x32x16_bf16(a01, b01, acc[0][0], 0, 0, 0);
        acc[0][1] = __builtin_amdgcn_mfma_f32_32x32x16_bf16(a01, b11, acc[0][1], 0, 0, 0);
        acc[1][0] = __builtin_amdgcn_mfma_f32_32x32x16_bf16(a11, b01, acc[1][0], 0, 0, 0);
        acc[1][1] = __builtin_amdgcn_mfma_f32_32x32x16_bf16(a11, b11, acc[1][1], 0, 0, 0);
        __builtin_amdgcn_s_setprio(0);
        asm volatile("s_waitcnt vmcnt(0)" ::: "memory");
        __builtin_amdgcn_s_barrier();
        bf16x8 a02 = *(const bf16x8*)&As[ca + arow0 + sk2];
        bf16x8 a03 = *(const bf16x8*)&As[ca + arow0 + sk3];
        bf16x8 a12 = *(const bf16x8*)&As[ca + arow1 + sk2];
        bf16x8 a13 = *(const bf16x8*)&As[ca + arow1 + sk3];
        bf16x8 b02 = *(const bf16x8*)&Bs[cb + brow0 + tk2];
        bf16x8 b03 = *(const bf16x8*)&Bs[cb + brow0 + tk3];
        bf16x8 b12 = *(const bf16x8*)&Bs[cb + brow1 + tk2];
        bf16x8 b13 = *(const bf16x8*)&Bs[cb + brow1 + tk3];
        asm volatile("s_waitcnt lgkmcnt(0)" ::: "memory");
        __builtin_amdgcn_s_setprio(1);
        acc[0][0] = __builtin_amdgcn_mfma_f32_32x32x16_bf16(a02, b02, acc[0][0], 0, 0, 0);
        acc[0][1] = __builtin_amdgcn_mfma_f32_32x32x16_bf16(a02, b12, acc[0][1], 0, 0, 0);
        acc[1][0] = __builtin_amdgcn_mfma_f32_32x32x16_bf16(a12, b02, acc[1][0], 0, 0, 0);
        acc[1][1] = __builtin_amdgcn_mfma_f32_32x32x16_bf16(a12, b12, acc[1][1], 0, 0, 0);
        acc[0][0] = __builtin_amdgcn_mfma_f32_32x32x16_bf16(a03, b03, acc[0][0], 0, 0, 0);
        acc[0][1] = __builtin_amdgcn_mfma_f32_32x32x16_bf16(a03, b13, acc[0][1], 0, 0, 0);
        acc[1][0] = __builtin_amdgcn_mfma_f32_32x32x16_bf16(a13, b03, acc[1][0], 0, 0, 0);
        acc[1][1] = __builtin_amdgcn_mfma_f32_32x32x16_bf16(a13, b13, acc[1][1], 0, 0, 0);
        __builtin_amdgcn_s_setprio(0);
    }

    // epilogue: bf16 gate_raw = silu(acc + bias); ni innermost.
    {
        const float bb0 = bias[n0 + wc * 64 + lc];
        const float bb1 = bias[n0 + wc * 64 + 32 + lc];
        #pragma unroll
        for (int mi = 0; mi < 2; ++mi) {
            #pragma unroll
            for (int r = 0; r < 16; ++r) {
                const int row = m0 + wr * 64 + mi * 32 + (r & 3) + 8 * (r >> 2) + 4 * q;
                ushort_t* cp = C + (size_t)row * ldc + n0 + wc * 64 + lc;
                float v0 = acc[mi][0][r] + bb0;
                float v1 = acc[mi][1][r] + bb1;
                cp[0]  = (ushort_t)f2bf(v0 / (1.0f + expf(-v0)));
                cp[32] = (ushort_t)f2bf(v1 / (1.0f + expf(-v1)));
            }
        }
    }
}

// ---------------------------------------------------------------------------
// TM=64 GEMM (proj: 512 blocks, 2/CU). fp32 out + bias[col].
// Triple-buffered, depth-2 prefetch, counted vmcnt; simple XCD swizzle.
// ---------------------------------------------------------------------------
__global__ __launch_bounds__(256)
void gemm_tm64(const ushort_t* __restrict__ A, int lda,
               const ushort_t* __restrict__ Bt, int ldb,
               const float* __restrict__ bias,
               float* __restrict__ C, int ldc, int nkt)  // nkt >= 3
{
    __shared__ ushort_t As[3 * 64 * 32];
    __shared__ ushort_t Bs[3 * 128 * 32];

    const int tid = threadIdx.x;
    const int w  = tid >> 6, l = tid & 63;
    const int lc = l & 31, q = l >> 5;
    const int wr = w >> 1, wc = w & 1;
    int bx, by; xcd_tile(bx, by);
    const int m0 = by * 64, n0 = bx * 128;

    const int rA = tid >> 2,          kcA = (tid & 3) ^ ((rA >> 1) & 3);
    const int rB1 = (256 + tid) >> 2, kcB1 = (tid & 3) ^ ((rB1 >> 1) & 3);
    const ushort_t* gA  = A  + (size_t)(m0 + rA)  * lda + kcA  * 8;
    const ushort_t* gB0 = Bt + (size_t)(n0 + rA)  * ldb + kcA  * 8;
    const ushort_t* gB1 = Bt + (size_t)(n0 + rB1) * ldb + kcB1 * 8;
    const int sA  = w * 512;
    const int sB0 = w * 512;
    const int sB1 = 2048 + w * 512;

    const int sl = (lc >> 1) & 3;
    int aoff[2], boff[2][2];
    #pragma unroll
    for (int ks = 0; ks < 2; ++ks) {
        const int kk = ks * 2 + q;
        const int mrow = wr * 32 + lc;
        aoff[ks] = (mrow * 4 + (kk ^ sl)) * 8;
        #pragma unroll
        for (int ni = 0; ni < 2; ++ni) {
            const int nrow = wc * 64 + ni * 32 + lc;
            boff[ni][ks] = (nrow * 4 + (kk ^ sl)) * 8;
        }
    }

    f32x16 acc[2];
    #pragma unroll
    for (int ni = 0; ni < 2; ++ni)
        #pragma unroll
        for (int e = 0; e < 16; ++e) acc[ni][e] = 0.0f;

    auto stage = [&](int ab, int bb) {
        async_copy16(&As[ab + sA], gA);
        async_copy16(&Bs[bb + sB0], gB0); async_copy16(&Bs[bb + sB1], gB1);
        gA += 32; gB0 += 32; gB1 += 32;
    };
    auto compute = [&](int ab, int bb) {
        bf16x8 a[2], b[2][2];
        #pragma unroll
        for (int ks = 0; ks < 2; ++ks) {
            a[ks] = *(const bf16x8*)&As[ab + aoff[ks]];
            b[0][ks] = *(const bf16x8*)&Bs[bb + boff[0][ks]];
            b[1][ks] = *(const bf16x8*)&Bs[bb + boff[1][ks]];
        }
        #pragma unroll
        for (int ks = 0; ks < 2; ++ks)
            #pragma unroll
            for (int ni = 0; ni < 2; ++ni)
                acc[ni] = __builtin_amdgcn_mfma_f32_32x32x16_bf16(
                    a[ks], b[ni][ks], acc[ni], 0, 0, 0);
    };

    stage(0, 0); stage(2048, 4096);
    int as_ = 4096, bs_ = 8192;
    int ac_ = 0,    bc_ = 0;
    for (int kt = 0; kt < nkt - 2; ++kt) {
        asm volatile("s_waitcnt vmcnt(3)" ::: "memory");
        __builtin_amdgcn_s_barrier();
        stage(as_, bs_);
        compute(ac_, bc_);
        as_ = ac_; bs_ = bc_;
        ac_ = (ac_ == 4096) ? 0 : ac_ + 2048;
        bc_ = (bc_ == 8192) ? 0 : bc_ + 4096;
    }
    asm volatile("s_waitcnt vmcnt(3)" ::: "memory");
    __builtin_amdgcn_s_barrier();
    compute(ac_, bc_);
    ac_ = (ac_ == 4096) ? 0 : ac_ + 2048;
    bc_ = (bc_ == 8192) ? 0 : bc_ + 4096;
    asm volatile("s_waitcnt vmcnt(0)" ::: "memory");
    __builtin_amdgcn_s_barrier();
    compute(ac_, bc_);

    #pragma unroll
    for (int ni = 0; ni < 2; ++ni) {
        const int col = n0 + wc * 64 + ni * 32 + lc;
        const float bb = bias[col];
        #pragma unroll
        for (int r = 0; r < 16; ++r) {
            const int row = m0 + wr * 32 + (r & 3) + 8 * (r >> 2) + 4 * q;
            C[(size_t)row * ldc + col] = acc[ni][r] + bb;
        }
    }
}

// ---------------------------------------------------------------------------
// Fused qkv prep: one launch does {qk_prep (xpos rotate), v_transpose}.
// Block-uniform branch:
//   [0,4096):      qk_prep row = blk
//   [4096,12288):  v_transpose: u = blk-4096; jx = u % 64; zz = u / 64
// ---------------------------------------------------------------------------
__global__ __launch_bounds__(256)
void qkv_prep(const ushort_t* __restrict__ qkvb,
              ushort_t* __restrict__ qh, ushort_t* __restrict__ kh,
              ushort_t* __restrict__ vt)
{
    __shared__ ushort_t tile[32][40];
    const int blk = blockIdx.x;
    const int t = threadIdx.x;
    if (blk < 4096) {
        // ---------------- qk_prep ----------------
        const int row = blk;
        const int b = row >> 11, trow = row & (T_SEQ - 1);
        const bool isK = t >= 128;
        const int col0 = (t & 127) * 8;
        const int h = col0 >> 7, d = col0 & 127;

        float ld, gamma;
        decay_params(h, ld, gamma);
        const float gsc = __expf(isK ? -ld * (float)(trow & 63) : ld * (float)(trow & 63));

        const ushort_t* src = qkvb + (size_t)row * 4096 + (isK ? E_DIM : 0) + col0;
        bf16x8 xv8 = *(const bf16x8*)src;
        float xv[8];
        #pragma unroll
        for (int p = 0; p < 8; ++p) xv[p] = bf2f((ushort_t)xv8[p]);

        const float tf = (float)trow * (1.0f / 512.0f);
        bf16x8 o;
        #pragma unroll
        for (int pi = 0; pi < 4; ++pi) {
            const int ip = col0 / 2 + pi;
            float sv = (2.0f * (float)ip + 409.6f) * (1.0f / 1433.6f);
            float e = __logf(sv) * tf;
            if (isK) e = -e;
            float sc = __expf(e);
            float invf = __expf((float)ip * -0.017988946038999563f);  // -ln(1e4)/512
            float sn, cs;
            sincosf((float)trow * invf, &sn, &cs);
            float c = cs * sc * gsc, s = sn * sc * gsc;
            float a = xv[2 * pi], bb = xv[2 * pi + 1];
            o[2 * pi]     = f2bf(a * c - bb * s);
            o[2 * pi + 1] = f2bf(bb * c + a * s);
        }
        ushort_t* dst = (isK ? kh : qh) + ((size_t)(b * 8 + h) * T_SEQ + trow) * 128 + d;
        *(bf16x8*)dst = o;
    } else {
        // ---------------- v_transpose ----------------
        const int u = blk - 4096;
        const int j0 = (u & 63) * 32;
        const int zz = u >> 6;
        const int bh = zz >> 3, v0 = (zz & 7) * 32;
        const int b = bh >> 3, h = bh & 7;
        const int r = t >> 3, c = (t & 7) * 4;

        *(u16x4*)&tile[r][c] = *(const u16x4*)(qkvb + (size_t)(b * T_SEQ + j0 + r) * 4096
                                               + 2 * E_DIM + h * DV + v0 + c);
        __syncthreads();
        u16x4 o;
        o[0] = tile[c][r];
        o[1] = tile[c + 1][r];
        o[2] = tile[c + 2][r];
        o[3] = tile[c + 3][r];
        *(u16x4*)&vt[((size_t)bh * 256 + v0 + r) * T_SEQ + j0 + c] = o;
    }
}

// ---------------------------------------------------------------------------
// kt2 = gamma^63 * kh^T per head: [bh][T][128] -> [bh][128][T]
// ---------------------------------------------------------------------------
__global__ __launch_bounds__(256)
void kt2_kernel(const ushort_t* __restrict__ kh, ushort_t* __restrict__ kt2)
{
    __shared__ ushort_t tile[32][40];
    const int j0 = blockIdx.x * 32;
    const int zz = blockIdx.y;
    const int bh = zz >> 2, k0 = (zz & 3) * 32;
    const int t = threadIdx.x;
    const int r = t >> 3, c = (t & 7) * 4;
    float ld, gamma; decay_params(bh & 7, ld, gamma);
    const float g63 = expf(ld * 63.0f);
    *(u16x4*)&tile[r][c] = *(const u16x4*)&kh[((size_t)bh * T_SEQ + j0 + r) * 128 + k0 + c];
    __syncthreads();
    u16x4 o;
    o[0] = (ushort_t)f2bf(bf2f(tile[c][r])     * g63);
    o[1] = (ushort_t)f2bf(bf2f(tile[c + 1][r]) * g63);
    o[2] = (ushort_t)f2bf(bf2f(tile[c + 2][r]) * g63);
    o[3] = (ushort_t)f2bf(bf2f(tile[c + 3][r]) * g63);
    *(u16x4*)&kt2[((size_t)bh * 128 + k0 + r) * T_SEQ + j0 + c] = o;
}

// ---------------------------------------------------------------------------
// Phase A: A_c[v][k] = sum_{j in chunk} vt[v][j] * kt2[k][j]  (bf16)
// ---------------------------------------------------------------------------
__global__ __launch_bounds__(256)
void chunk_kv(const ushort_t* __restrict__ vt, const ushort_t* __restrict__ kt2,
              ushort_t* __restrict__ Abuf)
{
    const int c = blockIdx.x;
    const int bh = blockIdx.y;
    const int tid = threadIdx.x;
    const int w = tid >> 6, l = tid & 63, lc = l & 31, q = l >> 5;
    const int j0 = c * 64;

    f32x16 acc[2][4];
    #pragma unroll
    for (int mi = 0; mi < 2; ++mi)
        #pragma unroll
        for (int ni = 0; ni < 4; ++ni)
            #pragma unroll
            for (int e = 0; e < 16; ++e) acc[mi][ni][e] = 0.0f;

    #pragma unroll
    for (int ks = 0; ks < 4; ++ks) {
        bf16x8 a[2], bfr[4];
        #pragma unroll
        for (int mi = 0; mi < 2; ++mi)
            a[mi] = *(const bf16x8*)(vt + ((size_t)bh * 256 + w * 64 + mi * 32 + lc) * T_SEQ
                                     + j0 + ks * 16 + q * 8);
        #pragma unroll
        for (int ni = 0; ni < 4; ++ni)
            bfr[ni] = *(const bf16x8*)(kt2 + ((size_t)bh * 128 + ni * 32 + lc) * T_SEQ
                                       + j0 + ks * 16 + q * 8);
        #pragma unroll
        for (int mi = 0; mi < 2; ++mi)
            #pragma unroll
            for (int ni = 0; ni < 4; ++ni)
                acc[mi][ni] = __builtin_amdgcn_mfma_f32_32x32x16_bf16(
                    a[mi], bfr[ni], acc[mi][ni], 0, 0, 0);
    }

    ushort_t* ab = Abuf + (size_t)(bh * 32 + c) * 256 * 128;
    #pragma unroll
    for (int mi = 0; mi < 2; ++mi)
        #pragma unroll
        for (int ni = 0; ni < 4; ++ni)
            #pragma unroll
            for (int r = 0; r < 16; ++r) {
                const int v = w * 64 + mi * 32 + (r & 3) + 8 * (r >> 2) + 4 * q;
                const int k = ni * 32 + lc;
                ab[(size_t)v * 128 + k] = (ushort_t)f2bf(acc[mi][ni][r]);
            }
}

// ---------------------------------------------------------------------------
// Phase B: IN-PLACE scan over chunks.  NOTE: Abuf and St intentionally alias
// (no __restrict__): Abuf[off] is read BEFORE St[off] is written.
// ---------------------------------------------------------------------------
__global__ __launch_bounds__(256)
void scan_state(const ushort_t* Abuf, ushort_t* St,
                float* __restrict__ ckv)
{
    const int blk = blockIdx.x;
    const int bh = blk >> 7, sub = blk & 127;
    const int tid = threadIdx.x;
    const int v = sub * 2 + (tid >> 7), k = tid & 127;

    float ld, gamma;
    decay_params(bh & 7, ld, gamma);
    const float g64 = expf(ld * 64.0f);

    const size_t base = ((size_t)bh * 32 * 256 + v) * 128 + k;
    const size_t cstr = 256 * 128;
    float s = 0.0f;
    for (int c = 0; c < 32; ++c) {
        const size_t off = base + (size_t)c * cstr;
        const float a = bf2f(Abuf[off]);     // read BEFORE the aliased write
        St[off] = (ushort_t)f2bf(gamma * s);
        s = g64 * s + a;
    }
    const float inv_scale = rsqrtf((1.0f - expf(ld * (float)T_SEQ)) / (1.0f - gamma));
    ckv[((size_t)bh * 128 + k) * 256 + v] = s * inv_scale;
}

// ---------------------------------------------------------------------------
// Phase C: per-i-tile output, single-wave blocks, fused groupnorm AND gating
// multiply (gate_raw = silu(hs@w_g+b_g) precomputed) -> bf16 gated.
// ---------------------------------------------------------------------------
__global__ __launch_bounds__(64)
void retention_chunk(const ushort_t* __restrict__ qh,
                     const ushort_t* __restrict__ kh,
                     const ushort_t* __restrict__ vt,
                     const ushort_t* __restrict__ St,
                     const ushort_t* __restrict__ grw,
                     ushort_t* __restrict__ gated)
{
    const int it = blockIdx.x;
    const int bh = blockIdx.y;
    const int b = bh >> 3, h = bh & 7;
    const int c = it >> 1, w = it & 1;
    const int l = threadIdx.x, lc = l & 31, q = l >> 5;
    const int i0 = it * 32;
    const size_t bhT = (size_t)bh * T_SEQ;

    float ld, gamma;
    decay_params(h, ld, gamma);

    bf16x8 qf[8];
    {
        const ushort_t* qp = qh + (bhT + i0 + lc) * 128 + q * 8;
        #pragma unroll
        for (int c8 = 0; c8 < 8; ++c8)
            qf[c8] = *(const bf16x8*)(qp + c8 * 16);
    }

    f32x16 acc[8];
    #pragma unroll
    for (int vg = 0; vg < 8; ++vg)
        #pragma unroll
        for (int e = 0; e < 16; ++e) acc[vg][e] = 0.0f;

    if (c > 0) {
        const ushort_t* sp = St + ((size_t)(bh * 32 + c) * 256 + lc) * 128 + q * 8;
        #pragma unroll
        for (int vg = 0; vg < 8; ++vg) {
            const ushort_t* spv = sp + (size_t)vg * 32 * 128;
            #pragma unroll
            for (int ks = 0; ks < 8; ++ks) {
                bf16x8 sb = *(const bf16x8*)(spv + ks * 16);
                acc[vg] = __builtin_amdgcn_mfma_f32_32x32x16_bf16(
                    qf[ks], sb, acc[vg], 0, 0, 0);
            }
        }
    }

    for (int jt2 = 0; jt2 <= w; ++jt2) {
        const int j0 = c * 64 + jt2 * 32;

        f32x16 s;
        #pragma unroll
        for (int e = 0; e < 16; ++e) s[e] = 0.0f;
        const ushort_t* kp = kh + (bhT + j0 + lc) * 128 + q * 8;
        #pragma unroll
        for (int c8 = 0; c8 < 8; ++c8) {
            bf16x8 ka = *(const bf16x8*)(kp + c8 * 16);
            s = __builtin_amdgcn_mfma_f32_32x32x16_bf16(ka, qf[c8], s, 0, 0, 0);
        }

        float sv[16];
        #pragma unroll
        for (int r = 0; r < 16; ++r) {
            float val = s[r];
            if (jt2 == w) {
                int jr_ = (r & 3) + 8 * (r >> 2) + 4 * q;
                val = (jr_ <= lc) ? val : 0.0f;
            }
            sv[r] = val;
        }

        bf16x8 pa0, pa1;
        #pragma unroll
        for (int e = 0; e < 4; ++e) {
            float t1 = __shfl_xor(sv[e + 4], 32);
            float t0 = __shfl_xor(sv[e], 32);
            pa0[e]     = f2bf(q ? t1 : sv[e]);
            pa0[e + 4] = f2bf(q ? sv[e + 4] : t0);
            float t3 = __shfl_xor(sv[e + 12], 32);
            float t2 = __shfl_xor(sv[e + 8], 32);
            pa1[e]     = f2bf(q ? t3 : sv[e + 8]);
            pa1[e + 4] = f2bf(q ? sv[e + 12] : t2);
        }

        #pragma unroll
        for (int vg = 0; vg < 8; ++vg) {
            const ushort_t* vp = vt + ((size_t)bh * 256 + vg * 32 + lc) * T_SEQ + j0 + q * 8;
            bf16x8 vb0 = *(const bf16x8*)vp;
            bf16x8 vb1 = *(const bf16x8*)(vp + 16);
            acc[vg] = __builtin_amdgcn_mfma_f32_32x32x16_bf16(pa0, vb0, acc[vg], 0, 0, 0);
            acc[vg] = __builtin_amdgcn_mfma_f32_32x32x16_bf16(pa1, vb1, acc[vg], 0, 0, 0);
        }
    }

    #pragma unroll
    for (int r = 0; r < 16; ++r) {
        const int il = (r & 3) + 8 * (r >> 2) + 4 * q;
        const int i  = i0 + il;
        float denom = (1.0f - expf(ld * (float)(i + 1))) / (1.0f - gamma);
        float fs = 0.08838834764831845f * rsqrtf(denom);
        float vals[8];
        float a1 = 0.0f, a2 = 0.0f;
        #pragma unroll
        for (int vg = 0; vg < 8; ++vg) {
            float x = acc[vg][r] * fs;
            vals[vg] = x;
            a1 += x; a2 += x * x;
        }
        a1 += __shfl_xor(a1, 1);  a2 += __shfl_xor(a2, 1);
        a1 += __shfl_xor(a1, 2);  a2 += __shfl_xor(a2, 2);
        a1 += __shfl_xor(a1, 4);  a2 += __shfl_xor(a2, 4);
        a1 += __shfl_xor(a1, 8);  a2 += __shfl_xor(a2, 8);
        a1 += __shfl_xor(a1, 16); a2 += __shfl_xor(a2, 16);
        float mu = a1 * (1.0f / 256.0f);
        float var = a2 * (1.0f / 256.0f) - mu * mu;
        float rs = rsqrtf(var + 1e-5f);
        const size_t ob = ((size_t)(b * T_SEQ + i)) * V_DIM + h * DV + lc;
        ushort_t* op = gated + ob;
        const ushort_t* gp = grw + ob;
        #pragma unroll
        for (int vg = 0; vg < 8; ++vg) {
            float g = bf2f(gp[vg * 32]);
            op[vg * 32] = (ushort_t)f2bf((vals[vg] - mu) * rs * g);
        }
    }
}

// ---------------------------------------------------------------------------
extern "C" void kernel_launch(void* const* d_in, const int* in_sizes, int n_in,
                              void* d_out, int out_size, void* d_ws, size_t ws_size,
                              hipStream_t stream)
{
    const float* hs    = (const float*)d_in[0];
    const float* w_qkv = (const float*)d_in[1];
    const float* b_qkv = (const float*)d_in[2];
    const float* w_g   = (const float*)d_in[3];
    const float* b_g   = (const float*)d_in[4];
    const float* w_p   = (const float*)d_in[5];
    const float* b_p   = (const float*)d_in[6];
    float* out = (float*)d_out;

    const size_t MB = 1024 * 1024;
    // ws (96MB) timeline (qkv bf16, in-place scan):
    //   [0,32):  qkv_bf (qkv GEMM -> preps)  ->  Abuf (chunk_kv -> scan)
    //            -> St IN-PLACE (scan -> retention) -> wp_t@[0,4) (-> proj)
    //   [32,48): gate_raw (gate GEMM -> retention)
    //   [48,64): gated (retention -> proj)
    //   [64,72): wg_t@[64,68) (-> gate GEMM) -> qh (qkv_prep -> retention)
    //   [72,88): vt (qkv_prep -> retention)
    //   [88,96): wqkv_t (-> qkv GEMM) -> kh (qkv_prep -> kt2/retention)
    // d_out (18MB): hs_bf@[0,8), kt2@[8,16) — dead before proj store;
    //               proj writes out@[0,16) at the END; ckv@[16,18).
    // NOTE: qh/kh overwrite wg_t/wqkv_t, which are dead only after BOTH GEMMs
    // have run — qkv_prep runs after both, so the ordering is safe.
    ushort_t* qkv_bf   = (ushort_t*)d_ws;
    ushort_t* Abuf     = (ushort_t*)d_ws;               // aliases qkv_bf (dead)
    ushort_t* Stbuf    = (ushort_t*)d_ws;               // IN-PLACE with Abuf
    ushort_t* wp_t     = (ushort_t*)d_ws;               // after retention
    ushort_t* gate_raw = (ushort_t*)((char*)d_ws + 32 * MB);
    ushort_t* gated_bf = (ushort_t*)((char*)d_ws + 48 * MB);
    ushort_t* wg_t     = (ushort_t*)((char*)d_ws + 64 * MB);
    ushort_t* qh       = (ushort_t*)((char*)d_ws + 64 * MB);  // after wg_t dead
    ushort_t* vt       = (ushort_t*)((char*)d_ws + 72 * MB);
    ushort_t* wqkv_t   = (ushort_t*)((char*)d_ws + 88 * MB);
    ushort_t* kh       = (ushort_t*)((char*)d_ws + 88 * MB);  // after wqkv_t dead
    ushort_t* hs_bf    = (ushort_t*)d_out;
    ushort_t* kt2      = (ushort_t*)((char*)d_out + 8 * MB);
    float*    ckv_out  = out + (size_t)BT * E_DIM;

    // 1. batched conversions: hs->bf16, w_qkv^T, w_g^T (one launch)
    prep_batch<<<dim3(8192), 256, 0, stream>>>(hs, hs_bf, w_qkv, wqkv_t, w_g, wg_t);

    // 2. gate_raw = silu(hs @ w_g + b_g)
    gemm_gate_p8<<<dim3(8, 32), 512, 0, stream>>>(
        hs_bf, wg_t, b_g, gate_raw, V_DIM, E_DIM / 64);

    // 3. qkv = hs @ w_qkv + b_qkv -> bf16 (round-8 proven 8-phase 256x256)
    gemm256p8<<<dim3(16, 16), 512, 0, stream>>>(
        hs_bf, wqkv_t, b_qkv, qkv_bf, 4096, E_DIM / 64);

    // 4. fused preps: qk xpos + v transpose (one launch)
    qkv_prep<<<dim3(12288), 256, 0, stream>>>(qkv_bf, qh, kh, vt);
    kt2_kernel<<<dim3(64, 64), 256, 0, stream>>>(kh, kt2);

    // 5. chunked retention: A (over dead qkv_bf) -> in-place scan -> outputs
    chunk_kv<<<dim3(32, 16), 256, 0, stream>>>(vt, kt2, Abuf);
    scan_state<<<dim3(2048), 256, 0, stream>>>(Abuf, Stbuf, ckv_out);
    retention_chunk<<<dim3(64, 16), 64, 0, stream>>>(qh, kh, vt, Stbuf, gate_raw, gated_bf);

    // 6. proj = gated @ w_p + b_p  (wp_t over dead St; out over dead hs_bf/kt2)
    transpose_w_kernel<<<dim3(32, 64), 256, 0, stream>>>(w_p, wp_t, V_DIM, E_DIM);
    gemm_tm64<<<dim3(8, 64), 256, 0, stream>>>(
        gated_bf, V_DIM, wp_t, V_DIM, b_p, out, E_DIM, V_DIM / 32);
}

// Round 11
// 291.802 us; speedup vs baseline: 1.0192x; 1.0129x over previous
//
#include <hip/hip_runtime.h>
#include <math.h>

#define BT      4096
#define T_SEQ   2048
#define E_DIM   1024
#define V_DIM   2048
#define DK      128
#define DV      256

typedef unsigned short ushort_t;
typedef __attribute__((ext_vector_type(8)))  short bf16x8;
typedef __attribute__((ext_vector_type(4)))  unsigned short u16x4;
typedef __attribute__((ext_vector_type(16))) float f32x16;

__device__ __forceinline__ void decay_params(int h, float& ld, float& gamma) {
    const float s0 = -3.4657359027997265f;  // ln(1/32)
    const float e0 = -6.2383246250395092f;  // ln(1/512)
    float lin = s0 + (e0 - s0) * ((float)h * (1.0f / 7.0f));
    gamma = 1.0f - expf(lin);
    ld = logf(gamma);
}

__device__ __forceinline__ short f2bf(float f) {
    unsigned u = __float_as_uint(f);
    unsigned r = (u + 0x7fffu + ((u >> 16) & 1u)) >> 16;
    return (short)r;
}
__device__ __forceinline__ float bf2f(ushort_t u) {
    return __uint_as_float((unsigned)u << 16);
}

__device__ __forceinline__ void async_copy16(void* lds, const void* g) {
    __builtin_amdgcn_global_load_lds(
        (const __attribute__((address_space(1))) unsigned int*)g,
        (__attribute__((address_space(3))) unsigned int*)lds, 16, 0, 0);
}

// Simple XCD swizzle (contiguous strip per XCD) — used by tm64.
__device__ __forceinline__ void xcd_tile(int& bx, int& by) {
    const int nwgx = gridDim.x;
    const int nwg  = nwgx * gridDim.y;
    int bid = blockIdx.y * nwgx + blockIdx.x;
    bid = (bid & 7) * (nwg >> 3) + (bid >> 3);
    bx = bid % nwgx;
    by = bid / nwgx;
}

// Square XCD regions for qkv grid (16,16): each XCD owns 8 n-cols x 4 m-rows.
__device__ __forceinline__ void xcd_map_qkv(int& bx, int& by) {
    int bid = blockIdx.y * 16 + blockIdx.x;
    const int xcd = bid & 7, idx = bid >> 3;            // idx in [0,32)
    bx = (xcd & 1) * 8 + (idx & 7);
    by = (xcd >> 1) * 4 + (idx >> 3);
}

// Square XCD regions for gate grid (8,32): each XCD owns 4 n-cols x 8 m-rows.
__device__ __forceinline__ void xcd_map_gate(int& bx, int& by) {
    int bid = blockIdx.y * 8 + blockIdx.x;
    const int xcd = bid & 7, idx = bid >> 3;            // idx in [0,32)
    bx = (xcd & 1) * 4 + (idx & 3);
    by = (xcd >> 1) * 8 + (idx >> 2);
}

// ---------------------------------------------------------------------------
// Batched prep: one launch does {w_qkv transpose, w_g transpose, hs f32->bf16}.
// ---------------------------------------------------------------------------
__device__ __forceinline__ void transpose_tile_body(
    const float* __restrict__ W, ushort_t* __restrict__ Wt,
    int K, int N, int bx, int by, float (*tile)[33], int t)
{
    const int k0 = by * 32, n0 = bx * 32;
    const int r = t >> 3, c = (t & 7) * 4;
    float4 v = *(const float4*)&W[(size_t)(k0 + r) * N + n0 + c];
    tile[r][c] = v.x; tile[r][c + 1] = v.y; tile[r][c + 2] = v.z; tile[r][c + 3] = v.w;
    __syncthreads();
    u16x4 o;
    o[0] = (ushort_t)f2bf(tile[c][r]);
    o[1] = (ushort_t)f2bf(tile[c + 1][r]);
    o[2] = (ushort_t)f2bf(tile[c + 2][r]);
    o[3] = (ushort_t)f2bf(tile[c + 3][r]);
    *(u16x4*)&Wt[(size_t)(n0 + r) * K + k0 + c] = o;
}

__global__ __launch_bounds__(256)
void prep_batch(const float* __restrict__ hs, ushort_t* __restrict__ hs_bf,
                const float* __restrict__ w_qkv, ushort_t* __restrict__ wqkv_t,
                const float* __restrict__ w_g, ushort_t* __restrict__ wg_t)
{
    __shared__ float tile[32][33];
    const int t = threadIdx.x;
    const int blk = blockIdx.x;
    if (blk < 4096) {
        transpose_tile_body(w_qkv, wqkv_t, 1024, 4096, blk % 128, blk / 128, tile, t);
    } else if (blk < 6144) {
        const int u = blk - 4096;
        transpose_tile_body(w_g, wg_t, 1024, 2048, u % 64, u / 64, tile, t);
    } else {
        const int u = blk - 6144;
        int i = (u * 256 + t) * 8;
        float4 a = *(const float4*)&hs[i];
        float4 b = *(const float4*)&hs[i + 4];
        bf16x8 o;
        o[0] = f2bf(a.x); o[1] = f2bf(a.y); o[2] = f2bf(a.z); o[3] = f2bf(a.w);
        o[4] = f2bf(b.x); o[5] = f2bf(b.y); o[6] = f2bf(b.z); o[7] = f2bf(b.w);
        *(bf16x8*)&hs_bf[i] = o;
    }
}

// ---------------------------------------------------------------------------
// W[K][N] fp32 -> Wt[N][K] bf16 (standalone; used late for w_p only)
// ---------------------------------------------------------------------------
__global__ __launch_bounds__(256)
void transpose_w_kernel(const float* __restrict__ W, ushort_t* __restrict__ Wt,
                        int K, int N)
{
    __shared__ float tile[32][33];
    transpose_tile_body(W, Wt, K, N, blockIdx.x, blockIdx.y, tile, threadIdx.x);
}

// ---------------------------------------------------------------------------
// 8-PHASE 256x256 GEMM for qkv (round-8 proven; frozen)
// ---------------------------------------------------------------------------
__global__ __launch_bounds__(512, 2)
void gemm256p8(const ushort_t* __restrict__ A,
               const ushort_t* __restrict__ Bt,
               const float* __restrict__ bias,
               ushort_t* __restrict__ C, int ldc, int nkt)  // nkt >= 2
{
    __shared__ ushort_t As[2 * 16384];   // 64 KB
    __shared__ ushort_t Bs[2 * 16384];   // 64 KB

    const int tid = threadIdx.x;
    const int wid = tid >> 6, l = tid & 63;
    const int lc = l & 31, q = l >> 5;
    const int wr = wid >> 2, wc = wid & 3;
    int bx, by; xcd_map_qkv(bx, by);
    const int m0 = by * 256, n0 = bx * 256;

    const int sra = tid >> 3;
    const int spa = (tid & 7) ^ (sra & 7);
    const ushort_t* gA = A + (size_t)(m0 + sra) * 1024 + spa * 8;
    const int srb = tid >> 2;
    const int spb = (tid & 3) ^ ((srb >> 1) & 3);
    const ushort_t* gB = Bt + (size_t)(n0 + srb) * 1024 + spb * 8;
    const int da = tid * 8;

    int arow0 = (wr * 128 +  0 + lc) * 64;
    int arow1 = (wr * 128 + 32 + lc) * 64;
    int arow2 = (wr * 128 + 64 + lc) * 64;
    int arow3 = (wr * 128 + 96 + lc) * 64;
    int sk0 = ((0 * 2 + q) ^ (lc & 7)) * 8;
    int sk1 = ((1 * 2 + q) ^ (lc & 7)) * 8;
    int sk2 = ((2 * 2 + q) ^ (lc & 7)) * 8;
    int sk3 = ((3 * 2 + q) ^ (lc & 7)) * 8;
    int brow0 = (wc * 64 +  0 + lc) * 32;
    int brow1 = (wc * 64 + 32 + lc) * 32;
    int tk0 = ((0 + q) ^ ((lc >> 1) & 3)) * 8;
    int tk1 = ((2 + q) ^ ((lc >> 1) & 3)) * 8;
    int tk2 = 8192 + ((0 + q) ^ ((lc >> 1) & 3)) * 8;
    int tk3 = 8192 + ((2 + q) ^ ((lc >> 1) & 3)) * 8;

    f32x16 acc[4][2];
    #pragma unroll
    for (int mi = 0; mi < 4; ++mi)
        #pragma unroll
        for (int ni = 0; ni < 2; ++ni)
            #pragma unroll
            for (int e = 0; e < 16; ++e) acc[mi][ni][e] = 0.0f;

    async_copy16(&As[da],          gA);
    async_copy16(&As[8192 + da],   gA + 131072);
    async_copy16(&Bs[da],          gB);
    async_copy16(&Bs[4096 + da],   gB + 131072);
    async_copy16(&As[4096 + da],   gA + 65536);
    async_copy16(&As[12288 + da],  gA + 196608);
    async_copy16(&Bs[8192 + da],   gB + 32);
    async_copy16(&Bs[12288 + da],  gB + 131072 + 32);
    gA += 64; gB += 64;
    asm volatile("s_waitcnt vmcnt(0)" ::: "memory");
    __builtin_amdgcn_s_barrier();

    int cur = 0;
    for (int t = 0; t < nkt - 1; ++t) {
        const int cb = cur * 16384;
        const int nb = 16384 - cb;
        // ---- PH0 ----
        bf16x8 a00 = *(const bf16x8*)&As[cb + arow0 + sk0];
        bf16x8 a01 = *(const bf16x8*)&As[cb + arow0 + sk1];
        bf16x8 a10 = *(const bf16x8*)&As[cb + arow1 + sk0];
        bf16x8 a11 = *(const bf16x8*)&As[cb + arow1 + sk1];
        bf16x8 b00 = *(const bf16x8*)&Bs[cb + brow0 + tk0];
        bf16x8 b01 = *(const bf16x8*)&Bs[cb + brow0 + tk1];
        bf16x8 b10 = *(const bf16x8*)&Bs[cb + brow1 + tk0];
        bf16x8 b11 = *(const bf16x8*)&Bs[cb + brow1 + tk1];
        async_copy16(&As[nb + da],        gA);
        async_copy16(&As[nb + 8192 + da], gA + 131072);
        async_copy16(&Bs[nb + da],        gB);
        async_copy16(&Bs[nb + 4096 + da], gB + 131072);
        __builtin_amdgcn_s_barrier();
        asm volatile("s_waitcnt lgkmcnt(0)" ::: "memory");
        __builtin_amdgcn_s_setprio(1);
        acc[0][0] = __builtin_amdgcn_mfma_f32_32x32x16_bf16(a00, b00, acc[0][0], 0, 0, 0);
        acc[0][1] = __builtin_amdgcn_mfma_f32_32x32x16_bf16(a00, b10, acc[0][1], 0, 0, 0);
        acc[1][0] = __builtin_amdgcn_mfma_f32_32x32x16_bf16(a10, b00, acc[1][0], 0, 0, 0);
        acc[1][1] = __builtin_amdgcn_mfma_f32_32x32x16_bf16(a10, b10, acc[1][1], 0, 0, 0);
        acc[0][0] = __builtin_amdgcn_mfma_f32_32x32x16_bf16(a01, b01, acc[0][0], 0, 0, 0);
        acc[0][1] = __builtin_amdgcn_mfma_f32_32x32x16_bf16(a01, b11, acc[0][1], 0, 0, 0);
        acc[1][0] = __builtin_amdgcn_mfma_f32_32x32x16_bf16(a11, b01, acc[1][0], 0, 0, 0);
        acc[1][1] = __builtin_amdgcn_mfma_f32_32x32x16_bf16(a11, b11, acc[1][1], 0, 0, 0);
        __builtin_amdgcn_s_setprio(0);
        asm volatile("s_waitcnt vmcnt(6)" ::: "memory");
        __builtin_amdgcn_s_barrier();
        // ---- PH1 ----
        bf16x8 a20 = *(const bf16x8*)&As[cb + arow2 + sk0];
        bf16x8 a21 = *(const bf16x8*)&As[cb + arow2 + sk1];
        bf16x8 a30 = *(const bf16x8*)&As[cb + arow3 + sk0];
        bf16x8 a31 = *(const bf16x8*)&As[cb + arow3 + sk1];
        async_copy16(&As[nb + 4096 + da],  gA + 65536);
        async_copy16(&As[nb + 12288 + da], gA + 196608);
        __builtin_amdgcn_s_barrier();
        asm volatile("s_waitcnt lgkmcnt(0)" ::: "memory");
        __builtin_amdgcn_s_setprio(1);
        acc[2][0] = __builtin_amdgcn_mfma_f32_32x32x16_bf16(a20, b00, acc[2][0], 0, 0, 0);
        acc[2][1] = __builtin_amdgcn_mfma_f32_32x32x16_bf16(a20, b10, acc[2][1], 0, 0, 0);
        acc[3][0] = __builtin_amdgcn_mfma_f32_32x32x16_bf16(a30, b00, acc[3][0], 0, 0, 0);
        acc[3][1] = __builtin_amdgcn_mfma_f32_32x32x16_bf16(a30, b10, acc[3][1], 0, 0, 0);
        acc[2][0] = __builtin_amdgcn_mfma_f32_32x32x16_bf16(a21, b01, acc[2][0], 0, 0, 0);
        acc[2][1] = __builtin_amdgcn_mfma_f32_32x32x16_bf16(a21, b11, acc[2][1], 0, 0, 0);
        acc[3][0] = __builtin_amdgcn_mfma_f32_32x32x16_bf16(a31, b01, acc[3][0], 0, 0, 0);
        acc[3][1] = __builtin_amdgcn_mfma_f32_32x32x16_bf16(a31, b11, acc[3][1], 0, 0, 0);
        __builtin_amdgcn_s_setprio(0);
        asm volatile("s_waitcnt vmcnt(6)" ::: "memory");
        __builtin_amdgcn_s_barrier();
        // ---- PH2 ----
        bf16x8 a02 = *(const bf16x8*)&As[cb + arow0 + sk2];
        bf16x8 a03 = *(const bf16x8*)&As[cb + arow0 + sk3];
        bf16x8 a12 = *(const bf16x8*)&As[cb + arow1 + sk2];
        bf16x8 a13 = *(const bf16x8*)&As[cb + arow1 + sk3];
        bf16x8 b02 = *(const bf16x8*)&Bs[cb + brow0 + tk2];
        bf16x8 b03 = *(const bf16x8*)&Bs[cb + brow0 + tk3];
        bf16x8 b12 = *(const bf16x8*)&Bs[cb + brow1 + tk2];
        bf16x8 b13 = *(const bf16x8*)&Bs[cb + brow1 + tk3];
        async_copy16(&Bs[nb + 8192 + da],  gB + 32);
        async_copy16(&Bs[nb + 12288 + da], gB + 131072 + 32);
        gA += 64; gB += 64;
        __builtin_amdgcn_s_barrier();
        asm volatile("s_waitcnt lgkmcnt(0)" ::: "memory");
        __builtin_amdgcn_s_setprio(1);
        acc[0][0] = __builtin_amdgcn_mfma_f32_32x32x16_bf16(a02, b02, acc[0][0], 0, 0, 0);
        acc[0][1] = __builtin_amdgcn_mfma_f32_32x32x16_bf16(a02, b12, acc[0][1], 0, 0, 0);
        acc[1][0] = __builtin_amdgcn_mfma_f32_32x32x16_bf16(a12, b02, acc[1][0], 0, 0, 0);
        acc[1][1] = __builtin_amdgcn_mfma_f32_32x32x16_bf16(a12, b12, acc[1][1], 0, 0, 0);
        acc[0][0] = __builtin_amdgcn_mfma_f32_32x32x16_bf16(a03, b03, acc[0][0], 0, 0, 0);
        acc[0][1] = __builtin_amdgcn_mfma_f32_32x32x16_bf16(a03, b13, acc[0][1], 0, 0, 0);
        acc[1][0] = __builtin_amdgcn_mfma_f32_32x32x16_bf16(a13, b03, acc[1][0], 0, 0, 0);
        acc[1][1] = __builtin_amdgcn_mfma_f32_32x32x16_bf16(a13, b13, acc[1][1], 0, 0, 0);
        __builtin_amdgcn_s_setprio(0);
        __builtin_amdgcn_s_barrier();
        // ---- PH3 ----
        bf16x8 a22 = *(const bf16x8*)&As[cb + arow2 + sk2];
        bf16x8 a23 = *(const bf16x8*)&As[cb + arow2 + sk3];
        bf16x8 a32 = *(const bf16x8*)&As[cb + arow3 + sk2];
        bf16x8 a33 = *(const bf16x8*)&As[cb + arow3 + sk3];
        __builtin_amdgcn_s_barrier();
        asm volatile("s_waitcnt lgkmcnt(0)" ::: "memory");
        __builtin_amdgcn_s_setprio(1);
        acc[2][0] = __builtin_amdgcn_mfma_f32_32x32x16_bf16(a22, b02, acc[2][0], 0, 0, 0);
        acc[2][1] = __builtin_amdgcn_mfma_f32_32x32x16_bf16(a22, b12, acc[2][1], 0, 0, 0);
        acc[3][0] = __builtin_amdgcn_mfma_f32_32x32x16_bf16(a32, b02, acc[3][0], 0, 0, 0);
        acc[3][1] = __builtin_amdgcn_mfma_f32_32x32x16_bf16(a32, b12, acc[3][1], 0, 0, 0);
        acc[2][0] = __builtin_amdgcn_mfma_f32_32x32x16_bf16(a23, b03, acc[2][0], 0, 0, 0);
        acc[2][1] = __builtin_amdgcn_mfma_f32_32x32x16_bf16(a23, b13, acc[2][1], 0, 0, 0);
        acc[3][0] = __builtin_amdgcn_mfma_f32_32x32x16_bf16(a33, b03, acc[3][0], 0, 0, 0);
        acc[3][1] = __builtin_amdgcn_mfma_f32_32x32x16_bf16(a33, b13, acc[3][1], 0, 0, 0);
        __builtin_amdgcn_s_setprio(0);
        asm volatile("s_waitcnt vmcnt(4)" ::: "memory");
        __builtin_amdgcn_s_barrier();
        cur ^= 1;
    }

    {   // tail tile
        const int cb = cur * 16384;
        bf16x8 a00 = *(const bf16x8*)&As[cb + arow0 + sk0];
        bf16x8 a01 = *(const bf16x8*)&As[cb + arow0 + sk1];
        bf16x8 a10 = *(const bf16x8*)&As[cb + arow1 + sk0];
        bf16x8 a11 = *(const bf16x8*)&As[cb + arow1 + sk1];
        bf16x8 b00 = *(const bf16x8*)&Bs[cb + brow0 + tk0];
        bf16x8 b01 = *(const bf16x8*)&Bs[cb + brow0 + tk1];
        bf16x8 b10 = *(const bf16x8*)&Bs[cb + brow1 + tk0];
        bf16x8 b11 = *(const bf16x8*)&Bs[cb + brow1 + tk1];
        __builtin_amdgcn_s_barrier();
        asm volatile("s_waitcnt lgkmcnt(0)" ::: "memory");
        __builtin_amdgcn_s_setprio(1);
        acc[0][0] = __builtin_amdgcn_mfma_f32_32x32x16_bf16(a00, b00, acc[0][0], 0, 0, 0);
        acc[0][1] = __builtin_amdgcn_mfma_f32_32x32x16_bf16(a00, b10, acc[0][1], 0, 0, 0);
        acc[1][0] = __builtin_amdgcn_mfma_f32_32x32x16_bf16(a10, b00, acc[1][0], 0, 0, 0);
        acc[1][1] = __builtin_amdgcn_mfma_f32_32x32x16_bf16(a10, b10, acc[1][1], 0, 0, 0);
        acc[0][0] = __builtin_amdgcn_mfma_f32_32x32x16_bf16(a01, b01, acc[0][0], 0, 0, 0);
        acc[0][1] = __builtin_amdgcn_mfma_f32_32x32x16_bf16(a01, b11, acc[0][1], 0, 0, 0);
        acc[1][0] = __builtin_amdgcn_mfma_f32_32x32x16_bf16(a11, b01, acc[1][0], 0, 0, 0);
        acc[1][1] = __builtin_amdgcn_mfma_f32_32x32x16_bf16(a11, b11, acc[1][1], 0, 0, 0);
        __builtin_amdgcn_s_setprio(0);
        asm volatile("s_waitcnt vmcnt(2)" ::: "memory");
        __builtin_amdgcn_s_barrier();
        bf16x8 a20 = *(const bf16x8*)&As[cb + arow2 + sk0];
        bf16x8 a21 = *(const bf16x8*)&As[cb + arow2 + sk1];
        bf16x8 a30 = *(const bf16x8*)&As[cb + arow3 + sk0];
        bf16x8 a31 = *(const bf16x8*)&As[cb + arow3 + sk1];
        __builtin_amdgcn_s_barrier();
        asm volatile("s_waitcnt lgkmcnt(0)" ::: "memory");
        __builtin_amdgcn_s_setprio(1);
        acc[2][0] = __builtin_amdgcn_mfma_f32_32x32x16_bf16(a20, b00, acc[2][0], 0, 0, 0);
        acc[2][1] = __builtin_amdgcn_mfma_f32_32x32x16_bf16(a20, b10, acc[2][1], 0, 0, 0);
        acc[3][0] = __builtin_amdgcn_mfma_f32_32x32x16_bf16(a30, b00, acc[3][0], 0, 0, 0);
        acc[3][1] = __builtin_amdgcn_mfma_f32_32x32x16_bf16(a30, b10, acc[3][1], 0, 0, 0);
        acc[2][0] = __builtin_amdgcn_mfma_f32_32x32x16_bf16(a21, b01, acc[2][0], 0, 0, 0);
        acc[2][1] = __builtin_amdgcn_mfma_f32_32x32x16_bf16(a21, b11, acc[2][1], 0, 0, 0);
        acc[3][0] = __builtin_amdgcn_mfma_f32_32x32x16_bf16(a31, b01, acc[3][0], 0, 0, 0);
        acc[3][1] = __builtin_amdgcn_mfma_f32_32x32x16_bf16(a31, b11, acc[3][1], 0, 0, 0);
        __builtin_amdgcn_s_setprio(0);
        asm volatile("s_waitcnt vmcnt(0)" ::: "memory");
        __builtin_amdgcn_s_barrier();
        bf16x8 a02 = *(const bf16x8*)&As[cb + arow0 + sk2];
        bf16x8 a03 = *(const bf16x8*)&As[cb + arow0 + sk3];
        bf16x8 a12 = *(const bf16x8*)&As[cb + arow1 + sk2];
        bf16x8 a13 = *(const bf16x8*)&As[cb + arow1 + sk3];
        bf16x8 b02 = *(const bf16x8*)&Bs[cb + brow0 + tk2];
        bf16x8 b03 = *(const bf16x8*)&Bs[cb + brow0 + tk3];
        bf16x8 b12 = *(const bf16x8*)&Bs[cb + brow1 + tk2];
        bf16x8 b13 = *(const bf16x8*)&Bs[cb + brow1 + tk3];
        __builtin_amdgcn_s_barrier();
        asm volatile("s_waitcnt lgkmcnt(0)" ::: "memory");
        __builtin_amdgcn_s_setprio(1);
        acc[0][0] = __builtin_amdgcn_mfma_f32_32x32x16_bf16(a02, b02, acc[0][0], 0, 0, 0);
        acc[0][1] = __builtin_amdgcn_mfma_f32_32x32x16_bf16(a02, b12, acc[0][1], 0, 0, 0);
        acc[1][0] = __builtin_amdgcn_mfma_f32_32x32x16_bf16(a12, b02, acc[1][0], 0, 0, 0);
        acc[1][1] = __builtin_amdgcn_mfma_f32_32x32x16_bf16(a12, b12, acc[1][1], 0, 0, 0);
        acc[0][0] = __builtin_amdgcn_mfma_f32_32x32x16_bf16(a03, b03, acc[0][0], 0, 0, 0);
        acc[0][1] = __builtin_amdgcn_mfma_f32_32x32x16_bf16(a03, b13, acc[0][1], 0, 0, 0);
        acc[1][0] = __builtin_amdgcn_mfma_f32_32x32x16_bf16(a13, b03, acc[1][0], 0, 0, 0);
        acc[1][1] = __builtin_amdgcn_mfma_f32_32x32x16_bf16(a13, b13, acc[1][1], 0, 0, 0);
        __builtin_amdgcn_s_setprio(0);
        __builtin_amdgcn_s_barrier();
        bf16x8 a22 = *(const bf16x8*)&As[cb + arow2 + sk2];
        bf16x8 a23 = *(const bf16x8*)&As[cb + arow2 + sk3];
        bf16x8 a32 = *(const bf16x8*)&As[cb + arow3 + sk2];
        bf16x8 a33 = *(const bf16x8*)&As[cb + arow3 + sk3];
        asm volatile("s_waitcnt lgkmcnt(0)" ::: "memory");
        __builtin_amdgcn_s_setprio(1);
        acc[2][0] = __builtin_amdgcn_mfma_f32_32x32x16_bf16(a22, b02, acc[2][0], 0, 0, 0);
        acc[2][1] = __builtin_amdgcn_mfma_f32_32x32x16_bf16(a22, b12, acc[2][1], 0, 0, 0);
        acc[3][0] = __builtin_amdgcn_mfma_f32_32x32x16_bf16(a32, b02, acc[3][0], 0, 0, 0);
        acc[3][1] = __builtin_amdgcn_mfma_f32_32x32x16_bf16(a32, b12, acc[3][1], 0, 0, 0);
        acc[2][0] = __builtin_amdgcn_mfma_f32_32x32x16_bf16(a23, b03, acc[2][0], 0, 0, 0);
        acc[2][1] = __builtin_amdgcn_mfma_f32_32x32x16_bf16(a23, b13, acc[2][1], 0, 0, 0);
        acc[3][0] = __builtin_amdgcn_mfma_f32_32x32x16_bf16(a33, b03, acc[3][0], 0, 0, 0);
        acc[3][1] = __builtin_amdgcn_mfma_f32_32x32x16_bf16(a33, b13, acc[3][1], 0, 0, 0);
        __builtin_amdgcn_s_setprio(0);
    }

    // epilogue: bf16 C = acc + bias; ni innermost.
    {
        const float bb0 = bias[n0 + wc * 64 + lc];
        const float bb1 = bias[n0 + wc * 64 + 32 + lc];
        #pragma unroll
        for (int mi = 0; mi < 4; ++mi) {
            #pragma unroll
            for (int r = 0; r < 16; ++r) {
                const int row = m0 + wr * 128 + mi * 32 + (r & 3) + 8 * (r >> 2) + 4 * q;
                ushort_t* cp = C + (size_t)row * ldc + n0 + wc * 64 + lc;
                cp[0]  = (ushort_t)f2bf(acc[mi][0][r] + bb0);
                cp[32] = (ushort_t)f2bf(acc[mi][1][r] + bb1);
            }
        }
    }
}

// ---------------------------------------------------------------------------
// 8-phase GATE GEMM (frozen)
// ---------------------------------------------------------------------------
__global__ __launch_bounds__(512)
void gemm_gate_p8(const ushort_t* __restrict__ A,
                  const ushort_t* __restrict__ Bt,
                  const float* __restrict__ bias,
                  ushort_t* __restrict__ C, int ldc,
                  int nkt)  // nkt >= 2
{
    __shared__ ushort_t As[2 * 8192];    // 32 KB
    __shared__ ushort_t Bs[2 * 16384];   // 64 KB

    const int tid = threadIdx.x;
    const int wid = tid >> 6, l = tid & 63;
    const int lc = l & 31, q = l >> 5;
    const int wr = wid >> 2, wc = wid & 3;
    int bx, by; xcd_map_gate(bx, by);
    const int m0 = by * 128, n0 = bx * 256;

    const int sra = tid >> 3;
    const int spa = (tid & 7) ^ (sra & 7);
    const ushort_t* gA = A + (size_t)(m0 + sra) * 1024 + spa * 8;
    const int srb = tid >> 2;
    const int spb = (tid & 3) ^ ((srb >> 1) & 3);
    const ushort_t* gB = Bt + (size_t)(n0 + srb) * 1024 + spb * 8;
    const int da = tid * 8;

    int arow0 = (wr * 64 +  0 + lc) * 64;
    int arow1 = (wr * 64 + 32 + lc) * 64;
    int sk0 = ((0 * 2 + q) ^ (lc & 7)) * 8;
    int sk1 = ((1 * 2 + q) ^ (lc & 7)) * 8;
    int sk2 = ((2 * 2 + q) ^ (lc & 7)) * 8;
    int sk3 = ((3 * 2 + q) ^ (lc & 7)) * 8;
    int brow0 = (wc * 64 +  0 + lc) * 32;
    int brow1 = (wc * 64 + 32 + lc) * 32;
    int tk0 = ((0 + q) ^ ((lc >> 1) & 3)) * 8;
    int tk1 = ((2 + q) ^ ((lc >> 1) & 3)) * 8;
    int tk2 = 8192 + ((0 + q) ^ ((lc >> 1) & 3)) * 8;
    int tk3 = 8192 + ((2 + q) ^ ((lc >> 1) & 3)) * 8;

    f32x16 acc[2][2];
    #pragma unroll
    for (int mi = 0; mi < 2; ++mi)
        #pragma unroll
        for (int ni = 0; ni < 2; ++ni)
            #pragma unroll
            for (int e = 0; e < 16; ++e) acc[mi][ni][e] = 0.0f;

    async_copy16(&As[da],          gA);
    async_copy16(&As[4096 + da],   gA + 65536);
    async_copy16(&Bs[da],          gB);
    async_copy16(&Bs[4096 + da],   gB + 131072);
    async_copy16(&Bs[8192 + da],   gB + 32);
    async_copy16(&Bs[12288 + da],  gB + 131072 + 32);
    gA += 64; gB += 64;
    asm volatile("s_waitcnt vmcnt(0)" ::: "memory");
    __builtin_amdgcn_s_barrier();

    int cur = 0;
    for (int t = 0; t < nkt - 1; ++t) {
        const int ca = cur * 8192,  na = 8192 - ca;
        const int cb = cur * 16384, nb = 16384 - cb;
        // ---- PH0: ks{0,1} ----
        bf16x8 a00 = *(const bf16x8*)&As[ca + arow0 + sk0];
        bf16x8 a01 = *(const bf16x8*)&As[ca + arow0 + sk1];
        bf16x8 a10 = *(const bf16x8*)&As[ca + arow1 + sk0];
        bf16x8 a11 = *(const bf16x8*)&As[ca + arow1 + sk1];
        bf16x8 b00 = *(const bf16x8*)&Bs[cb + brow0 + tk0];
        bf16x8 b01 = *(const bf16x8*)&Bs[cb + brow0 + tk1];
        bf16x8 b10 = *(const bf16x8*)&Bs[cb + brow1 + tk0];
        bf16x8 b11 = *(const bf16x8*)&Bs[cb + brow1 + tk1];
        async_copy16(&As[na + da],        gA);
        async_copy16(&As[na + 4096 + da], gA + 65536);
        async_copy16(&Bs[nb + da],        gB);
        async_copy16(&Bs[nb + 4096 + da], gB + 131072);
        __builtin_amdgcn_s_barrier();
        asm volatile("s_waitcnt lgkmcnt(0)" ::: "memory");
        __builtin_amdgcn_s_setprio(1);
        acc[0][0] = __builtin_amdgcn_mfma_f32_32x32x16_bf16(a00, b00, acc[0][0], 0, 0, 0);
        acc[0][1] = __builtin_amdgcn_mfma_f32_32x32x16_bf16(a00, b10, acc[0][1], 0, 0, 0);
        acc[1][0] = __builtin_amdgcn_mfma_f32_32x32x16_bf16(a10, b00, acc[1][0], 0, 0, 0);
        acc[1][1] = __builtin_amdgcn_mfma_f32_32x32x16_bf16(a10, b10, acc[1][1], 0, 0, 0);
        acc[0][0] = __builtin_amdgcn_mfma_f32_32x32x16_bf16(a01, b01, acc[0][0], 0, 0, 0);
        acc[0][1] = __builtin_amdgcn_mfma_f32_32x32x16_bf16(a01, b11, acc[0][1], 0, 0, 0);
        acc[1][0] = __builtin_amdgcn_mfma_f32_32x32x16_bf16(a11, b01, acc[1][0], 0, 0, 0);
        acc[1][1] = __builtin_amdgcn_mfma_f32_32x32x16_bf16(a11, b11, acc[1][1], 0, 0, 0);
        __builtin_amdgcn_s_setprio(0);
        asm volatile("s_waitcnt vmcnt(4)" ::: "memory");
        __builtin_amdgcn_s_barrier();
        // ---- PH1: ks{2,3} ----
        bf16x8 a02 = *(const bf16x8*)&As[ca + arow0 + sk2];
        bf16x8 a03 = *(const bf16x8*)&As[ca + arow0 + sk3];
        bf16x8 a12 = *(const bf16x8*)&As[ca + arow1 + sk2];
        bf16x8 a13 = *(const bf16x8*)&As[ca + arow1 + sk3];
        bf16x8 b02 = *(const bf16x8*)&Bs[cb + brow0 + tk2];
        bf16x8 b03 = *(const bf16x8*)&Bs[cb + brow0 + tk3];
        bf16x8 b12 = *(const bf16x8*)&Bs[cb + brow1 + tk2];
        bf16x8 b13 = *(const bf16x8*)&Bs[cb + brow1 + tk3];
        async_copy16(&Bs[nb + 8192 + da],  gB + 32);
        async_copy16(&Bs[nb + 12288 + da], gB + 131072 + 32);
        gA += 64; gB += 64;
        __builtin_amdgcn_s_barrier();
        asm volatile("s_waitcnt lgkmcnt(0)" ::: "memory");
        __builtin_amdgcn_s_setprio(1);
        acc[0][0] = __builtin_amdgcn_mfma_f32_32x32x16_bf16(a02, b02, acc[0][0], 0, 0, 0);
        acc[0][1] = __builtin_amdgcn_mfma_f32_32x32x16_bf16(a02, b12, acc[0][1], 0, 0, 0);
        acc[1][0] = __builtin_amdgcn_mfma_f32_32x32x16_bf16(a12, b02, acc[1][0], 0, 0, 0);
        acc[1][1] = __builtin_amdgcn_mfma_f32_32x32x16_bf16(a12, b12, acc[1][1], 0, 0, 0);
        acc[0][0] = __builtin_amdgcn_mfma_f32_32x32x16_bf16(a03, b03, acc[0][0], 0, 0, 0);
        acc[0][1] = __builtin_amdgcn_mfma_f32_32x32x16_bf16(a03, b13, acc[0][1], 0, 0, 0);
        acc[1][0] = __builtin_amdgcn_mfma_f32_32x32x16_bf16(a13, b03, acc[1][0], 0, 0, 0);
        acc[1][1] = __builtin_amdgcn_mfma_f32_32x32x16_bf16(a13, b13, acc[1][1], 0, 0, 0);
        __builtin_amdgcn_s_setprio(0);
        asm volatile("s_waitcnt vmcnt(2)" ::: "memory");
        __builtin_amdgcn_s_barrier();
        cur ^= 1;
    }

    {   // tail tile
        const int ca = cur * 8192;
        const int cb = cur * 16384;
        bf16x8 a00 = *(const bf16x8*)&As[ca + arow0 + sk0];
        bf16x8 a01 = *(const bf16x8*)&As[ca + arow0 + sk1];
        bf16x8 a10 = *(const bf16x8*)&As[ca + arow1 + sk0];
        bf16x8 a11 = *(const bf16x8*)&As[ca + arow1 + sk1];
        bf16x8 b00 = *(const bf16x8*)&Bs[cb + brow0 + tk0];
        bf16x8 b01 = *(const bf16x8*)&Bs[cb + brow0 + tk1];
        bf16x8 b10 = *(const bf16x8*)&Bs[cb + brow1 + tk0];
        bf16x8 b11 = *(const bf16x8*)&Bs[cb + brow1 + tk1];
        __builtin_amdgcn_s_barrier();
        asm volatile("s_waitcnt lgkmcnt(0)" ::: "memory");
        __builtin_amdgcn_s_setprio(1);
        acc[0][0] = __builtin_amdgcn_mfma_f32_32x32x16_bf16(a00, b00, acc[0][0], 0, 0, 0);
        acc[0][1] = __builtin_amdgcn_mfma_f32_32x32x16_bf16(a00, b10, acc[0][1], 0, 0, 0);
        acc[1][0] = __builtin_amdgcn_mfma_f32_32x32x16_bf16(a10, b00, acc[1][0], 0, 0, 0);
        acc[1][1] = __builtin_amdgcn_mfma_f32_32x32x16_bf16(a10, b10, acc[1][1], 0, 0, 0);
        acc[0][0] = __builtin_amdgcn_mfma_f32_32x32x16_bf16(a01, b01, acc[0][0], 0, 0, 0);
        acc[0][1] = __builtin_amdgcn_mfma_f32_32x32x16_bf16(a01, b11, acc[0][1], 0, 0, 0);
        acc[1][0] = __builtin_amdgcn_mfma_f32_32x32x16_bf16(a11, b01, acc[1][0], 0, 0, 0);
        acc[1][1] = __builtin_amdgcn_mfma_f32_32x32x16_bf16(a11, b11, acc[1][1], 0, 0, 0);
        __builtin_amdgcn_s_setprio(0);
        asm volatile("s_waitcnt vmcnt(0)" ::: "memory");
        __builtin_amdgcn_s_barrier();
        bf16x8 a02 = *(const bf16x8*)&As[ca + arow0 + sk2];
        bf16x8 a03 = *(const bf16x8*)&As[ca + arow0 + sk3];
        bf16x8 a12 = *(const bf16x8*)&As[ca + arow1 + sk2];
        bf16x8 a13 = *(const bf16x8*)&As[ca + arow1 + sk3];
        bf16x8 b02 = *(const bf16x8*)&Bs[cb + brow0 + tk2];
        bf16x8 b03 = *(const bf16x8*)&Bs[cb + brow0 + tk3];
        bf16x8 b12 = *(const bf16x8*)&Bs[cb + brow1 + tk2];
        bf16x8 b13 = *(const bf16x8*)&Bs[cb + brow1 + tk3];
        asm volatile("s_waitcnt lgkmcnt(0)" ::: "memory");
        __builtin_amdgcn_s_setprio(1);
        acc[0][0] = __builtin_amdgcn_mfma_f32_32x32x16_bf16(a02, b02, acc[0][0], 0, 0, 0);
        acc[0][1] = __builtin_amdgcn_mfma_f32_32x32x16_bf16(a02, b12, acc[0][1], 0, 0, 0);
        acc[1][0] = __builtin_amdgcn_mfma_f32_32x32x16_bf16(a12, b02, acc[1][0], 0, 0, 0);
        acc[1][1] = __builtin_amdgcn_mfma_f32_32x32x16_bf16(a12, b12, acc[1][1], 0, 0, 0);
        acc[0][0] = __builtin_amdgcn_mfma_f32_32x32x16_bf16(a03, b03, acc[0][0], 0, 0, 0);
        acc[0][1] = __builtin_amdgcn_mfma_f32_32x32x16_bf16(a03, b13, acc[0][1], 0, 0, 0);
        acc[1][0] = __builtin_amdgcn_mfma_f32_32x32x16_bf16(a13, b03, acc[1][0], 0, 0, 0);
        acc[1][1] = __builtin_amdgcn_mfma_f32_32x32x16_bf16(a13, b13, acc[1][1], 0, 0, 0);
        __builtin_amdgcn_s_setprio(0);
    }

    // epilogue: bf16 gate_raw = silu(acc + bias); ni innermost.
    {
        const float bb0 = bias[n0 + wc * 64 + lc];
        const float bb1 = bias[n0 + wc * 64 + 32 + lc];
        #pragma unroll
        for (int mi = 0; mi < 2; ++mi) {
            #pragma unroll
            for (int r = 0; r < 16; ++r) {
                const int row = m0 + wr * 64 + mi * 32 + (r & 3) + 8 * (r >> 2) + 4 * q;
                ushort_t* cp = C + (size_t)row * ldc + n0 + wc * 64 + lc;
                float v0 = acc[mi][0][r] + bb0;
                float v1 = acc[mi][1][r] + bb1;
                cp[0]  = (ushort_t)f2bf(v0 / (1.0f + expf(-v0)));
                cp[32] = (ushort_t)f2bf(v1 / (1.0f + expf(-v1)));
            }
        }
    }
}

// ---------------------------------------------------------------------------
// TM=64 GEMM (proj; frozen)
// ---------------------------------------------------------------------------
__global__ __launch_bounds__(256)
void gemm_tm64(const ushort_t* __restrict__ A, int lda,
               const ushort_t* __restrict__ Bt, int ldb,
               const float* __restrict__ bias,
               float* __restrict__ C, int ldc, int nkt)  // nkt >= 3
{
    __shared__ ushort_t As[3 * 64 * 32];
    __shared__ ushort_t Bs[3 * 128 * 32];

    const int tid = threadIdx.x;
    const int w  = tid >> 6, l = tid & 63;
    const int lc = l & 31, q = l >> 5;
    const int wr = w >> 1, wc = w & 1;
    int bx, by; xcd_tile(bx, by);
    const int m0 = by * 64, n0 = bx * 128;

    const int rA = tid >> 2,          kcA = (tid & 3) ^ ((rA >> 1) & 3);
    const int rB1 = (256 + tid) >> 2, kcB1 = (tid & 3) ^ ((rB1 >> 1) & 3);
    const ushort_t* gA  = A  + (size_t)(m0 + rA)  * lda + kcA  * 8;
    const ushort_t* gB0 = Bt + (size_t)(n0 + rA)  * ldb + kcA  * 8;
    const ushort_t* gB1 = Bt + (size_t)(n0 + rB1) * ldb + kcB1 * 8;
    const int sA  = w * 512;
    const int sB0 = w * 512;
    const int sB1 = 2048 + w * 512;

    const int sl = (lc >> 1) & 3;
    int aoff[2], boff[2][2];
    #pragma unroll
    for (int ks = 0; ks < 2; ++ks) {
        const int kk = ks * 2 + q;
        const int mrow = wr * 32 + lc;
        aoff[ks] = (mrow * 4 + (kk ^ sl)) * 8;
        #pragma unroll
        for (int ni = 0; ni < 2; ++ni) {
            const int nrow = wc * 64 + ni * 32 + lc;
            boff[ni][ks] = (nrow * 4 + (kk ^ sl)) * 8;
        }
    }

    f32x16 acc[2];
    #pragma unroll
    for (int ni = 0; ni < 2; ++ni)
        #pragma unroll
        for (int e = 0; e < 16; ++e) acc[ni][e] = 0.0f;

    auto stage = [&](int ab, int bb) {
        async_copy16(&As[ab + sA], gA);
        async_copy16(&Bs[bb + sB0], gB0); async_copy16(&Bs[bb + sB1], gB1);
        gA += 32; gB0 += 32; gB1 += 32;
    };
    auto compute = [&](int ab, int bb) {
        bf16x8 a[2], b[2][2];
        #pragma unroll
        for (int ks = 0; ks < 2; ++ks) {
            a[ks] = *(const bf16x8*)&As[ab + aoff[ks]];
            b[0][ks] = *(const bf16x8*)&Bs[bb + boff[0][ks]];
            b[1][ks] = *(const bf16x8*)&Bs[bb + boff[1][ks]];
        }
        #pragma unroll
        for (int ks = 0; ks < 2; ++ks)
            #pragma unroll
            for (int ni = 0; ni < 2; ++ni)
                acc[ni] = __builtin_amdgcn_mfma_f32_32x32x16_bf16(
                    a[ks], b[ni][ks], acc[ni], 0, 0, 0);
    };

    stage(0, 0); stage(2048, 4096);
    int as_ = 4096, bs_ = 8192;
    int ac_ = 0,    bc_ = 0;
    for (int kt = 0; kt < nkt - 2; ++kt) {
        asm volatile("s_waitcnt vmcnt(3)" ::: "memory");
        __builtin_amdgcn_s_barrier();
        stage(as_, bs_);
        compute(ac_, bc_);
        as_ = ac_; bs_ = bc_;
        ac_ = (ac_ == 4096) ? 0 : ac_ + 2048;
        bc_ = (bc_ == 8192) ? 0 : bc_ + 4096;
    }
    asm volatile("s_waitcnt vmcnt(3)" ::: "memory");
    __builtin_amdgcn_s_barrier();
    compute(ac_, bc_);
    ac_ = (ac_ == 4096) ? 0 : ac_ + 2048;
    bc_ = (bc_ == 8192) ? 0 : bc_ + 4096;
    asm volatile("s_waitcnt vmcnt(0)" ::: "memory");
    __builtin_amdgcn_s_barrier();
    compute(ac_, bc_);

    #pragma unroll
    for (int ni = 0; ni < 2; ++ni) {
        const int col = n0 + wc * 64 + ni * 32 + lc;
        const float bb = bias[col];
        #pragma unroll
        for (int r = 0; r < 16; ++r) {
            const int row = m0 + wr * 32 + (r & 3) + 8 * (r >> 2) + 4 * q;
            C[(size_t)row * ldc + col] = acc[ni][r] + bb;
        }
    }
}

// ---------------------------------------------------------------------------
// Fused qkv prep (frozen): {qk_prep xpos rotate, v_transpose}
// ---------------------------------------------------------------------------
__global__ __launch_bounds__(256)
void qkv_prep(const ushort_t* __restrict__ qkvb,
              ushort_t* __restrict__ qh, ushort_t* __restrict__ kh,
              ushort_t* __restrict__ vt)
{
    __shared__ ushort_t tile[32][40];
    const int blk = blockIdx.x;
    const int t = threadIdx.x;
    if (blk < 4096) {
        const int row = blk;
        const int b = row >> 11, trow = row & (T_SEQ - 1);
        const bool isK = t >= 128;
        const int col0 = (t & 127) * 8;
        const int h = col0 >> 7, d = col0 & 127;

        float ld, gamma;
        decay_params(h, ld, gamma);
        const float gsc = __expf(isK ? -ld * (float)(trow & 63) : ld * (float)(trow & 63));

        const ushort_t* src = qkvb + (size_t)row * 4096 + (isK ? E_DIM : 0) + col0;
        bf16x8 xv8 = *(const bf16x8*)src;
        float xv[8];
        #pragma unroll
        for (int p = 0; p < 8; ++p) xv[p] = bf2f((ushort_t)xv8[p]);

        const float tf = (float)trow * (1.0f / 512.0f);
        bf16x8 o;
        #pragma unroll
        for (int pi = 0; pi < 4; ++pi) {
            const int ip = col0 / 2 + pi;
            float sv = (2.0f * (float)ip + 409.6f) * (1.0f / 1433.6f);
            float e = __logf(sv) * tf;
            if (isK) e = -e;
            float sc = __expf(e);
            float invf = __expf((float)ip * -0.017988946038999563f);  // -ln(1e4)/512
            float sn, cs;
            sincosf((float)trow * invf, &sn, &cs);
            float c = cs * sc * gsc, s = sn * sc * gsc;
            float a = xv[2 * pi], bb = xv[2 * pi + 1];
            o[2 * pi]     = f2bf(a * c - bb * s);
            o[2 * pi + 1] = f2bf(bb * c + a * s);
        }
        ushort_t* dst = (isK ? kh : qh) + ((size_t)(b * 8 + h) * T_SEQ + trow) * 128 + d;
        *(bf16x8*)dst = o;
    } else {
        const int u = blk - 4096;
        const int j0 = (u & 63) * 32;
        const int zz = u >> 6;
        const int bh = zz >> 3, v0 = (zz & 7) * 32;
        const int b = bh >> 3, h = bh & 7;
        const int r = t >> 3, c = (t & 7) * 4;

        *(u16x4*)&tile[r][c] = *(const u16x4*)(qkvb + (size_t)(b * T_SEQ + j0 + r) * 4096
                                               + 2 * E_DIM + h * DV + v0 + c);
        __syncthreads();
        u16x4 o;
        o[0] = tile[c][r];
        o[1] = tile[c + 1][r];
        o[2] = tile[c + 2][r];
        o[3] = tile[c + 3][r];
        *(u16x4*)&vt[((size_t)bh * 256 + v0 + r) * T_SEQ + j0 + c] = o;
    }
}

// ---------------------------------------------------------------------------
// kt2 = gamma^63 * kh^T per head (frozen)
// ---------------------------------------------------------------------------
__global__ __launch_bounds__(256)
void kt2_kernel(const ushort_t* __restrict__ kh, ushort_t* __restrict__ kt2)
{
    __shared__ ushort_t tile[32][40];
    const int j0 = blockIdx.x * 32;
    const int zz = blockIdx.y;
    const int bh = zz >> 2, k0 = (zz & 3) * 32;
    const int t = threadIdx.x;
    const int r = t >> 3, c = (t & 7) * 4;
    float ld, gamma; decay_params(bh & 7, ld, gamma);
    const float g63 = expf(ld * 63.0f);
    *(u16x4*)&tile[r][c] = *(const u16x4*)&kh[((size_t)bh * T_SEQ + j0 + r) * 128 + k0 + c];
    __syncthreads();
    u16x4 o;
    o[0] = (ushort_t)f2bf(bf2f(tile[c][r])     * g63);
    o[1] = (ushort_t)f2bf(bf2f(tile[c + 1][r]) * g63);
    o[2] = (ushort_t)f2bf(bf2f(tile[c + 2][r]) * g63);
    o[3] = (ushort_t)f2bf(bf2f(tile[c + 3][r]) * g63);
    *(u16x4*)&kt2[((size_t)bh * 128 + k0 + r) * T_SEQ + j0 + c] = o;
}

// ---------------------------------------------------------------------------
// Phase A: A_c[v][k] (frozen)
// ---------------------------------------------------------------------------
__global__ __launch_bounds__(256)
void chunk_kv(const ushort_t* __restrict__ vt, const ushort_t* __restrict__ kt2,
              ushort_t* __restrict__ Abuf)
{
    const int c = blockIdx.x;
    const int bh = blockIdx.y;
    const int tid = threadIdx.x;
    const int w = tid >> 6, l = tid & 63, lc = l & 31, q = l >> 5;
    const int j0 = c * 64;

    f32x16 acc[2][4];
    #pragma unroll
    for (int mi = 0; mi < 2; ++mi)
        #pragma unroll
        for (int ni = 0; ni < 4; ++ni)
            #pragma unroll
            for (int e = 0; e < 16; ++e) acc[mi][ni][e] = 0.0f;

    #pragma unroll
    for (int ks = 0; ks < 4; ++ks) {
        bf16x8 a[2], bfr[4];
        #pragma unroll
        for (int mi = 0; mi < 2; ++mi)
            a[mi] = *(const bf16x8*)(vt + ((size_t)bh * 256 + w * 64 + mi * 32 + lc) * T_SEQ
                                     + j0 + ks * 16 + q * 8);
        #pragma unroll
        for (int ni = 0; ni < 4; ++ni)
            bfr[ni] = *(const bf16x8*)(kt2 + ((size_t)bh * 128 + ni * 32 + lc) * T_SEQ
                                       + j0 + ks * 16 + q * 8);
        #pragma unroll
        for (int mi = 0; mi < 2; ++mi)
            #pragma unroll
            for (int ni = 0; ni < 4; ++ni)
                acc[mi][ni] = __builtin_amdgcn_mfma_f32_32x32x16_bf16(
                    a[mi], bfr[ni], acc[mi][ni], 0, 0, 0);
    }

    ushort_t* ab = Abuf + (size_t)(bh * 32 + c) * 256 * 128;
    #pragma unroll
    for (int mi = 0; mi < 2; ++mi)
        #pragma unroll
        for (int ni = 0; ni < 4; ++ni)
            #pragma unroll
            for (int r = 0; r < 16; ++r) {
                const int v = w * 64 + mi * 32 + (r & 3) + 8 * (r >> 2) + 4 * q;
                const int k = ni * 32 + lc;
                ab[(size_t)v * 128 + k] = (ushort_t)f2bf(acc[mi][ni][r]);
            }
}

// ---------------------------------------------------------------------------
// Phase B: IN-PLACE scan (frozen; Abuf/St intentionally alias)
// ---------------------------------------------------------------------------
__global__ __launch_bounds__(256)
void scan_state(const ushort_t* Abuf, ushort_t* St,
                float* __restrict__ ckv)
{
    const int blk = blockIdx.x;
    const int bh = blk >> 7, sub = blk & 127;
    const int tid = threadIdx.x;
    const int v = sub * 2 + (tid >> 7), k = tid & 127;

    float ld, gamma;
    decay_params(bh & 7, ld, gamma);
    const float g64 = expf(ld * 64.0f);

    const size_t base = ((size_t)bh * 32 * 256 + v) * 128 + k;
    const size_t cstr = 256 * 128;
    float s = 0.0f;
    for (int c = 0; c < 32; ++c) {
        const size_t off = base + (size_t)c * cstr;
        const float a = bf2f(Abuf[off]);     // read BEFORE the aliased write
        St[off] = (ushort_t)f2bf(gamma * s);
        s = g64 * s + a;
    }
    const float inv_scale = rsqrtf((1.0f - expf(ld * (float)T_SEQ)) / (1.0f - gamma));
    ckv[((size_t)bh * 128 + k) * 256 + v] = s * inv_scale;
}

// ---------------------------------------------------------------------------
// Phase C v2: TWO waves per block (wave wv owns v-groups [4wv,4wv+4)).
// QK^T score compute duplicated per wave (cheap); groupnorm via per-wave
// shuffle partial + 512B LDS cross-wave combine (one barrier).
// Doubles occupancy of the former 1-wave latency-bound kernel.
// ---------------------------------------------------------------------------
__global__ __launch_bounds__(128)
void retention_chunk(const ushort_t* __restrict__ qh,
                     const ushort_t* __restrict__ kh,
                     const ushort_t* __restrict__ vt,
                     const ushort_t* __restrict__ St,
                     const ushort_t* __restrict__ grw,
                     ushort_t* __restrict__ gated)
{
    __shared__ float red[2][2][16][2];   // [wv][q][r][{a1,a2}]

    const int it = blockIdx.x;
    const int bh = blockIdx.y;
    const int b = bh >> 3, h = bh & 7;
    const int c = it >> 1, w = it & 1;
    const int tid = threadIdx.x;
    const int wv = tid >> 6;             // wave index 0/1
    const int l = tid & 63, lc = l & 31, q = l >> 5;
    const int vg0 = wv * 4;              // this wave's first v-group
    const int i0 = it * 32;
    const size_t bhT = (size_t)bh * T_SEQ;

    float ld, gamma;
    decay_params(h, ld, gamma);

    bf16x8 qf[8];
    {
        const ushort_t* qp = qh + (bhT + i0 + lc) * 128 + q * 8;
        #pragma unroll
        for (int c8 = 0; c8 < 8; ++c8)
            qf[c8] = *(const bf16x8*)(qp + c8 * 16);
    }

    f32x16 acc[4];
    #pragma unroll
    for (int vg = 0; vg < 4; ++vg)
        #pragma unroll
        for (int e = 0; e < 16; ++e) acc[vg][e] = 0.0f;

    if (c > 0) {
        const ushort_t* sp = St + ((size_t)(bh * 32 + c) * 256 + vg0 * 32 + lc) * 128 + q * 8;
        #pragma unroll
        for (int vg = 0; vg < 4; ++vg) {
            const ushort_t* spv = sp + (size_t)vg * 32 * 128;
            #pragma unroll
            for (int ks = 0; ks < 8; ++ks) {
                bf16x8 sb = *(const bf16x8*)(spv + ks * 16);
                acc[vg] = __builtin_amdgcn_mfma_f32_32x32x16_bf16(
                    qf[ks], sb, acc[vg], 0, 0, 0);
            }
        }
    }

    for (int jt2 = 0; jt2 <= w; ++jt2) {
        const int j0 = c * 64 + jt2 * 32;

        f32x16 s;
        #pragma unroll
        for (int e = 0; e < 16; ++e) s[e] = 0.0f;
        const ushort_t* kp = kh + (bhT + j0 + lc) * 128 + q * 8;
        #pragma unroll
        for (int c8 = 0; c8 < 8; ++c8) {
            bf16x8 ka = *(const bf16x8*)(kp + c8 * 16);
            s = __builtin_amdgcn_mfma_f32_32x32x16_bf16(ka, qf[c8], s, 0, 0, 0);
        }

        float sv[16];
        #pragma unroll
        for (int r = 0; r < 16; ++r) {
            float val = s[r];
            if (jt2 == w) {
                int jr_ = (r & 3) + 8 * (r >> 2) + 4 * q;
                val = (jr_ <= lc) ? val : 0.0f;
            }
            sv[r] = val;
        }

        bf16x8 pa0, pa1;
        #pragma unroll
        for (int e = 0; e < 4; ++e) {
            float t1 = __shfl_xor(sv[e + 4], 32);
            float t0 = __shfl_xor(sv[e], 32);
            pa0[e]     = f2bf(q ? t1 : sv[e]);
            pa0[e + 4] = f2bf(q ? sv[e + 4] : t0);
            float t3 = __shfl_xor(sv[e + 12], 32);
            float t2 = __shfl_xor(sv[e + 8], 32);
            pa1[e]     = f2bf(q ? t3 : sv[e + 8]);
            pa1[e + 4] = f2bf(q ? sv[e + 12] : t2);
        }

        #pragma unroll
        for (int vg = 0; vg < 4; ++vg) {
            const ushort_t* vp = vt + ((size_t)bh * 256 + (vg0 + vg) * 32 + lc) * T_SEQ
                                 + j0 + q * 8;
            bf16x8 vb0 = *(const bf16x8*)vp;
            bf16x8 vb1 = *(const bf16x8*)(vp + 16);
            acc[vg] = __builtin_amdgcn_mfma_f32_32x32x16_bf16(pa0, vb0, acc[vg], 0, 0, 0);
            acc[vg] = __builtin_amdgcn_mfma_f32_32x32x16_bf16(pa1, vb1, acc[vg], 0, 0, 0);
        }
    }

    // ---- groupnorm: per-wave partials (this wave's 4 vg x 32 lanes = 128 el) ----
    float fsv[16], p1[16], p2[16];
    #pragma unroll
    for (int r = 0; r < 16; ++r) {
        const int il = (r & 3) + 8 * (r >> 2) + 4 * q;
        const int i  = i0 + il;
        float denom = (1.0f - expf(ld * (float)(i + 1))) / (1.0f - gamma);
        fsv[r] = 0.08838834764831845f * rsqrtf(denom);
        float a1 = 0.0f, a2 = 0.0f;
        #pragma unroll
        for (int vg = 0; vg < 4; ++vg) {
            float x = acc[vg][r] * fsv[r];
            a1 += x; a2 += x * x;
        }
        a1 += __shfl_xor(a1, 1);  a2 += __shfl_xor(a2, 1);
        a1 += __shfl_xor(a1, 2);  a2 += __shfl_xor(a2, 2);
        a1 += __shfl_xor(a1, 4);  a2 += __shfl_xor(a2, 4);
        a1 += __shfl_xor(a1, 8);  a2 += __shfl_xor(a2, 8);
        a1 += __shfl_xor(a1, 16); a2 += __shfl_xor(a2, 16);
        p1[r] = a1; p2[r] = a2;
    }
    if (lc == 0) {
        #pragma unroll
        for (int r = 0; r < 16; ++r) {
            red[wv][q][r][0] = p1[r];
            red[wv][q][r][1] = p2[r];
        }
    }
    __syncthreads();

    #pragma unroll
    for (int r = 0; r < 16; ++r) {
        const int il = (r & 3) + 8 * (r >> 2) + 4 * q;
        const int i  = i0 + il;
        float a1 = p1[r] + red[1 - wv][q][r][0];
        float a2 = p2[r] + red[1 - wv][q][r][1];
        float mu = a1 * (1.0f / 256.0f);
        float var = a2 * (1.0f / 256.0f) - mu * mu;
        float rs = rsqrtf(var + 1e-5f);
        const size_t ob = ((size_t)(b * T_SEQ + i)) * V_DIM + h * DV + lc;
        ushort_t* op = gated + ob;
        const ushort_t* gp = grw + ob;
        #pragma unroll
        for (int vg = 0; vg < 4; ++vg) {
            float x = acc[vg][r] * fsv[r];
            float g = bf2f(gp[(vg0 + vg) * 32]);
            op[(vg0 + vg) * 32] = (ushort_t)f2bf((x - mu) * rs * g);
        }
    }
}

// ---------------------------------------------------------------------------
extern "C" void kernel_launch(void* const* d_in, const int* in_sizes, int n_in,
                              void* d_out, int out_size, void* d_ws, size_t ws_size,
                              hipStream_t stream)
{
    const float* hs    = (const float*)d_in[0];
    const float* w_qkv = (const float*)d_in[1];
    const float* b_qkv = (const float*)d_in[2];
    const float* w_g   = (const float*)d_in[3];
    const float* b_g   = (const float*)d_in[4];
    const float* w_p   = (const float*)d_in[5];
    const float* b_p   = (const float*)d_in[6];
    float* out = (float*)d_out;

    const size_t MB = 1024 * 1024;
    // ws (96MB) timeline (qkv bf16, in-place scan):
    //   [0,32):  qkv_bf (qkv GEMM -> preps)  ->  Abuf (chunk_kv -> scan)
    //            -> St IN-PLACE (scan -> retention) -> wp_t@[0,4) (-> proj)
    //   [32,48): gate_raw (gate GEMM -> retention)
    //   [48,64): gated (retention -> proj)
    //   [64,72): wg_t@[64,68) (-> gate GEMM) -> qh (qkv_prep -> retention)
    //   [72,88): vt (qkv_prep -> retention)
    //   [88,96): wqkv_t (-> qkv GEMM) -> kh (qkv_prep -> kt2/retention)
    // d_out (18MB): hs_bf@[0,8), kt2@[8,16) — dead before proj store;
    //               proj writes out@[0,16) at the END; ckv@[16,18).
    ushort_t* qkv_bf   = (ushort_t*)d_ws;
    ushort_t* Abuf     = (ushort_t*)d_ws;               // aliases qkv_bf (dead)
    ushort_t* Stbuf    = (ushort_t*)d_ws;               // IN-PLACE with Abuf
    ushort_t* wp_t     = (ushort_t*)d_ws;               // after retention
    ushort_t* gate_raw = (ushort_t*)((char*)d_ws + 32 * MB);
    ushort_t* gated_bf = (ushort_t*)((char*)d_ws + 48 * MB);
    ushort_t* wg_t     = (ushort_t*)((char*)d_ws + 64 * MB);
    ushort_t* qh       = (ushort_t*)((char*)d_ws + 64 * MB);  // after wg_t dead
    ushort_t* vt       = (ushort_t*)((char*)d_ws + 72 * MB);
    ushort_t* wqkv_t   = (ushort_t*)((char*)d_ws + 88 * MB);
    ushort_t* kh       = (ushort_t*)((char*)d_ws + 88 * MB);  // after wqkv_t dead
    ushort_t* hs_bf    = (ushort_t*)d_out;
    ushort_t* kt2      = (ushort_t*)((char*)d_out + 8 * MB);
    float*    ckv_out  = out + (size_t)BT * E_DIM;

    // 1. batched conversions: hs->bf16, w_qkv^T, w_g^T (one launch)
    prep_batch<<<dim3(8192), 256, 0, stream>>>(hs, hs_bf, w_qkv, wqkv_t, w_g, wg_t);

    // 2. gate_raw = silu(hs @ w_g + b_g)
    gemm_gate_p8<<<dim3(8, 32), 512, 0, stream>>>(
        hs_bf, wg_t, b_g, gate_raw, V_DIM, E_DIM / 64);

    // 3. qkv = hs @ w_qkv + b_qkv -> bf16 (round-8 proven 8-phase 256x256)
    gemm256p8<<<dim3(16, 16), 512, 0, stream>>>(
        hs_bf, wqkv_t, b_qkv, qkv_bf, 4096, E_DIM / 64);

    // 4. fused preps: qk xpos + v transpose (one launch)
    qkv_prep<<<dim3(12288), 256, 0, stream>>>(qkv_bf, qh, kh, vt);
    kt2_kernel<<<dim3(64, 64), 256, 0, stream>>>(kh, kt2);

    // 5. chunked retention: A (over dead qkv_bf) -> in-place scan -> outputs
    chunk_kv<<<dim3(32, 16), 256, 0, stream>>>(vt, kt2, Abuf);
    scan_state<<<dim3(2048), 256, 0, stream>>>(Abuf, Stbuf, ckv_out);
    retention_chunk<<<dim3(64, 16), 128, 0, stream>>>(qh, kh, vt, Stbuf, gate_raw, gated_bf);

    // 6. proj = gated @ w_p + b_p  (wp_t over dead St; out over dead hs_bf/kt2)
    transpose_w_kernel<<<dim3(32, 64), 256, 0, stream>>>(w_p, wp_t, V_DIM, E_DIM);
    gemm_tm64<<<dim3(8, 64), 256, 0, stream>>>(
        gated_bf, V_DIM, wp_t, V_DIM, b_p, out, E_DIM, V_DIM / 32);
}